// Round 2
// baseline (1099.530 us; speedup 1.0000x reference)
//
#include <hip/hip_runtime.h>
#include <math.h>

constexpr int H = 64;

// ---- CSR build ----
__global__ void k_hist(const int* __restrict__ dst, int* __restrict__ hist, int E) {
  int e = blockIdx.x * blockDim.x + threadIdx.x;
  if (e < E) atomicAdd(&hist[dst[e]], 1);
}

// chunked scan: each thread owns a contiguous chunk; one 1024-wide LDS scan.
__global__ void k_scan(const int* __restrict__ hist, int* __restrict__ row_ptr,
                       int* __restrict__ pos, float* __restrict__ degf, int n) {
  __shared__ int ssum[1024];
  int tid = threadIdx.x;
  int chunk = (n + 1023) >> 10;
  int c0 = tid * chunk;
  int c1 = c0 + chunk; if (c1 > n) c1 = n;
  int s = 0;
  for (int i = c0; i < c1; ++i) s += hist[i];
  ssum[tid] = s;
  __syncthreads();
  for (int d = 1; d < 1024; d <<= 1) {
    int t = (tid >= d) ? ssum[tid - d] : 0;
    __syncthreads();
    ssum[tid] += t;
    __syncthreads();
  }
  int run = ssum[tid] - s;  // exclusive prefix for this chunk
  if (tid == 0) row_ptr[0] = 0;
  for (int i = c0; i < c1; ++i) {
    int v = hist[i];
    pos[i] = run;
    degf[i] = (float)(v > 1 ? v : 1);
    run += v;
    row_ptr[i + 1] = run;
  }
}

__global__ void k_scatter(const int* __restrict__ src, const int* __restrict__ dst,
                          const float* __restrict__ ea, int* __restrict__ pos,
                          int* __restrict__ ssrc, float* __restrict__ sea, int E) {
  int e = blockIdx.x * blockDim.x + threadIdx.x;
  if (e < E) {
    int d = dst[e];
    int p = atomicAdd(&pos[d], 1);
    ssrc[p] = src[e];
    sea[2 * p]     = ea[2 * e];
    sea[2 * p + 1] = ea[2 * e + 1];
  }
}

// ---- input projection: h = x @ W_in + b_in ----
__global__ void k_inproj(const float* __restrict__ x, const float* __restrict__ Win,
                         const float* __restrict__ bin, float* __restrict__ h, int n) {
  int t = blockIdx.x * blockDim.x + threadIdx.x;
  int v = t >> 6, j = t & 63;
  if (v < n) {
    float x0 = x[2 * v], x1 = x[2 * v + 1];
    h[(size_t)v * H + j] = fmaf(x0, Win[j], fmaf(x1, Win[H + j], bin[j]));
  }
}

// ---- g = h @ Wm1 (64x64), one wave per node, persistent blocks ----
__global__ void k_gemm64(const float* __restrict__ h, const float* __restrict__ W,
                         float* __restrict__ g, int n) {
  __shared__ float sW[64 * 64];
  for (int i = threadIdx.x; i < 64 * 64; i += 256) sW[i] = W[i];
  __syncthreads();
  int j = threadIdx.x & 63;
  int w = threadIdx.x >> 6;
  int stride = gridDim.x * 4;
  for (int v = blockIdx.x * 4 + w; v < n; v += stride) {
    float hv = h[(size_t)v * H + j];
    float acc = 0.f;
#pragma unroll
    for (int k = 0; k < 64; ++k)
      acc = fmaf(__shfl(hv, k), sW[k * 64 + j], acc);
    g[(size_t)v * H + j] = acc;
  }
}

// ---- fused aggregate (CSR, no atomics) + update MLP, persistent blocks ----
__global__ void k_aggupd(const float* __restrict__ g, const int* __restrict__ row_ptr,
                         const int* __restrict__ ssrc, const float* __restrict__ sea,
                         const float* __restrict__ degf,
                         const float* __restrict__ Wm, const float* __restrict__ bm,
                         const float* __restrict__ Wu, const float* __restrict__ bu,
                         float* __restrict__ h, int n) {
  __shared__ float sWu[128 * 64];  // 32 KB
  for (int i = threadIdx.x; i < 128 * 64; i += 256) sWu[i] = Wu[i];
  __syncthreads();
  int j = threadIdx.x & 63;
  int w = threadIdx.x >> 6;
  float w2a = Wm[64 * 64 + j], w2b = Wm[65 * 64 + j], bmj = bm[j];
  float buj = bu[j];
  int stride = gridDim.x * 4;
  for (int v = blockIdx.x * 4 + w; v < n; v += stride) {
    int beg = row_ptr[v], end = row_ptr[v + 1];
    float acc = 0.f;
    int i = beg;
    for (; i + 1 < end; i += 2) {
      int s0 = ssrc[i], s1 = ssrc[i + 1];
      float ga = g[(size_t)s0 * H + j], gb = g[(size_t)s1 * H + j];
      float e0a = sea[2 * i],     e1a = sea[2 * i + 1];
      float e0b = sea[2 * i + 2], e1b = sea[2 * i + 3];
      float va = fmaf(e0a, w2a, fmaf(e1a, w2b, ga + bmj));
      float vb = fmaf(e0b, w2a, fmaf(e1b, w2b, gb + bmj));
      acc += fmaxf(va, 0.f) + fmaxf(vb, 0.f);
    }
    if (i < end) {
      int s0 = ssrc[i];
      float va = fmaf(sea[2 * i], w2a, fmaf(sea[2 * i + 1], w2b, g[(size_t)s0 * H + j] + bmj));
      acc += fmaxf(va, 0.f);
    }
    acc /= degf[v];  // agg[v][j]
    float hv = h[(size_t)v * H + j];
    float out = buj;
#pragma unroll
    for (int k = 0; k < 64; ++k) {
      out = fmaf(__shfl(hv, k),  sWu[k * 64 + j],        out);
      out = fmaf(__shfl(acc, k), sWu[(64 + k) * 64 + j], out);
    }
    h[(size_t)v * H + j] = fmaxf(out, 0.f);
  }
}

// ---- node head (sigmoid) + block-reduced partial sums -> atomic hsum[64] ----
__global__ void k_head(const float* __restrict__ h, const float* __restrict__ Wn,
                       const float* __restrict__ bn, float* __restrict__ probs,
                       float* __restrict__ hsum, int n) {
  __shared__ float red[256];
  int j = threadIdx.x & 63;
  int gw = blockIdx.x * (blockDim.x >> 6) + (threadIdx.x >> 6);
  int nw = gridDim.x * (blockDim.x >> 6);
  float wj = Wn[j], b0 = bn[0];
  float psum = 0.f;
  for (int v = gw; v < n; v += nw) {
    float hv = h[(size_t)v * H + j];
    psum += hv;
    float t = hv * wj;
#pragma unroll
    for (int d = 32; d > 0; d >>= 1) t += __shfl_down(t, d);
    if (j == 0) probs[v] = 1.f / (1.f + expf(-(t + b0)));
  }
  red[threadIdx.x] = psum;
  __syncthreads();
  if (threadIdx.x < 64) {
    float t = red[threadIdx.x] + red[threadIdx.x + 64] +
              red[threadIdx.x + 128] + red[threadIdx.x + 192];
    atomicAdd(&hsum[threadIdx.x], t);
  }
}

// ---- global mean + 2-layer head (tiny) ----
__global__ void k_final(const float* __restrict__ hsum,
                        const float* __restrict__ W1, const float* __restrict__ b1,
                        const float* __restrict__ W2, const float* __restrict__ b2,
                        float* __restrict__ out4, float n_nodes) {
  __shared__ float hmean[64];
  __shared__ float z1[32];
  int tid = threadIdx.x;
  if (tid < 64) hmean[tid] = hsum[tid] / n_nodes;
  __syncthreads();
  if (tid < 32) {
    float a = b1[tid];
    for (int k = 0; k < 64; ++k) a = fmaf(hmean[k], W1[k * 32 + tid], a);
    z1[tid] = fmaxf(a, 0.f);
  }
  __syncthreads();
  if (tid < 4) {
    float a = b2[tid];
    for (int k = 0; k < 32; ++k) a = fmaf(z1[k], W2[k * 4 + tid], a);
    out4[tid] = a;
  }
}

extern "C" void kernel_launch(void* const* d_in, const int* in_sizes, int n_in,
                              void* d_out, int out_size, void* d_ws, size_t ws_size,
                              hipStream_t stream) {
  const float* x    = (const float*)d_in[0];
  const int*   ei   = (const int*)d_in[1];
  const float* ea   = (const float*)d_in[2];
  const float* Win  = (const float*)d_in[3];
  const float* bin  = (const float*)d_in[4];
  const float* Wmsg = (const float*)d_in[5];
  const float* bmsg = (const float*)d_in[6];
  const float* Wupd = (const float*)d_in[7];
  const float* bupd = (const float*)d_in[8];
  const float* Wn   = (const float*)d_in[9];
  const float* bn   = (const float*)d_in[10];
  const float* W1   = (const float*)d_in[13];
  const float* b1   = (const float*)d_in[14];
  const float* W2   = (const float*)d_in[15];
  const float* b2   = (const float*)d_in[16];

  const int N = in_sizes[0] / 2;   // x is [N, 2]
  const int E = in_sizes[1] / 2;   // edge_index is [2, E]
  const int* src = ei;
  const int* dst = ei + E;

  char* ws = (char*)d_ws;
  size_t off = 0;
  auto alloc = [&](size_t bytes) {
    void* p = ws + off;
    off = (off + bytes + 255) & ~(size_t)255;
    return p;
  };
  int*   hist = (int*)  alloc((size_t)N * 4);
  int*   rptr = (int*)  alloc((size_t)(N + 1) * 4);
  int*   pos  = (int*)  alloc((size_t)N * 4);
  float* degf = (float*)alloc((size_t)N * 4);
  int*   ssrc = (int*)  alloc((size_t)E * 4);
  float* sea  = (float*)alloc((size_t)E * 8);
  float* g    = (float*)alloc((size_t)N * H * 4);
  float* hsum = (float*)alloc(64 * 4);
  (void)ws_size;

  float* probs = (float*)d_out;          // [N]
  float* out4  = probs + N;              // [4]
  float* h     = out4 + 4;               // [N, 64]  (working buffer == output)

  hipMemsetAsync(hist, 0, (size_t)N * 4, stream);
  hipMemsetAsync(hsum, 0, 64 * 4, stream);
  int eb = (E + 255) / 256;
  k_hist<<<eb, 256, 0, stream>>>(dst, hist, E);
  k_scan<<<1, 1024, 0, stream>>>(hist, rptr, pos, degf, N);
  k_scatter<<<eb, 256, 0, stream>>>(src, dst, ea, pos, ssrc, sea, E);

  int nb = (N + 3) / 4;  // node-group count (one wave per node, 4 waves/block)
  k_inproj<<<nb, 256, 0, stream>>>(x, Win, bin, h, N);

  int gb_gemm = nb < 2048 ? nb : 2048;   // persistent: 8 blocks/CU (16 KB LDS)
  int gb_agg  = nb < 1280 ? nb : 1280;   // persistent: 5 blocks/CU (32 KB LDS)
  for (int l = 0; l < 3; ++l) {
    k_gemm64<<<gb_gemm, 256, 0, stream>>>(h, Wmsg + (size_t)l * 66 * 64, g, N);
    k_aggupd<<<gb_agg, 256, 0, stream>>>(g, rptr, ssrc, sea, degf,
                                         Wmsg + (size_t)l * 66 * 64, bmsg + (size_t)l * 64,
                                         Wupd + (size_t)l * 128 * 64, bupd + (size_t)l * 64,
                                         h, N);
  }

  k_head<<<512, 256, 0, stream>>>(h, Wn, bn, probs, hsum, N);
  k_final<<<1, 64, 0, stream>>>(hsum, W1, b1, W2, b2, out4, (float)N);
}

// Round 3
// 818.293 us; speedup vs baseline: 1.3437x; 1.3437x over previous
//
#include <hip/hip_runtime.h>
#include <math.h>

constexpr int H = 64;

// ---- CSR build ----
__global__ void k_hist(const int* __restrict__ dst, int* __restrict__ hist, int E) {
  int e = blockIdx.x * blockDim.x + threadIdx.x;
  if (e < E) atomicAdd(&hist[dst[e]], 1);
}

// chunked scan: each thread owns a contiguous chunk; one 1024-wide LDS scan.
__global__ void k_scan(const int* __restrict__ hist, int* __restrict__ row_ptr,
                       int* __restrict__ pos, float* __restrict__ degf, int n) {
  __shared__ int ssum[1024];
  int tid = threadIdx.x;
  int chunk = (n + 1023) >> 10;
  int c0 = tid * chunk;
  int c1 = c0 + chunk; if (c1 > n) c1 = n;
  int s = 0;
  for (int i = c0; i < c1; ++i) s += hist[i];
  ssum[tid] = s;
  __syncthreads();
  for (int d = 1; d < 1024; d <<= 1) {
    int t = (tid >= d) ? ssum[tid - d] : 0;
    __syncthreads();
    ssum[tid] += t;
    __syncthreads();
  }
  int run = ssum[tid] - s;  // exclusive prefix for this chunk
  if (tid == 0) row_ptr[0] = 0;
  for (int i = c0; i < c1; ++i) {
    int v = hist[i];
    pos[i] = run;
    degf[i] = (float)(v > 1 ? v : 1);
    run += v;
    row_ptr[i + 1] = run;
  }
}

__global__ void k_scatter(const int* __restrict__ src, const int* __restrict__ dst,
                          const float* __restrict__ ea, int* __restrict__ pos,
                          int* __restrict__ ssrc, float* __restrict__ sea, int E) {
  int e = blockIdx.x * blockDim.x + threadIdx.x;
  if (e < E) {
    int d = dst[e];
    int p = atomicAdd(&pos[d], 1);
    ssrc[p] = src[e];
    sea[2 * p]     = ea[2 * e];
    sea[2 * p + 1] = ea[2 * e + 1];
  }
}

// ---- input projection: h = x @ W_in + b_in ----
__global__ void k_inproj(const float* __restrict__ x, const float* __restrict__ Win,
                         const float* __restrict__ bin, float* __restrict__ h, int n) {
  int t = blockIdx.x * blockDim.x + threadIdx.x;
  int v = t >> 6, j = t & 63;
  if (v < n) {
    float x0 = x[2 * v], x1 = x[2 * v + 1];
    h[(size_t)v * H + j] = fmaf(x0, Win[j], fmaf(x1, Win[H + j], bin[j]));
  }
}

// ---- g = h @ Wm1 (64x64), one wave per node, persistent blocks ----
__global__ void k_gemm64(const float* __restrict__ h, const float* __restrict__ W,
                         float* __restrict__ g, int n) {
  __shared__ float sW[64 * 64];
  for (int i = threadIdx.x; i < 64 * 64; i += 256) sW[i] = W[i];
  __syncthreads();
  int j = threadIdx.x & 63;
  int w = threadIdx.x >> 6;
  int stride = gridDim.x * 4;
  for (int v = blockIdx.x * 4 + w; v < n; v += stride) {
    float hv = h[(size_t)v * H + j];
    float acc = 0.f;
#pragma unroll
    for (int k = 0; k < 64; ++k)
      acc = fmaf(__shfl(hv, k), sW[k * 64 + j], acc);
    g[(size_t)v * H + j] = acc;
  }
}

// ---- aggregation only: zero LDS, max occupancy, deep gather pipeline ----
// one wave per node; lane j owns feature j. agg[v] = mean_e relu(g[src]+ea@Wm2+b)
__global__ void k_agg(const float* __restrict__ g, const int* __restrict__ row_ptr,
                      const int* __restrict__ ssrc, const float2* __restrict__ sea2,
                      const float* __restrict__ degf,
                      const float* __restrict__ Wm2, const float* __restrict__ bm,
                      float* __restrict__ agg, int n) {
  int t = blockIdx.x * blockDim.x + threadIdx.x;
  int v = t >> 6, j = t & 63;
  if (v >= n) return;
  float w2a = Wm2[j], w2b = Wm2[64 + j], bmj = bm[j];
  int beg = row_ptr[v], end = row_ptr[v + 1];
  float acc = 0.f;
  int i = beg;
  if (i + 3 < end) {
    // software-pipelined quads: prefetch next quad's indices during gathers
    int sA0 = ssrc[i], sA1 = ssrc[i + 1], sA2 = ssrc[i + 2], sA3 = ssrc[i + 3];
    for (; i + 7 < end; i += 4) {
      int sB0 = ssrc[i + 4], sB1 = ssrc[i + 5], sB2 = ssrc[i + 6], sB3 = ssrc[i + 7];
      float g0 = g[(size_t)sA0 * H + j];
      float g1 = g[(size_t)sA1 * H + j];
      float g2 = g[(size_t)sA2 * H + j];
      float g3 = g[(size_t)sA3 * H + j];
      float2 e0 = sea2[i], e1 = sea2[i + 1], e2 = sea2[i + 2], e3 = sea2[i + 3];
      acc += fmaxf(fmaf(e0.x, w2a, fmaf(e0.y, w2b, g0 + bmj)), 0.f)
           + fmaxf(fmaf(e1.x, w2a, fmaf(e1.y, w2b, g1 + bmj)), 0.f)
           + fmaxf(fmaf(e2.x, w2a, fmaf(e2.y, w2b, g2 + bmj)), 0.f)
           + fmaxf(fmaf(e3.x, w2a, fmaf(e3.y, w2b, g3 + bmj)), 0.f);
      sA0 = sB0; sA1 = sB1; sA2 = sB2; sA3 = sB3;
    }
    float g0 = g[(size_t)sA0 * H + j];
    float g1 = g[(size_t)sA1 * H + j];
    float g2 = g[(size_t)sA2 * H + j];
    float g3 = g[(size_t)sA3 * H + j];
    float2 e0 = sea2[i], e1 = sea2[i + 1], e2 = sea2[i + 2], e3 = sea2[i + 3];
    acc += fmaxf(fmaf(e0.x, w2a, fmaf(e0.y, w2b, g0 + bmj)), 0.f)
         + fmaxf(fmaf(e1.x, w2a, fmaf(e1.y, w2b, g1 + bmj)), 0.f)
         + fmaxf(fmaf(e2.x, w2a, fmaf(e2.y, w2b, g2 + bmj)), 0.f)
         + fmaxf(fmaf(e3.x, w2a, fmaf(e3.y, w2b, g3 + bmj)), 0.f);
    i += 4;
  }
  for (; i < end; ++i) {
    int s0 = ssrc[i];
    float2 e0 = sea2[i];
    acc += fmaxf(fmaf(e0.x, w2a, fmaf(e0.y, w2b, g[(size_t)s0 * H + j] + bmj)), 0.f);
  }
  agg[(size_t)v * H + j] = acc / degf[v];
}

// ---- update MLP: h = relu([h || agg] @ Wu + bu), persistent, LDS-staged Wu ----
__global__ void k_upd(const float* __restrict__ agg,
                      const float* __restrict__ Wu, const float* __restrict__ bu,
                      float* __restrict__ h, int n) {
  __shared__ float sWu[128 * 64];  // 32 KB
  for (int i = threadIdx.x; i < 128 * 64; i += 256) sWu[i] = Wu[i];
  __syncthreads();
  int j = threadIdx.x & 63;
  int w = threadIdx.x >> 6;
  float buj = bu[j];
  int stride = gridDim.x * 4;
  for (int v = blockIdx.x * 4 + w; v < n; v += stride) {
    float hv = h[(size_t)v * H + j];
    float av = agg[(size_t)v * H + j];
    float out = buj;
#pragma unroll
    for (int k = 0; k < 64; ++k) {
      out = fmaf(__shfl(hv, k), sWu[k * 64 + j],        out);
      out = fmaf(__shfl(av, k), sWu[(64 + k) * 64 + j], out);
    }
    h[(size_t)v * H + j] = fmaxf(out, 0.f);
  }
}

// ---- node head (sigmoid) + block-reduced partial sums -> atomic hsum[64] ----
__global__ void k_head(const float* __restrict__ h, const float* __restrict__ Wn,
                       const float* __restrict__ bn, float* __restrict__ probs,
                       float* __restrict__ hsum, int n) {
  __shared__ float red[256];
  int j = threadIdx.x & 63;
  int gw = blockIdx.x * (blockDim.x >> 6) + (threadIdx.x >> 6);
  int nw = gridDim.x * (blockDim.x >> 6);
  float wj = Wn[j], b0 = bn[0];
  float psum = 0.f;
  for (int v = gw; v < n; v += nw) {
    float hv = h[(size_t)v * H + j];
    psum += hv;
    float t = hv * wj;
#pragma unroll
    for (int d = 32; d > 0; d >>= 1) t += __shfl_down(t, d);
    if (j == 0) probs[v] = 1.f / (1.f + expf(-(t + b0)));
  }
  red[threadIdx.x] = psum;
  __syncthreads();
  if (threadIdx.x < 64) {
    float t = red[threadIdx.x] + red[threadIdx.x + 64] +
              red[threadIdx.x + 128] + red[threadIdx.x + 192];
    atomicAdd(&hsum[threadIdx.x], t);
  }
}

// ---- global mean + 2-layer head (tiny) ----
__global__ void k_final(const float* __restrict__ hsum,
                        const float* __restrict__ W1, const float* __restrict__ b1,
                        const float* __restrict__ W2, const float* __restrict__ b2,
                        float* __restrict__ out4, float n_nodes) {
  __shared__ float hmean[64];
  __shared__ float z1[32];
  int tid = threadIdx.x;
  if (tid < 64) hmean[tid] = hsum[tid] / n_nodes;
  __syncthreads();
  if (tid < 32) {
    float a = b1[tid];
    for (int k = 0; k < 64; ++k) a = fmaf(hmean[k], W1[k * 32 + tid], a);
    z1[tid] = fmaxf(a, 0.f);
  }
  __syncthreads();
  if (tid < 4) {
    float a = b2[tid];
    for (int k = 0; k < 32; ++k) a = fmaf(z1[k], W2[k * 4 + tid], a);
    out4[tid] = a;
  }
}

extern "C" void kernel_launch(void* const* d_in, const int* in_sizes, int n_in,
                              void* d_out, int out_size, void* d_ws, size_t ws_size,
                              hipStream_t stream) {
  const float* x    = (const float*)d_in[0];
  const int*   ei   = (const int*)d_in[1];
  const float* ea   = (const float*)d_in[2];
  const float* Win  = (const float*)d_in[3];
  const float* bin  = (const float*)d_in[4];
  const float* Wmsg = (const float*)d_in[5];
  const float* bmsg = (const float*)d_in[6];
  const float* Wupd = (const float*)d_in[7];
  const float* bupd = (const float*)d_in[8];
  const float* Wn   = (const float*)d_in[9];
  const float* bn   = (const float*)d_in[10];
  const float* W1   = (const float*)d_in[13];
  const float* b1   = (const float*)d_in[14];
  const float* W2   = (const float*)d_in[15];
  const float* b2   = (const float*)d_in[16];

  const int N = in_sizes[0] / 2;   // x is [N, 2]
  const int E = in_sizes[1] / 2;   // edge_index is [2, E]
  const int* src = ei;
  const int* dst = ei + E;

  char* ws = (char*)d_ws;
  size_t off = 0;
  auto alloc = [&](size_t bytes) {
    void* p = ws + off;
    off = (off + bytes + 255) & ~(size_t)255;
    return p;
  };
  int*   hist = (int*)  alloc((size_t)N * 4);
  int*   rptr = (int*)  alloc((size_t)(N + 1) * 4);
  int*   pos  = (int*)  alloc((size_t)N * 4);
  float* degf = (float*)alloc((size_t)N * 4);
  int*   ssrc = (int*)  alloc((size_t)E * 4);
  float* sea  = (float*)alloc((size_t)E * 8);
  float* g    = (float*)alloc((size_t)N * H * 4);
  float* agg  = (float*)alloc((size_t)N * H * 4);
  float* hsum = (float*)alloc(64 * 4);
  (void)ws_size;

  float* probs = (float*)d_out;          // [N]
  float* out4  = probs + N;              // [4]
  float* h     = out4 + 4;               // [N, 64]  (working buffer == output)

  hipMemsetAsync(hist, 0, (size_t)N * 4, stream);
  hipMemsetAsync(hsum, 0, 64 * 4, stream);
  int eb = (E + 255) / 256;
  k_hist<<<eb, 256, 0, stream>>>(dst, hist, E);
  k_scan<<<1, 1024, 0, stream>>>(hist, rptr, pos, degf, N);
  k_scatter<<<eb, 256, 0, stream>>>(src, dst, ea, pos, ssrc, sea, E);

  int nb = (N + 3) / 4;  // one wave per node, 4 waves/block
  k_inproj<<<nb, 256, 0, stream>>>(x, Win, bin, h, N);

  int gb_gemm = nb < 2048 ? nb : 2048;   // persistent: 16 KB LDS
  int gb_upd  = nb < 1280 ? nb : 1280;   // persistent: 32 KB LDS, compute-bound
  for (int l = 0; l < 3; ++l) {
    k_gemm64<<<gb_gemm, 256, 0, stream>>>(h, Wmsg + (size_t)l * 66 * 64, g, N);
    k_agg<<<nb, 256, 0, stream>>>(g, rptr, ssrc, (const float2*)sea, degf,
                                  Wmsg + (size_t)l * 66 * 64 + 64 * 64,
                                  bmsg + (size_t)l * 64, agg, N);
    k_upd<<<gb_upd, 256, 0, stream>>>(agg,
                                      Wupd + (size_t)l * 128 * 64, bupd + (size_t)l * 64,
                                      h, N);
  }

  k_head<<<512, 256, 0, stream>>>(h, Wn, bn, probs, hsum, N);
  k_final<<<1, 64, 0, stream>>>(hsum, W1, b1, W2, b2, out4, (float)N);
}

// Round 4
// 679.176 us; speedup vs baseline: 1.6189x; 1.2048x over previous
//
#include <hip/hip_runtime.h>
#include <math.h>

constexpr int H = 64;

__device__ inline unsigned short f2bf(float f) {
  union { float f; unsigned int u; } c; c.f = f;
  unsigned int u = c.u;
  return (unsigned short)((u + 0x7FFF + ((u >> 16) & 1)) >> 16);  // RNE
}
__device__ inline float bf2f(unsigned short s) {
  union { unsigned int u; float f; } c; c.u = ((unsigned int)s) << 16;
  return c.f;
}

// ---- CSR build ----
__global__ void k_hist(const int* __restrict__ dst, int* __restrict__ hist, int E) {
  int e = blockIdx.x * blockDim.x + threadIdx.x;
  if (e < E) atomicAdd(&hist[dst[e]], 1);
}

// multi-block scan, phase 1: per-block (1024 elems) sums
__global__ void k_scan1(const int* __restrict__ hist, int* __restrict__ bsum, int n) {
  __shared__ int sred[256];
  int tid = threadIdx.x;
  int base = blockIdx.x * 1024 + tid * 4;
  int s = 0;
#pragma unroll
  for (int k = 0; k < 4; ++k) { int i = base + k; if (i < n) s += hist[i]; }
  sred[tid] = s;
  __syncthreads();
  for (int d = 128; d > 0; d >>= 1) {
    if (tid < d) sred[tid] += sred[tid + d];
    __syncthreads();
  }
  if (tid == 0) bsum[blockIdx.x] = sred[0];
}

// phase 2: exclusive scan of block sums (nb <= 1024), in place
__global__ void k_scan2(int* __restrict__ bsum, int nb) {
  __shared__ int sd[1024];
  int tid = threadIdx.x;
  int v = (tid < nb) ? bsum[tid] : 0;
  sd[tid] = v;
  __syncthreads();
  for (int d = 1; d < 1024; d <<= 1) {
    int t = (tid >= d) ? sd[tid - d] : 0;
    __syncthreads();
    sd[tid] += t;
    __syncthreads();
  }
  if (tid < nb) bsum[tid] = sd[tid] - v;
}

// phase 3: per-block local scan + block offset -> row_ptr, pos, degf
__global__ void k_scan3(const int* __restrict__ hist, const int* __restrict__ bsum,
                        int* __restrict__ row_ptr, int* __restrict__ pos,
                        float* __restrict__ degf, int n) {
  __shared__ int sth[256];
  int tid = threadIdx.x;
  int base = blockIdx.x * 1024 + tid * 4;
  int v[4]; int s = 0;
#pragma unroll
  for (int k = 0; k < 4; ++k) { int i = base + k; v[k] = (i < n) ? hist[i] : 0; s += v[k]; }
  sth[tid] = s;
  __syncthreads();
  for (int d = 1; d < 256; d <<= 1) {
    int t = (tid >= d) ? sth[tid - d] : 0;
    __syncthreads();
    sth[tid] += t;
    __syncthreads();
  }
  int run = bsum[blockIdx.x] + sth[tid] - s;  // exclusive prefix for this thread
  if (blockIdx.x == 0 && tid == 0) row_ptr[0] = 0;
#pragma unroll
  for (int k = 0; k < 4; ++k) {
    int i = base + k;
    if (i < n) {
      pos[i] = run;
      degf[i] = (float)(v[k] > 1 ? v[k] : 1);
      run += v[k];
      row_ptr[i + 1] = run;
    }
  }
}

__global__ void k_scatter(const int* __restrict__ src, const int* __restrict__ dst,
                          const float* __restrict__ ea, int* __restrict__ pos,
                          int* __restrict__ ssrc, float* __restrict__ sea, int E) {
  int e = blockIdx.x * blockDim.x + threadIdx.x;
  if (e < E) {
    int d = dst[e];
    int p = atomicAdd(&pos[d], 1);
    ssrc[p] = src[e];
    sea[2 * p]     = ea[2 * e];
    sea[2 * p + 1] = ea[2 * e + 1];
  }
}

// ---- input projection: h = x @ W_in + b_in ----
__global__ void k_inproj(const float* __restrict__ x, const float* __restrict__ Win,
                         const float* __restrict__ bin, float* __restrict__ h, int n) {
  int t = blockIdx.x * blockDim.x + threadIdx.x;
  int v = t >> 6, j = t & 63;
  if (v < n) {
    float x0 = x[2 * v], x1 = x[2 * v + 1];
    h[(size_t)v * H + j] = fmaf(x0, Win[j], fmaf(x1, Win[H + j], bin[j]));
  }
}

// ---- g = bf16(h @ Wm1) (64x64), one wave per node, persistent blocks ----
__global__ void k_gemm64(const float* __restrict__ h, const float* __restrict__ W,
                         unsigned short* __restrict__ g, int n) {
  __shared__ float sW[64 * 64];
  for (int i = threadIdx.x; i < 64 * 64; i += 256) sW[i] = W[i];
  __syncthreads();
  int j = threadIdx.x & 63;
  int w = threadIdx.x >> 6;
  int stride = gridDim.x * 4;
  for (int v = blockIdx.x * 4 + w; v < n; v += stride) {
    float hv = h[(size_t)v * H + j];
    float acc = 0.f;
#pragma unroll
    for (int k = 0; k < 64; ++k)
      acc = fmaf(__shfl(hv, k), sW[k * 64 + j], acc);
    g[(size_t)v * H + j] = f2bf(acc);
  }
}

// ---- aggregation: zero LDS, max occupancy, deep gather pipeline, bf16 g ----
__global__ void k_agg(const unsigned short* __restrict__ g, const int* __restrict__ row_ptr,
                      const int* __restrict__ ssrc, const float2* __restrict__ sea2,
                      const float* __restrict__ degf,
                      const float* __restrict__ Wm2, const float* __restrict__ bm,
                      float* __restrict__ agg, int n) {
  int t = blockIdx.x * blockDim.x + threadIdx.x;
  int v = t >> 6, j = t & 63;
  if (v >= n) return;
  float w2a = Wm2[j], w2b = Wm2[64 + j], bmj = bm[j];
  int beg = row_ptr[v], end = row_ptr[v + 1];
  float acc = 0.f;
  int i = beg;
  if (i + 3 < end) {
    int sA0 = ssrc[i], sA1 = ssrc[i + 1], sA2 = ssrc[i + 2], sA3 = ssrc[i + 3];
    for (; i + 7 < end; i += 4) {
      int sB0 = ssrc[i + 4], sB1 = ssrc[i + 5], sB2 = ssrc[i + 6], sB3 = ssrc[i + 7];
      float g0 = bf2f(g[(size_t)sA0 * H + j]);
      float g1 = bf2f(g[(size_t)sA1 * H + j]);
      float g2 = bf2f(g[(size_t)sA2 * H + j]);
      float g3 = bf2f(g[(size_t)sA3 * H + j]);
      float2 e0 = sea2[i], e1 = sea2[i + 1], e2 = sea2[i + 2], e3 = sea2[i + 3];
      acc += fmaxf(fmaf(e0.x, w2a, fmaf(e0.y, w2b, g0 + bmj)), 0.f)
           + fmaxf(fmaf(e1.x, w2a, fmaf(e1.y, w2b, g1 + bmj)), 0.f)
           + fmaxf(fmaf(e2.x, w2a, fmaf(e2.y, w2b, g2 + bmj)), 0.f)
           + fmaxf(fmaf(e3.x, w2a, fmaf(e3.y, w2b, g3 + bmj)), 0.f);
      sA0 = sB0; sA1 = sB1; sA2 = sB2; sA3 = sB3;
    }
    float g0 = bf2f(g[(size_t)sA0 * H + j]);
    float g1 = bf2f(g[(size_t)sA1 * H + j]);
    float g2 = bf2f(g[(size_t)sA2 * H + j]);
    float g3 = bf2f(g[(size_t)sA3 * H + j]);
    float2 e0 = sea2[i], e1 = sea2[i + 1], e2 = sea2[i + 2], e3 = sea2[i + 3];
    acc += fmaxf(fmaf(e0.x, w2a, fmaf(e0.y, w2b, g0 + bmj)), 0.f)
         + fmaxf(fmaf(e1.x, w2a, fmaf(e1.y, w2b, g1 + bmj)), 0.f)
         + fmaxf(fmaf(e2.x, w2a, fmaf(e2.y, w2b, g2 + bmj)), 0.f)
         + fmaxf(fmaf(e3.x, w2a, fmaf(e3.y, w2b, g3 + bmj)), 0.f);
    i += 4;
  }
  for (; i < end; ++i) {
    int s0 = ssrc[i];
    float2 e0 = sea2[i];
    acc += fmaxf(fmaf(e0.x, w2a, fmaf(e0.y, w2b, bf2f(g[(size_t)s0 * H + j]) + bmj)), 0.f);
  }
  agg[(size_t)v * H + j] = acc / degf[v];
}

// ---- update MLP: h = relu([h || agg] @ Wu + bu), persistent, LDS-staged Wu ----
__global__ void k_upd(const float* __restrict__ agg,
                      const float* __restrict__ Wu, const float* __restrict__ bu,
                      float* __restrict__ h, int n) {
  __shared__ float sWu[128 * 64];  // 32 KB
  for (int i = threadIdx.x; i < 128 * 64; i += 256) sWu[i] = Wu[i];
  __syncthreads();
  int j = threadIdx.x & 63;
  int w = threadIdx.x >> 6;
  float buj = bu[j];
  int stride = gridDim.x * 4;
  for (int v = blockIdx.x * 4 + w; v < n; v += stride) {
    float hv = h[(size_t)v * H + j];
    float av = agg[(size_t)v * H + j];
    float out = buj;
#pragma unroll
    for (int k = 0; k < 64; ++k) {
      out = fmaf(__shfl(hv, k), sWu[k * 64 + j],        out);
      out = fmaf(__shfl(av, k), sWu[(64 + k) * 64 + j], out);
    }
    h[(size_t)v * H + j] = fmaxf(out, 0.f);
  }
}

// ---- node head (sigmoid) + block-reduced partial sums -> atomic hsum[64] ----
__global__ void k_head(const float* __restrict__ h, const float* __restrict__ Wn,
                       const float* __restrict__ bn, float* __restrict__ probs,
                       float* __restrict__ hsum, int n) {
  __shared__ float red[256];
  int j = threadIdx.x & 63;
  int gw = blockIdx.x * (blockDim.x >> 6) + (threadIdx.x >> 6);
  int nw = gridDim.x * (blockDim.x >> 6);
  float wj = Wn[j], b0 = bn[0];
  float psum = 0.f;
  for (int v = gw; v < n; v += nw) {
    float hv = h[(size_t)v * H + j];
    psum += hv;
    float t = hv * wj;
#pragma unroll
    for (int d = 32; d > 0; d >>= 1) t += __shfl_down(t, d);
    if (j == 0) probs[v] = 1.f / (1.f + expf(-(t + b0)));
  }
  red[threadIdx.x] = psum;
  __syncthreads();
  if (threadIdx.x < 64) {
    float t = red[threadIdx.x] + red[threadIdx.x + 64] +
              red[threadIdx.x + 128] + red[threadIdx.x + 192];
    atomicAdd(&hsum[threadIdx.x], t);
  }
}

// ---- global mean + 2-layer head (tiny) ----
__global__ void k_final(const float* __restrict__ hsum,
                        const float* __restrict__ W1, const float* __restrict__ b1,
                        const float* __restrict__ W2, const float* __restrict__ b2,
                        float* __restrict__ out4, float n_nodes) {
  __shared__ float hmean[64];
  __shared__ float z1[32];
  int tid = threadIdx.x;
  if (tid < 64) hmean[tid] = hsum[tid] / n_nodes;
  __syncthreads();
  if (tid < 32) {
    float a = b1[tid];
    for (int k = 0; k < 64; ++k) a = fmaf(hmean[k], W1[k * 32 + tid], a);
    z1[tid] = fmaxf(a, 0.f);
  }
  __syncthreads();
  if (tid < 4) {
    float a = b2[tid];
    for (int k = 0; k < 32; ++k) a = fmaf(z1[k], W2[k * 4 + tid], a);
    out4[tid] = a;
  }
}

extern "C" void kernel_launch(void* const* d_in, const int* in_sizes, int n_in,
                              void* d_out, int out_size, void* d_ws, size_t ws_size,
                              hipStream_t stream) {
  const float* x    = (const float*)d_in[0];
  const int*   ei   = (const int*)d_in[1];
  const float* ea   = (const float*)d_in[2];
  const float* Win  = (const float*)d_in[3];
  const float* bin  = (const float*)d_in[4];
  const float* Wmsg = (const float*)d_in[5];
  const float* bmsg = (const float*)d_in[6];
  const float* Wupd = (const float*)d_in[7];
  const float* bupd = (const float*)d_in[8];
  const float* Wn   = (const float*)d_in[9];
  const float* bn   = (const float*)d_in[10];
  const float* W1   = (const float*)d_in[13];
  const float* b1   = (const float*)d_in[14];
  const float* W2   = (const float*)d_in[15];
  const float* b2   = (const float*)d_in[16];

  const int N = in_sizes[0] / 2;   // x is [N, 2]
  const int E = in_sizes[1] / 2;   // edge_index is [2, E]
  const int* src = ei;
  const int* dst = ei + E;

  char* ws = (char*)d_ws;
  size_t off = 0;
  auto alloc = [&](size_t bytes) {
    void* p = ws + off;
    off = (off + bytes + 255) & ~(size_t)255;
    return p;
  };
  int*   hist = (int*)  alloc((size_t)N * 4);
  int*   rptr = (int*)  alloc((size_t)(N + 1) * 4);
  int*   pos  = (int*)  alloc((size_t)N * 4);
  float* degf = (float*)alloc((size_t)N * 4);
  int*   bsum = (int*)  alloc((size_t)1024 * 4);
  int*   ssrc = (int*)  alloc((size_t)E * 4);
  float* sea  = (float*)alloc((size_t)E * 8);
  unsigned short* g = (unsigned short*)alloc((size_t)N * H * 2);
  float* agg  = (float*)alloc((size_t)N * H * 4);
  float* hsum = (float*)alloc(64 * 4);
  (void)ws_size;

  float* probs = (float*)d_out;          // [N]
  float* out4  = probs + N;              // [4]
  float* h     = out4 + 4;               // [N, 64]  (working buffer == output)

  hipMemsetAsync(hist, 0, (size_t)N * 4, stream);
  hipMemsetAsync(hsum, 0, 64 * 4, stream);
  int eb = (E + 255) / 256;
  int sb = (N + 1023) / 1024;            // scan blocks (49 for N=50000)
  k_hist<<<eb, 256, 0, stream>>>(dst, hist, E);
  k_scan1<<<sb, 256, 0, stream>>>(hist, bsum, N);
  k_scan2<<<1, 1024, 0, stream>>>(bsum, sb);
  k_scan3<<<sb, 256, 0, stream>>>(hist, bsum, rptr, pos, degf, N);
  k_scatter<<<eb, 256, 0, stream>>>(src, dst, ea, pos, ssrc, sea, E);

  int nb = (N + 3) / 4;  // one wave per node, 4 waves/block
  k_inproj<<<nb, 256, 0, stream>>>(x, Win, bin, h, N);

  int gb_gemm = nb < 2048 ? nb : 2048;   // persistent: 16 KB LDS
  int gb_upd  = nb < 1280 ? nb : 1280;   // persistent: 32 KB LDS
  for (int l = 0; l < 3; ++l) {
    k_gemm64<<<gb_gemm, 256, 0, stream>>>(h, Wmsg + (size_t)l * 66 * 64, g, N);
    k_agg<<<nb, 256, 0, stream>>>(g, rptr, ssrc, (const float2*)sea, degf,
                                  Wmsg + (size_t)l * 66 * 64 + 64 * 64,
                                  bmsg + (size_t)l * 64, agg, N);
    k_upd<<<gb_upd, 256, 0, stream>>>(agg,
                                      Wupd + (size_t)l * 128 * 64, bupd + (size_t)l * 64,
                                      h, N);
  }

  k_head<<<512, 256, 0, stream>>>(h, Wn, bn, probs, hsum, N);
  k_final<<<1, 64, 0, stream>>>(hsum, W1, b1, W2, b2, out4, (float)N);
}

// Round 5
// 322.821 us; speedup vs baseline: 3.4060x; 2.1039x over previous
//
#include <hip/hip_runtime.h>
#include <math.h>

constexpr int H = 64;

typedef __attribute__((ext_vector_type(8))) short bf16x8;
typedef __attribute__((ext_vector_type(4))) float f32x4;

__device__ inline unsigned short f2bf(float f) {
  union { float f; unsigned int u; } c; c.f = f;
  unsigned int u = c.u;
  return (unsigned short)((u + 0x7FFF + ((u >> 16) & 1)) >> 16);  // RNE
}
__device__ inline float bf2f(unsigned short s) {
  union { unsigned int u; float f; } c; c.u = ((unsigned int)s) << 16;
  return c.f;
}

// ---- CSR build ----
__global__ void k_hist(const int* __restrict__ dst, int* __restrict__ hist, int E) {
  int e = blockIdx.x * blockDim.x + threadIdx.x;
  if (e < E) atomicAdd(&hist[dst[e]], 1);
}

__global__ void k_scan1(const int* __restrict__ hist, int* __restrict__ bsum, int n) {
  __shared__ int sred[256];
  int tid = threadIdx.x;
  int base = blockIdx.x * 1024 + tid * 4;
  int s = 0;
#pragma unroll
  for (int k = 0; k < 4; ++k) { int i = base + k; if (i < n) s += hist[i]; }
  sred[tid] = s;
  __syncthreads();
  for (int d = 128; d > 0; d >>= 1) {
    if (tid < d) sred[tid] += sred[tid + d];
    __syncthreads();
  }
  if (tid == 0) bsum[blockIdx.x] = sred[0];
}

__global__ void k_scan2(int* __restrict__ bsum, int nb) {
  __shared__ int sd[1024];
  int tid = threadIdx.x;
  int v = (tid < nb) ? bsum[tid] : 0;
  sd[tid] = v;
  __syncthreads();
  for (int d = 1; d < 1024; d <<= 1) {
    int t = (tid >= d) ? sd[tid - d] : 0;
    __syncthreads();
    sd[tid] += t;
    __syncthreads();
  }
  if (tid < nb) bsum[tid] = sd[tid] - v;
}

__global__ void k_scan3(const int* __restrict__ hist, const int* __restrict__ bsum,
                        int* __restrict__ row_ptr, int* __restrict__ pos,
                        float* __restrict__ degf, int n) {
  __shared__ int sth[256];
  int tid = threadIdx.x;
  int base = blockIdx.x * 1024 + tid * 4;
  int v[4]; int s = 0;
#pragma unroll
  for (int k = 0; k < 4; ++k) { int i = base + k; v[k] = (i < n) ? hist[i] : 0; s += v[k]; }
  sth[tid] = s;
  __syncthreads();
  for (int d = 1; d < 256; d <<= 1) {
    int t = (tid >= d) ? sth[tid - d] : 0;
    __syncthreads();
    sth[tid] += t;
    __syncthreads();
  }
  int run = bsum[blockIdx.x] + sth[tid] - s;
  if (blockIdx.x == 0 && tid == 0) row_ptr[0] = 0;
#pragma unroll
  for (int k = 0; k < 4; ++k) {
    int i = base + k;
    if (i < n) {
      pos[i] = run;
      degf[i] = (float)(v[k] > 1 ? v[k] : 1);
      run += v[k];
      row_ptr[i + 1] = run;
    }
  }
}

__global__ void k_scatter(const int* __restrict__ src, const int* __restrict__ dst,
                          const float* __restrict__ ea, int* __restrict__ pos,
                          int* __restrict__ ssrc, float* __restrict__ sea, int E) {
  int e = blockIdx.x * blockDim.x + threadIdx.x;
  if (e < E) {
    int d = dst[e];
    int p = atomicAdd(&pos[d], 1);
    ssrc[p] = src[e];
    sea[2 * p]     = ea[2 * e];
    sea[2 * p + 1] = ea[2 * e + 1];
  }
}

// ---- weight prep: WmT[l][64][64] = Wm1^T (bf16), WuT[l][64][128] = Wu^T (bf16) ----
__global__ void k_wprep(const float* __restrict__ Wmsg, const float* __restrict__ Wupd,
                        unsigned short* __restrict__ WmT, unsigned short* __restrict__ WuT) {
  int l = blockIdx.x;
  const float* Wm = Wmsg + (size_t)l * 66 * 64;   // [66][64]; rows 0..63 = h part
  const float* Wu = Wupd + (size_t)l * 128 * 64;  // [128][64]
  unsigned short* wmt = WmT + (size_t)l * 64 * 64;
  unsigned short* wut = WuT + (size_t)l * 64 * 128;
  for (int i = threadIdx.x; i < 64 * 64; i += blockDim.x) {
    int j = i >> 6, k = i & 63;
    wmt[i] = f2bf(Wm[k * 64 + j]);     // wmt[j][k]
  }
  for (int i = threadIdx.x; i < 64 * 128; i += blockDim.x) {
    int j = i >> 7, k = i & 127;
    wut[i] = f2bf(Wu[k * 64 + j]);     // wut[j][k]
  }
}

// ---- input projection -> bf16 hb ----
__global__ void k_inproj(const float* __restrict__ x, const float* __restrict__ Win,
                         const float* __restrict__ bin, unsigned short* __restrict__ hb, int n) {
  int t = blockIdx.x * blockDim.x + threadIdx.x;
  int v = t >> 6, j = t & 63;
  if (v < n) {
    float x0 = x[2 * v], x1 = x[2 * v + 1];
    hb[(size_t)v * H + j] = f2bf(fmaf(x0, Win[j], fmaf(x1, Win[H + j], bin[j])));
  }
}

// ---- g = bf16(hb @ Wm1): MFMA, one wave per 16-node tile ----
__global__ void k_gemm_mfma(const unsigned short* __restrict__ hb,
                            const unsigned short* __restrict__ wmt,  // [64][64] (j,k)
                            unsigned short* __restrict__ g, int n) {
  int lane = threadIdx.x & 63;
  int wv = blockIdx.x * (blockDim.x >> 6) + (threadIdx.x >> 6);
  int v0 = wv * 16;
  if (v0 >= n) return;
  int r16 = lane & 15, hi = lane >> 4;
  bf16x8 bfr[2][4];
#pragma unroll
  for (int ks = 0; ks < 2; ++ks)
#pragma unroll
    for (int jt = 0; jt < 4; ++jt)
      bfr[ks][jt] = *(const bf16x8*)(wmt + (jt * 16 + r16) * 64 + ks * 32 + hi * 8);
  bf16x8 afr[2];
  int row = v0 + r16;
  if (row < n) {
    const unsigned short* arow = hb + (size_t)row * H + hi * 8;
    afr[0] = *(const bf16x8*)(arow);
    afr[1] = *(const bf16x8*)(arow + 32);
  } else {
    afr[0] = (bf16x8){0,0,0,0,0,0,0,0};
    afr[1] = (bf16x8){0,0,0,0,0,0,0,0};
  }
  f32x4 acc[4] = {};
#pragma unroll
  for (int ks = 0; ks < 2; ++ks)
#pragma unroll
    for (int jt = 0; jt < 4; ++jt)
      acc[jt] = __builtin_amdgcn_mfma_f32_16x16x32_bf16(afr[ks], bfr[ks][jt], acc[jt], 0, 0, 0);
#pragma unroll
  for (int jt = 0; jt < 4; ++jt) {
    int col = jt * 16 + r16;
#pragma unroll
    for (int r = 0; r < 4; ++r) {
      int orow = v0 + hi * 4 + r;
      if (orow < n) g[(size_t)orow * H + col] = f2bf(acc[jt][r]);
    }
  }
}

// ---- aggregation: zero LDS, deep gather pipeline, bf16 in/out ----
__global__ void k_agg(const unsigned short* __restrict__ g, const int* __restrict__ row_ptr,
                      const int* __restrict__ ssrc, const float2* __restrict__ sea2,
                      const float* __restrict__ degf,
                      const float* __restrict__ Wm2, const float* __restrict__ bm,
                      unsigned short* __restrict__ aggb, int n) {
  int t = blockIdx.x * blockDim.x + threadIdx.x;
  int v = t >> 6, j = t & 63;
  if (v >= n) return;
  float w2a = Wm2[j], w2b = Wm2[64 + j], bmj = bm[j];
  int beg = row_ptr[v], end = row_ptr[v + 1];
  float acc = 0.f;
  int i = beg;
  if (i + 3 < end) {
    int sA0 = ssrc[i], sA1 = ssrc[i + 1], sA2 = ssrc[i + 2], sA3 = ssrc[i + 3];
    for (; i + 7 < end; i += 4) {
      int sB0 = ssrc[i + 4], sB1 = ssrc[i + 5], sB2 = ssrc[i + 6], sB3 = ssrc[i + 7];
      float g0 = bf2f(g[(size_t)sA0 * H + j]);
      float g1 = bf2f(g[(size_t)sA1 * H + j]);
      float g2 = bf2f(g[(size_t)sA2 * H + j]);
      float g3 = bf2f(g[(size_t)sA3 * H + j]);
      float2 e0 = sea2[i], e1 = sea2[i + 1], e2 = sea2[i + 2], e3 = sea2[i + 3];
      acc += fmaxf(fmaf(e0.x, w2a, fmaf(e0.y, w2b, g0 + bmj)), 0.f)
           + fmaxf(fmaf(e1.x, w2a, fmaf(e1.y, w2b, g1 + bmj)), 0.f)
           + fmaxf(fmaf(e2.x, w2a, fmaf(e2.y, w2b, g2 + bmj)), 0.f)
           + fmaxf(fmaf(e3.x, w2a, fmaf(e3.y, w2b, g3 + bmj)), 0.f);
      sA0 = sB0; sA1 = sB1; sA2 = sB2; sA3 = sB3;
    }
    float g0 = bf2f(g[(size_t)sA0 * H + j]);
    float g1 = bf2f(g[(size_t)sA1 * H + j]);
    float g2 = bf2f(g[(size_t)sA2 * H + j]);
    float g3 = bf2f(g[(size_t)sA3 * H + j]);
    float2 e0 = sea2[i], e1 = sea2[i + 1], e2 = sea2[i + 2], e3 = sea2[i + 3];
    acc += fmaxf(fmaf(e0.x, w2a, fmaf(e0.y, w2b, g0 + bmj)), 0.f)
         + fmaxf(fmaf(e1.x, w2a, fmaf(e1.y, w2b, g1 + bmj)), 0.f)
         + fmaxf(fmaf(e2.x, w2a, fmaf(e2.y, w2b, g2 + bmj)), 0.f)
         + fmaxf(fmaf(e3.x, w2a, fmaf(e3.y, w2b, g3 + bmj)), 0.f);
    i += 4;
  }
  for (; i < end; ++i) {
    int s0 = ssrc[i];
    float2 e0 = sea2[i];
    acc += fmaxf(fmaf(e0.x, w2a, fmaf(e0.y, w2b, bf2f(g[(size_t)s0 * H + j]) + bmj)), 0.f);
  }
  aggb[(size_t)v * H + j] = f2bf(acc / degf[v]);
}

// ---- update MLP via MFMA: hb = relu([hb || aggb] @ Wu + bu); optional fp32 out ----
__global__ void k_upd_mfma(const unsigned short* __restrict__ hb,
                           const unsigned short* __restrict__ aggb,
                           const unsigned short* __restrict__ wut,  // [64][128] (j,k)
                           const float* __restrict__ bu,
                           unsigned short* __restrict__ hb_out,
                           float* __restrict__ hout, int n) {
  int lane = threadIdx.x & 63;
  int wv = blockIdx.x * (blockDim.x >> 6) + (threadIdx.x >> 6);
  int v0 = wv * 16;
  if (v0 >= n) return;
  int r16 = lane & 15, hi = lane >> 4;
  bf16x8 bfr[4][4];
#pragma unroll
  for (int ks = 0; ks < 4; ++ks)
#pragma unroll
    for (int jt = 0; jt < 4; ++jt)
      bfr[ks][jt] = *(const bf16x8*)(wut + (jt * 16 + r16) * 128 + ks * 32 + hi * 8);
  f32x4 acc[4];
#pragma unroll
  for (int jt = 0; jt < 4; ++jt) {
    float b = bu[jt * 16 + r16];
    acc[jt] = (f32x4){b, b, b, b};
  }
  bf16x8 afr[4];
  int row = v0 + r16;
  if (row < n) {
    const unsigned short* hrow = hb   + (size_t)row * H + hi * 8;
    const unsigned short* arow = aggb + (size_t)row * H + hi * 8;
    afr[0] = *(const bf16x8*)(hrow);
    afr[1] = *(const bf16x8*)(hrow + 32);
    afr[2] = *(const bf16x8*)(arow);
    afr[3] = *(const bf16x8*)(arow + 32);
  } else {
    afr[0] = afr[1] = afr[2] = afr[3] = (bf16x8){0,0,0,0,0,0,0,0};
  }
#pragma unroll
  for (int ks = 0; ks < 4; ++ks)
#pragma unroll
    for (int jt = 0; jt < 4; ++jt)
      acc[jt] = __builtin_amdgcn_mfma_f32_16x16x32_bf16(afr[ks], bfr[ks][jt], acc[jt], 0, 0, 0);
#pragma unroll
  for (int jt = 0; jt < 4; ++jt) {
    int col = jt * 16 + r16;
#pragma unroll
    for (int r = 0; r < 4; ++r) {
      int orow = v0 + hi * 4 + r;
      if (orow < n) {
        float o = fmaxf(acc[jt][r], 0.f);
        hb_out[(size_t)orow * H + col] = f2bf(o);
        if (hout) hout[(size_t)orow * H + col] = o;
      }
    }
  }
}

// ---- node head (reads fp32 h) + atomic hsum[64] ----
__global__ void k_head(const float* __restrict__ h, const float* __restrict__ Wn,
                       const float* __restrict__ bn, float* __restrict__ probs,
                       float* __restrict__ hsum, int n) {
  __shared__ float red[256];
  int j = threadIdx.x & 63;
  int gw = blockIdx.x * (blockDim.x >> 6) + (threadIdx.x >> 6);
  int nw = gridDim.x * (blockDim.x >> 6);
  float wj = Wn[j], b0 = bn[0];
  float psum = 0.f;
  for (int v = gw; v < n; v += nw) {
    float hv = h[(size_t)v * H + j];
    psum += hv;
    float t = hv * wj;
#pragma unroll
    for (int d = 32; d > 0; d >>= 1) t += __shfl_down(t, d);
    if (j == 0) probs[v] = 1.f / (1.f + expf(-(t + b0)));
  }
  red[threadIdx.x] = psum;
  __syncthreads();
  if (threadIdx.x < 64) {
    float t = red[threadIdx.x] + red[threadIdx.x + 64] +
              red[threadIdx.x + 128] + red[threadIdx.x + 192];
    atomicAdd(&hsum[threadIdx.x], t);
  }
}

__global__ void k_final(const float* __restrict__ hsum,
                        const float* __restrict__ W1, const float* __restrict__ b1,
                        const float* __restrict__ W2, const float* __restrict__ b2,
                        float* __restrict__ out4, float n_nodes) {
  __shared__ float hmean[64];
  __shared__ float z1[32];
  int tid = threadIdx.x;
  if (tid < 64) hmean[tid] = hsum[tid] / n_nodes;
  __syncthreads();
  if (tid < 32) {
    float a = b1[tid];
    for (int k = 0; k < 64; ++k) a = fmaf(hmean[k], W1[k * 32 + tid], a);
    z1[tid] = fmaxf(a, 0.f);
  }
  __syncthreads();
  if (tid < 4) {
    float a = b2[tid];
    for (int k = 0; k < 32; ++k) a = fmaf(z1[k], W2[k * 4 + tid], a);
    out4[tid] = a;
  }
}

extern "C" void kernel_launch(void* const* d_in, const int* in_sizes, int n_in,
                              void* d_out, int out_size, void* d_ws, size_t ws_size,
                              hipStream_t stream) {
  const float* x    = (const float*)d_in[0];
  const int*   ei   = (const int*)d_in[1];
  const float* ea   = (const float*)d_in[2];
  const float* Win  = (const float*)d_in[3];
  const float* bin  = (const float*)d_in[4];
  const float* Wmsg = (const float*)d_in[5];
  const float* bmsg = (const float*)d_in[6];
  const float* Wupd = (const float*)d_in[7];
  const float* bupd = (const float*)d_in[8];
  const float* Wn   = (const float*)d_in[9];
  const float* bn   = (const float*)d_in[10];
  const float* W1   = (const float*)d_in[13];
  const float* b1   = (const float*)d_in[14];
  const float* W2   = (const float*)d_in[15];
  const float* b2   = (const float*)d_in[16];

  const int N = in_sizes[0] / 2;
  const int E = in_sizes[1] / 2;
  const int* src = ei;
  const int* dst = ei + E;

  char* ws = (char*)d_ws;
  size_t off = 0;
  auto alloc = [&](size_t bytes) {
    void* p = ws + off;
    off = (off + bytes + 255) & ~(size_t)255;
    return p;
  };
  int*   hist = (int*)  alloc((size_t)N * 4);
  int*   rptr = (int*)  alloc((size_t)(N + 1) * 4);
  int*   pos  = (int*)  alloc((size_t)N * 4);
  float* degf = (float*)alloc((size_t)N * 4);
  int*   bsum = (int*)  alloc((size_t)1024 * 4);
  int*   ssrc = (int*)  alloc((size_t)E * 4);
  float* sea  = (float*)alloc((size_t)E * 8);
  unsigned short* hb   = (unsigned short*)alloc((size_t)N * H * 2);
  unsigned short* g    = (unsigned short*)alloc((size_t)N * H * 2);
  unsigned short* aggb = (unsigned short*)alloc((size_t)N * H * 2);
  unsigned short* WmT  = (unsigned short*)alloc((size_t)3 * 64 * 64 * 2);
  unsigned short* WuT  = (unsigned short*)alloc((size_t)3 * 64 * 128 * 2);
  float* hsum = (float*)alloc(64 * 4);
  (void)ws_size;

  float* probs = (float*)d_out;          // [N]
  float* out4  = probs + N;              // [4]
  float* h     = out4 + 4;               // [N, 64] fp32 final output

  hipMemsetAsync(hist, 0, (size_t)N * 4, stream);
  hipMemsetAsync(hsum, 0, 64 * 4, stream);
  int eb = (E + 255) / 256;
  int sb = (N + 1023) / 1024;
  k_hist<<<eb, 256, 0, stream>>>(dst, hist, E);
  k_scan1<<<sb, 256, 0, stream>>>(hist, bsum, N);
  k_scan2<<<1, 1024, 0, stream>>>(bsum, sb);
  k_scan3<<<sb, 256, 0, stream>>>(hist, bsum, rptr, pos, degf, N);
  k_scatter<<<eb, 256, 0, stream>>>(src, dst, ea, pos, ssrc, sea, E);
  k_wprep<<<3, 256, 0, stream>>>(Wmsg, Wupd, WmT, WuT);

  k_inproj<<<(N * 64 + 255) / 256, 256, 0, stream>>>(x, Win, bin, hb, N);

  int tiles = (N + 15) / 16;
  int mb = (tiles + 3) / 4;          // 4 waves/block, one 16-node tile per wave
  int nb = (N + 3) / 4;              // k_agg: one wave per node
  for (int l = 0; l < 3; ++l) {
    k_gemm_mfma<<<mb, 256, 0, stream>>>(hb, WmT + (size_t)l * 64 * 64, g, N);
    k_agg<<<nb, 256, 0, stream>>>(g, rptr, ssrc, (const float2*)sea, degf,
                                  Wmsg + (size_t)l * 66 * 64 + 64 * 64,
                                  bmsg + (size_t)l * 64, aggb, N);
    k_upd_mfma<<<mb, 256, 0, stream>>>(hb, aggb, WuT + (size_t)l * 64 * 128,
                                       bupd + (size_t)l * 64, hb,
                                       (l == 2) ? h : nullptr, N);
  }

  k_head<<<512, 256, 0, stream>>>(h, Wn, bn, probs, hsum, N);
  k_final<<<1, 64, 0, stream>>>(hsum, W1, b1, W2, b2, out4, (float)N);
}

// Round 6
// 293.741 us; speedup vs baseline: 3.7432x; 1.0990x over previous
//
#include <hip/hip_runtime.h>
#include <math.h>

constexpr int H = 64;

typedef __attribute__((ext_vector_type(8))) short bf16x8;
typedef __attribute__((ext_vector_type(4))) float f32x4;

__device__ inline unsigned short f2bf(float f) {
  union { float f; unsigned int u; } c; c.f = f;
  unsigned int u = c.u;
  return (unsigned short)((u + 0x7FFF + ((u >> 16) & 1)) >> 16);  // RNE
}
__device__ inline float bf2f(unsigned int s) {
  union { unsigned int u; float f; } c; c.u = s << 16;
  return c.f;
}

// ---- CSR build ----
__global__ void k_hist(const int* __restrict__ dst, int* __restrict__ hist, int E) {
  int e = blockIdx.x * blockDim.x + threadIdx.x;
  if (e < E) atomicAdd(&hist[dst[e]], 1);
}

__global__ void k_scan1(const int* __restrict__ hist, int* __restrict__ bsum, int n) {
  __shared__ int sred[256];
  int tid = threadIdx.x;
  int base = blockIdx.x * 1024 + tid * 4;
  int s = 0;
#pragma unroll
  for (int k = 0; k < 4; ++k) { int i = base + k; if (i < n) s += hist[i]; }
  sred[tid] = s;
  __syncthreads();
  for (int d = 128; d > 0; d >>= 1) {
    if (tid < d) sred[tid] += sred[tid + d];
    __syncthreads();
  }
  if (tid == 0) bsum[blockIdx.x] = sred[0];
}

__global__ void k_scan2(int* __restrict__ bsum, int nb) {
  __shared__ int sd[1024];
  int tid = threadIdx.x;
  int v = (tid < nb) ? bsum[tid] : 0;
  sd[tid] = v;
  __syncthreads();
  for (int d = 1; d < 1024; d <<= 1) {
    int t = (tid >= d) ? sd[tid - d] : 0;
    __syncthreads();
    sd[tid] += t;
    __syncthreads();
  }
  if (tid < nb) bsum[tid] = sd[tid] - v;
}

__global__ void k_scan3(const int* __restrict__ hist, const int* __restrict__ bsum,
                        int* __restrict__ row_ptr, int* __restrict__ pos, int n) {
  __shared__ int sth[256];
  int tid = threadIdx.x;
  int base = blockIdx.x * 1024 + tid * 4;
  int v[4]; int s = 0;
#pragma unroll
  for (int k = 0; k < 4; ++k) { int i = base + k; v[k] = (i < n) ? hist[i] : 0; s += v[k]; }
  sth[tid] = s;
  __syncthreads();
  for (int d = 1; d < 256; d <<= 1) {
    int t = (tid >= d) ? sth[tid - d] : 0;
    __syncthreads();
    sth[tid] += t;
    __syncthreads();
  }
  int run = bsum[blockIdx.x] + sth[tid] - s;
  if (blockIdx.x == 0 && tid == 0) row_ptr[0] = 0;
#pragma unroll
  for (int k = 0; k < 4; ++k) {
    int i = base + k;
    if (i < n) {
      pos[i] = run;
      run += v[k];
      row_ptr[i + 1] = run;
    }
  }
}

// ---- scatter: ONE 8B record per edge {src, ea as 2xbf16} ----
__global__ void k_scatter(const int* __restrict__ src, const int* __restrict__ dst,
                          const float* __restrict__ ea, int* __restrict__ pos,
                          uint2* __restrict__ erec, int E) {
  int e = blockIdx.x * blockDim.x + threadIdx.x;
  if (e < E) {
    int d = dst[e];
    int p = atomicAdd(&pos[d], 1);
    unsigned int lo = f2bf(ea[2 * e]);
    unsigned int hi = f2bf(ea[2 * e + 1]);
    erec[p] = make_uint2((unsigned int)src[e], lo | (hi << 16));
  }
}

// ---- input projection -> bf16 hb ----
__global__ void k_inproj(const float* __restrict__ x, const float* __restrict__ Win,
                         const float* __restrict__ bin, unsigned short* __restrict__ hb, int n) {
  int t = blockIdx.x * blockDim.x + threadIdx.x;
  int v = t >> 6, j = t & 63;
  if (v < n) {
    float x0 = x[2 * v], x1 = x[2 * v + 1];
    hb[(size_t)v * H + j] = f2bf(fmaf(x0, Win[j], fmaf(x1, Win[H + j], bin[j])));
  }
}

// ---- weight prep: WmT[l][64][64] = Wm1^T (bf16), WuT[l][64][128] = Wu^T (bf16) ----
__global__ void k_wprep(const float* __restrict__ Wmsg, const float* __restrict__ Wupd,
                        unsigned short* __restrict__ WmT, unsigned short* __restrict__ WuT) {
  int l = blockIdx.x;
  const float* Wm = Wmsg + (size_t)l * 66 * 64;
  const float* Wu = Wupd + (size_t)l * 128 * 64;
  unsigned short* wmt = WmT + (size_t)l * 64 * 64;
  unsigned short* wut = WuT + (size_t)l * 64 * 128;
  for (int i = threadIdx.x; i < 64 * 64; i += blockDim.x) {
    int j = i >> 6, k = i & 63;
    wmt[i] = f2bf(Wm[k * 64 + j]);
  }
  for (int i = threadIdx.x; i < 64 * 128; i += blockDim.x) {
    int j = i >> 7, k = i & 127;
    wut[i] = f2bf(Wu[k * 64 + j]);
  }
}

// ---- g = bf16(hb @ Wm1): MFMA, one wave per 16-node tile ----
__global__ void k_gemm_mfma(const unsigned short* __restrict__ hb,
                            const unsigned short* __restrict__ wmt,
                            unsigned short* __restrict__ g, int n) {
  int lane = threadIdx.x & 63;
  int wv = blockIdx.x * (blockDim.x >> 6) + (threadIdx.x >> 6);
  int v0 = wv * 16;
  if (v0 >= n) return;
  int r16 = lane & 15, hi = lane >> 4;
  bf16x8 bfr[2][4];
#pragma unroll
  for (int ks = 0; ks < 2; ++ks)
#pragma unroll
    for (int jt = 0; jt < 4; ++jt)
      bfr[ks][jt] = *(const bf16x8*)(wmt + (jt * 16 + r16) * 64 + ks * 32 + hi * 8);
  bf16x8 afr[2];
  int row = v0 + r16;
  if (row < n) {
    const unsigned short* arow = hb + (size_t)row * H + hi * 8;
    afr[0] = *(const bf16x8*)(arow);
    afr[1] = *(const bf16x8*)(arow + 32);
  } else {
    afr[0] = (bf16x8){0,0,0,0,0,0,0,0};
    afr[1] = (bf16x8){0,0,0,0,0,0,0,0};
  }
  f32x4 acc[4] = {};
#pragma unroll
  for (int ks = 0; ks < 2; ++ks)
#pragma unroll
    for (int jt = 0; jt < 4; ++jt)
      acc[jt] = __builtin_amdgcn_mfma_f32_16x16x32_bf16(afr[ks], bfr[ks][jt], acc[jt], 0, 0, 0);
#pragma unroll
  for (int jt = 0; jt < 4; ++jt) {
    int col = jt * 16 + r16;
#pragma unroll
    for (int r = 0; r < 4; ++r) {
      int orow = v0 + hi * 4 + r;
      if (orow < n) g[(size_t)orow * H + col] = f2bf(acc[jt][r]);
    }
  }
}

// ---- aggregation: 4 feats/lane x 4 edges/wave, 8B records, 8B gathers ----
__global__ void k_agg(const unsigned short* __restrict__ g, const int* __restrict__ row_ptr,
                      const uint2* __restrict__ erec,
                      const float* __restrict__ Wm2, const float* __restrict__ bm,
                      unsigned short* __restrict__ aggb, int n) {
  int t = blockIdx.x * blockDim.x + threadIdx.x;
  int v = t >> 6, lane = t & 63;
  if (v >= n) return;
  int r = lane & 15, grp = lane >> 4;
  int j0 = r * 4;
  float4 w2a = *(const float4*)(Wm2 + j0);
  float4 w2b = *(const float4*)(Wm2 + 64 + j0);
  float4 bm4 = *(const float4*)(bm + j0);
  int beg = row_ptr[v], end = row_ptr[v + 1];
  float a0 = 0.f, a1 = 0.f, a2 = 0.f, a3 = 0.f;
  int i = beg + grp;
  for (; i + 4 < end; i += 8) {  // 2 independent gather chains per iteration
    uint2 rA = erec[i], rB = erec[i + 4];
    uint2 gwA = *(const uint2*)(g + (size_t)rA.x * H + j0);
    uint2 gwB = *(const uint2*)(g + (size_t)rB.x * H + j0);
    float eA0 = bf2f(rA.y & 0xffffu), eA1 = bf2f(rA.y >> 16);
    float eB0 = bf2f(rB.y & 0xffffu), eB1 = bf2f(rB.y >> 16);
    a0 += fmaxf(fmaf(eA0, w2a.x, fmaf(eA1, w2b.x, bf2f(gwA.x & 0xffffu) + bm4.x)), 0.f)
        + fmaxf(fmaf(eB0, w2a.x, fmaf(eB1, w2b.x, bf2f(gwB.x & 0xffffu) + bm4.x)), 0.f);
    a1 += fmaxf(fmaf(eA0, w2a.y, fmaf(eA1, w2b.y, bf2f(gwA.x >> 16)      + bm4.y)), 0.f)
        + fmaxf(fmaf(eB0, w2a.y, fmaf(eB1, w2b.y, bf2f(gwB.x >> 16)      + bm4.y)), 0.f);
    a2 += fmaxf(fmaf(eA0, w2a.z, fmaf(eA1, w2b.z, bf2f(gwA.y & 0xffffu) + bm4.z)), 0.f)
        + fmaxf(fmaf(eB0, w2a.z, fmaf(eB1, w2b.z, bf2f(gwB.y & 0xffffu) + bm4.z)), 0.f);
    a3 += fmaxf(fmaf(eA0, w2a.w, fmaf(eA1, w2b.w, bf2f(gwA.y >> 16)      + bm4.w)), 0.f)
        + fmaxf(fmaf(eB0, w2a.w, fmaf(eB1, w2b.w, bf2f(gwB.y >> 16)      + bm4.w)), 0.f);
  }
  if (i < end) {
    uint2 rA = erec[i];
    uint2 gwA = *(const uint2*)(g + (size_t)rA.x * H + j0);
    float eA0 = bf2f(rA.y & 0xffffu), eA1 = bf2f(rA.y >> 16);
    a0 += fmaxf(fmaf(eA0, w2a.x, fmaf(eA1, w2b.x, bf2f(gwA.x & 0xffffu) + bm4.x)), 0.f);
    a1 += fmaxf(fmaf(eA0, w2a.y, fmaf(eA1, w2b.y, bf2f(gwA.x >> 16)      + bm4.y)), 0.f);
    a2 += fmaxf(fmaf(eA0, w2a.z, fmaf(eA1, w2b.z, bf2f(gwA.y & 0xffffu) + bm4.z)), 0.f);
    a3 += fmaxf(fmaf(eA0, w2a.w, fmaf(eA1, w2b.w, bf2f(gwA.y >> 16)      + bm4.w)), 0.f);
  }
  // reduce across the 4 groups
  a0 += __shfl_xor(a0, 16); a0 += __shfl_xor(a0, 32);
  a1 += __shfl_xor(a1, 16); a1 += __shfl_xor(a1, 32);
  a2 += __shfl_xor(a2, 16); a2 += __shfl_xor(a2, 32);
  a3 += __shfl_xor(a3, 16); a3 += __shfl_xor(a3, 32);
  if (grp == 0) {
    float inv = 1.f / fmaxf((float)(end - beg), 1.f);
    unsigned int p0 = f2bf(a0 * inv) | ((unsigned int)f2bf(a1 * inv) << 16);
    unsigned int p1 = f2bf(a2 * inv) | ((unsigned int)f2bf(a3 * inv) << 16);
    *(uint2*)(aggb + (size_t)v * H + j0) = make_uint2(p0, p1);
  }
}

// ---- update MLP via MFMA ----
__global__ void k_upd_mfma(const unsigned short* __restrict__ hb,
                           const unsigned short* __restrict__ aggb,
                           const unsigned short* __restrict__ wut,
                           const float* __restrict__ bu,
                           unsigned short* __restrict__ hb_out,
                           float* __restrict__ hout, int n) {
  int lane = threadIdx.x & 63;
  int wv = blockIdx.x * (blockDim.x >> 6) + (threadIdx.x >> 6);
  int v0 = wv * 16;
  if (v0 >= n) return;
  int r16 = lane & 15, hi = lane >> 4;
  bf16x8 bfr[4][4];
#pragma unroll
  for (int ks = 0; ks < 4; ++ks)
#pragma unroll
    for (int jt = 0; jt < 4; ++jt)
      bfr[ks][jt] = *(const bf16x8*)(wut + (jt * 16 + r16) * 128 + ks * 32 + hi * 8);
  f32x4 acc[4];
#pragma unroll
  for (int jt = 0; jt < 4; ++jt) {
    float b = bu[jt * 16 + r16];
    acc[jt] = (f32x4){b, b, b, b};
  }
  bf16x8 afr[4];
  int row = v0 + r16;
  if (row < n) {
    const unsigned short* hrow = hb   + (size_t)row * H + hi * 8;
    const unsigned short* arow = aggb + (size_t)row * H + hi * 8;
    afr[0] = *(const bf16x8*)(hrow);
    afr[1] = *(const bf16x8*)(hrow + 32);
    afr[2] = *(const bf16x8*)(arow);
    afr[3] = *(const bf16x8*)(arow + 32);
  } else {
    afr[0] = afr[1] = afr[2] = afr[3] = (bf16x8){0,0,0,0,0,0,0,0};
  }
#pragma unroll
  for (int ks = 0; ks < 4; ++ks)
#pragma unroll
    for (int jt = 0; jt < 4; ++jt)
      acc[jt] = __builtin_amdgcn_mfma_f32_16x16x32_bf16(afr[ks], bfr[ks][jt], acc[jt], 0, 0, 0);
#pragma unroll
  for (int jt = 0; jt < 4; ++jt) {
    int col = jt * 16 + r16;
#pragma unroll
    for (int r = 0; r < 4; ++r) {
      int orow = v0 + hi * 4 + r;
      if (orow < n) {
        float o = fmaxf(acc[jt][r], 0.f);
        hb_out[(size_t)orow * H + col] = f2bf(o);
        if (hout) hout[(size_t)orow * H + col] = o;
      }
    }
  }
}

// ---- node head (sigmoid) + atomic hsum[64] ----
__global__ void k_head(const float* __restrict__ h, const float* __restrict__ Wn,
                       const float* __restrict__ bn, float* __restrict__ probs,
                       float* __restrict__ hsum, int n) {
  __shared__ float red[256];
  int j = threadIdx.x & 63;
  int gw = blockIdx.x * (blockDim.x >> 6) + (threadIdx.x >> 6);
  int nw = gridDim.x * (blockDim.x >> 6);
  float wj = Wn[j], b0 = bn[0];
  float psum = 0.f;
  for (int v = gw; v < n; v += nw) {
    float hv = h[(size_t)v * H + j];
    psum += hv;
    float t = hv * wj;
#pragma unroll
    for (int d = 32; d > 0; d >>= 1) t += __shfl_down(t, d);
    if (j == 0) probs[v] = 1.f / (1.f + expf(-(t + b0)));
  }
  red[threadIdx.x] = psum;
  __syncthreads();
  if (threadIdx.x < 64) {
    float t = red[threadIdx.x] + red[threadIdx.x + 64] +
              red[threadIdx.x + 128] + red[threadIdx.x + 192];
    atomicAdd(&hsum[threadIdx.x], t);
  }
}

__global__ void k_final(const float* __restrict__ hsum,
                        const float* __restrict__ W1, const float* __restrict__ b1,
                        const float* __restrict__ W2, const float* __restrict__ b2,
                        float* __restrict__ out4, float n_nodes) {
  __shared__ float hmean[64];
  __shared__ float z1[32];
  int tid = threadIdx.x;
  if (tid < 64) hmean[tid] = hsum[tid] / n_nodes;
  __syncthreads();
  if (tid < 32) {
    float a = b1[tid];
    for (int k = 0; k < 64; ++k) a = fmaf(hmean[k], W1[k * 32 + tid], a);
    z1[tid] = fmaxf(a, 0.f);
  }
  __syncthreads();
  if (tid < 4) {
    float a = b2[tid];
    for (int k = 0; k < 32; ++k) a = fmaf(z1[k], W2[k * 4 + tid], a);
    out4[tid] = a;
  }
}

extern "C" void kernel_launch(void* const* d_in, const int* in_sizes, int n_in,
                              void* d_out, int out_size, void* d_ws, size_t ws_size,
                              hipStream_t stream) {
  const float* x    = (const float*)d_in[0];
  const int*   ei   = (const int*)d_in[1];
  const float* ea   = (const float*)d_in[2];
  const float* Win  = (const float*)d_in[3];
  const float* bin  = (const float*)d_in[4];
  const float* Wmsg = (const float*)d_in[5];
  const float* bmsg = (const float*)d_in[6];
  const float* Wupd = (const float*)d_in[7];
  const float* bupd = (const float*)d_in[8];
  const float* Wn   = (const float*)d_in[9];
  const float* bn   = (const float*)d_in[10];
  const float* W1   = (const float*)d_in[13];
  const float* b1   = (const float*)d_in[14];
  const float* W2   = (const float*)d_in[15];
  const float* b2   = (const float*)d_in[16];

  const int N = in_sizes[0] / 2;
  const int E = in_sizes[1] / 2;
  const int* src = ei;
  const int* dst = ei + E;

  char* ws = (char*)d_ws;
  size_t off = 0;
  auto alloc = [&](size_t bytes) {
    void* p = ws + off;
    off = (off + bytes + 255) & ~(size_t)255;
    return p;
  };
  int*   hist = (int*)  alloc((size_t)N * 4);
  int*   rptr = (int*)  alloc((size_t)(N + 1) * 4);
  int*   pos  = (int*)  alloc((size_t)N * 4);
  int*   bsum = (int*)  alloc((size_t)1024 * 4);
  uint2* erec = (uint2*)alloc((size_t)E * 8);
  unsigned short* hb   = (unsigned short*)alloc((size_t)N * H * 2);
  unsigned short* g    = (unsigned short*)alloc((size_t)N * H * 2);
  unsigned short* aggb = (unsigned short*)alloc((size_t)N * H * 2);
  unsigned short* WmT  = (unsigned short*)alloc((size_t)3 * 64 * 64 * 2);
  unsigned short* WuT  = (unsigned short*)alloc((size_t)3 * 64 * 128 * 2);
  float* hsum = (float*)alloc(64 * 4);
  (void)ws_size;

  float* probs = (float*)d_out;          // [N]
  float* out4  = probs + N;              // [4]
  float* h     = out4 + 4;               // [N, 64] fp32 final embeddings

  hipMemsetAsync(hist, 0, (size_t)N * 4, stream);
  hipMemsetAsync(hsum, 0, 64 * 4, stream);
  int eb = (E + 255) / 256;
  int sb = (N + 1023) / 1024;
  k_hist<<<eb, 256, 0, stream>>>(dst, hist, E);
  k_scan1<<<sb, 256, 0, stream>>>(hist, bsum, N);
  k_scan2<<<1, 1024, 0, stream>>>(bsum, sb);
  k_scan3<<<sb, 256, 0, stream>>>(hist, bsum, rptr, pos, N);
  k_scatter<<<eb, 256, 0, stream>>>(src, dst, ea, pos, erec, E);
  k_wprep<<<3, 256, 0, stream>>>(Wmsg, Wupd, WmT, WuT);

  k_inproj<<<(N * 64 + 255) / 256, 256, 0, stream>>>(x, Win, bin, hb, N);

  int tiles = (N + 15) / 16;
  int mb = (tiles + 3) / 4;
  int nb = (N + 3) / 4;
  for (int l = 0; l < 3; ++l) {
    k_gemm_mfma<<<mb, 256, 0, stream>>>(hb, WmT + (size_t)l * 64 * 64, g, N);
    k_agg<<<nb, 256, 0, stream>>>(g, rptr, erec,
                                  Wmsg + (size_t)l * 66 * 64 + 64 * 64,
                                  bmsg + (size_t)l * 64, aggb, N);
    k_upd_mfma<<<mb, 256, 0, stream>>>(hb, aggb, WuT + (size_t)l * 64 * 128,
                                       bupd + (size_t)l * 64, hb,
                                       (l == 2) ? h : nullptr, N);
  }

  k_head<<<512, 256, 0, stream>>>(h, Wn, bn, probs, hsum, N);
  k_final<<<1, 64, 0, stream>>>(hsum, W1, b1, W2, b2, out4, (float)N);
}

// Round 7
// 285.545 us; speedup vs baseline: 3.8506x; 1.0287x over previous
//
#include <hip/hip_runtime.h>
#include <math.h>

constexpr int H = 64;

typedef __attribute__((ext_vector_type(8))) short bf16x8;
typedef __attribute__((ext_vector_type(4))) float f32x4;

__device__ inline unsigned short f2bf(float f) {
  union { float f; unsigned int u; } c; c.f = f;
  unsigned int u = c.u;
  return (unsigned short)((u + 0x7FFF + ((u >> 16) & 1)) >> 16);  // RNE
}
__device__ inline float bf2f(unsigned int s) {
  union { unsigned int u; float f; } c; c.u = s << 16;
  return c.f;
}

// ---- CSR build ----
__global__ void k_hist(const int* __restrict__ dst, int* __restrict__ hist, int E) {
  int e = blockIdx.x * blockDim.x + threadIdx.x;
  if (e < E) atomicAdd(&hist[dst[e]], 1);
}

__global__ void k_scan1(const int* __restrict__ hist, int* __restrict__ bsum, int n) {
  __shared__ int sred[256];
  int tid = threadIdx.x;
  int base = blockIdx.x * 1024 + tid * 4;
  int s = 0;
#pragma unroll
  for (int k = 0; k < 4; ++k) { int i = base + k; if (i < n) s += hist[i]; }
  sred[tid] = s;
  __syncthreads();
  for (int d = 128; d > 0; d >>= 1) {
    if (tid < d) sred[tid] += sred[tid + d];
    __syncthreads();
  }
  if (tid == 0) bsum[blockIdx.x] = sred[0];
}

__global__ void k_scan2(int* __restrict__ bsum, int nb) {
  __shared__ int sd[1024];
  int tid = threadIdx.x;
  int v = (tid < nb) ? bsum[tid] : 0;
  sd[tid] = v;
  __syncthreads();
  for (int d = 1; d < 1024; d <<= 1) {
    int t = (tid >= d) ? sd[tid - d] : 0;
    __syncthreads();
    sd[tid] += t;
    __syncthreads();
  }
  if (tid < nb) bsum[tid] = sd[tid] - v;
}

__global__ void k_scan3(const int* __restrict__ hist, const int* __restrict__ bsum,
                        int* __restrict__ row_ptr, int* __restrict__ pos, int n) {
  __shared__ int sth[256];
  int tid = threadIdx.x;
  int base = blockIdx.x * 1024 + tid * 4;
  int v[4]; int s = 0;
#pragma unroll
  for (int k = 0; k < 4; ++k) { int i = base + k; v[k] = (i < n) ? hist[i] : 0; s += v[k]; }
  sth[tid] = s;
  __syncthreads();
  for (int d = 1; d < 256; d <<= 1) {
    int t = (tid >= d) ? sth[tid - d] : 0;
    __syncthreads();
    sth[tid] += t;
    __syncthreads();
  }
  int run = bsum[blockIdx.x] + sth[tid] - s;
  if (blockIdx.x == 0 && tid == 0) row_ptr[0] = 0;
#pragma unroll
  for (int k = 0; k < 4; ++k) {
    int i = base + k;
    if (i < n) {
      pos[i] = run;
      run += v[k];
      row_ptr[i + 1] = run;
    }
  }
}

// ---- scatter: ONE 8B nt-store per edge {src, ea as 2xbf16} ----
__global__ void k_scatter(const int* __restrict__ src, const int* __restrict__ dst,
                          const float* __restrict__ ea, int* __restrict__ pos,
                          unsigned long long* __restrict__ erec, int E) {
  int e = blockIdx.x * blockDim.x + threadIdx.x;
  if (e < E) {
    int d = dst[e];
    int p = atomicAdd(&pos[d], 1);
    unsigned long long lo = f2bf(ea[2 * e]);
    unsigned long long hi = f2bf(ea[2 * e + 1]);
    unsigned long long rec = (unsigned long long)(unsigned int)src[e]
                           | ((lo | (hi << 16)) << 32);
    __builtin_nontemporal_store(rec, &erec[p]);  // bypass L2: let shared L3 merge sectors
  }
}

// ---- input projection -> bf16 hb ----
__global__ void k_inproj(const float* __restrict__ x, const float* __restrict__ Win,
                         const float* __restrict__ bin, unsigned short* __restrict__ hb, int n) {
  int t = blockIdx.x * blockDim.x + threadIdx.x;
  int v = t >> 6, j = t & 63;
  if (v < n) {
    float x0 = x[2 * v], x1 = x[2 * v + 1];
    hb[(size_t)v * H + j] = f2bf(fmaf(x0, Win[j], fmaf(x1, Win[H + j], bin[j])));
  }
}

// ---- weight prep ----
__global__ void k_wprep(const float* __restrict__ Wmsg, const float* __restrict__ Wupd,
                        unsigned short* __restrict__ WmT, unsigned short* __restrict__ WuT) {
  int l = blockIdx.x;
  const float* Wm = Wmsg + (size_t)l * 66 * 64;
  const float* Wu = Wupd + (size_t)l * 128 * 64;
  unsigned short* wmt = WmT + (size_t)l * 64 * 64;
  unsigned short* wut = WuT + (size_t)l * 64 * 128;
  for (int i = threadIdx.x; i < 64 * 64; i += blockDim.x) {
    int j = i >> 6, k = i & 63;
    wmt[i] = f2bf(Wm[k * 64 + j]);
  }
  for (int i = threadIdx.x; i < 64 * 128; i += blockDim.x) {
    int j = i >> 7, k = i & 127;
    wut[i] = f2bf(Wu[k * 64 + j]);
  }
}

// ---- g = bf16(hb @ Wm1): MFMA, one wave per 16-node tile ----
__global__ void k_gemm_mfma(const unsigned short* __restrict__ hb,
                            const unsigned short* __restrict__ wmt,
                            unsigned short* __restrict__ g, int n) {
  int lane = threadIdx.x & 63;
  int wv = blockIdx.x * (blockDim.x >> 6) + (threadIdx.x >> 6);
  int v0 = wv * 16;
  if (v0 >= n) return;
  int r16 = lane & 15, hi = lane >> 4;
  bf16x8 bfr[2][4];
#pragma unroll
  for (int ks = 0; ks < 2; ++ks)
#pragma unroll
    for (int jt = 0; jt < 4; ++jt)
      bfr[ks][jt] = *(const bf16x8*)(wmt + (jt * 16 + r16) * 64 + ks * 32 + hi * 8);
  bf16x8 afr[2];
  int row = v0 + r16;
  if (row < n) {
    const unsigned short* arow = hb + (size_t)row * H + hi * 8;
    afr[0] = *(const bf16x8*)(arow);
    afr[1] = *(const bf16x8*)(arow + 32);
  } else {
    afr[0] = (bf16x8){0,0,0,0,0,0,0,0};
    afr[1] = (bf16x8){0,0,0,0,0,0,0,0};
  }
  f32x4 acc[4] = {};
#pragma unroll
  for (int ks = 0; ks < 2; ++ks)
#pragma unroll
    for (int jt = 0; jt < 4; ++jt)
      acc[jt] = __builtin_amdgcn_mfma_f32_16x16x32_bf16(afr[ks], bfr[ks][jt], acc[jt], 0, 0, 0);
#pragma unroll
  for (int jt = 0; jt < 4; ++jt) {
    int col = jt * 16 + r16;
#pragma unroll
    for (int r = 0; r < 4; ++r) {
      int orow = v0 + hi * 4 + r;
      if (orow < n) g[(size_t)orow * H + col] = f2bf(acc[jt][r]);
    }
  }
}

// ---- aggregation: 4 feats/lane x 4 edge-groups x 4 gather chains ----
__global__ void k_agg(const unsigned short* __restrict__ g, const int* __restrict__ row_ptr,
                      const unsigned long long* __restrict__ erec,
                      const float* __restrict__ Wm2, const float* __restrict__ bm,
                      unsigned short* __restrict__ aggb, int n) {
  int t = blockIdx.x * blockDim.x + threadIdx.x;
  int v = t >> 6, lane = t & 63;
  if (v >= n) return;
  int r = lane & 15, grp = lane >> 4;
  int j0 = r * 4;
  float4 w2a = *(const float4*)(Wm2 + j0);
  float4 w2b = *(const float4*)(Wm2 + 64 + j0);
  float4 bm4 = *(const float4*)(bm + j0);
  int beg = row_ptr[v], end = row_ptr[v + 1];
  float a0 = 0.f, a1 = 0.f, a2 = 0.f, a3 = 0.f;
  int i = beg + grp;
  for (; i + 12 < end; i += 16) {  // 4 independent gather chains
    unsigned long long rA = erec[i], rB = erec[i + 4], rC = erec[i + 8], rD = erec[i + 12];
    uint2 gwA = *(const uint2*)(g + (size_t)(unsigned int)rA * H + j0);
    uint2 gwB = *(const uint2*)(g + (size_t)(unsigned int)rB * H + j0);
    uint2 gwC = *(const uint2*)(g + (size_t)(unsigned int)rC * H + j0);
    uint2 gwD = *(const uint2*)(g + (size_t)(unsigned int)rD * H + j0);
    unsigned int eA = (unsigned int)(rA >> 32), eB = (unsigned int)(rB >> 32);
    unsigned int eC = (unsigned int)(rC >> 32), eD = (unsigned int)(rD >> 32);
    float eA0 = bf2f(eA & 0xffffu), eA1 = bf2f(eA >> 16);
    float eB0 = bf2f(eB & 0xffffu), eB1 = bf2f(eB >> 16);
    float eC0 = bf2f(eC & 0xffffu), eC1 = bf2f(eC >> 16);
    float eD0 = bf2f(eD & 0xffffu), eD1 = bf2f(eD >> 16);
    a0 += fmaxf(fmaf(eA0, w2a.x, fmaf(eA1, w2b.x, bf2f(gwA.x & 0xffffu) + bm4.x)), 0.f)
        + fmaxf(fmaf(eB0, w2a.x, fmaf(eB1, w2b.x, bf2f(gwB.x & 0xffffu) + bm4.x)), 0.f)
        + fmaxf(fmaf(eC0, w2a.x, fmaf(eC1, w2b.x, bf2f(gwC.x & 0xffffu) + bm4.x)), 0.f)
        + fmaxf(fmaf(eD0, w2a.x, fmaf(eD1, w2b.x, bf2f(gwD.x & 0xffffu) + bm4.x)), 0.f);
    a1 += fmaxf(fmaf(eA0, w2a.y, fmaf(eA1, w2b.y, bf2f(gwA.x >> 16) + bm4.y)), 0.f)
        + fmaxf(fmaf(eB0, w2a.y, fmaf(eB1, w2b.y, bf2f(gwB.x >> 16) + bm4.y)), 0.f)
        + fmaxf(fmaf(eC0, w2a.y, fmaf(eC1, w2b.y, bf2f(gwC.x >> 16) + bm4.y)), 0.f)
        + fmaxf(fmaf(eD0, w2a.y, fmaf(eD1, w2b.y, bf2f(gwD.x >> 16) + bm4.y)), 0.f);
    a2 += fmaxf(fmaf(eA0, w2a.z, fmaf(eA1, w2b.z, bf2f(gwA.y & 0xffffu) + bm4.z)), 0.f)
        + fmaxf(fmaf(eB0, w2a.z, fmaf(eB1, w2b.z, bf2f(gwB.y & 0xffffu) + bm4.z)), 0.f)
        + fmaxf(fmaf(eC0, w2a.z, fmaf(eC1, w2b.z, bf2f(gwC.y & 0xffffu) + bm4.z)), 0.f)
        + fmaxf(fmaf(eD0, w2a.z, fmaf(eD1, w2b.z, bf2f(gwD.y & 0xffffu) + bm4.z)), 0.f);
    a3 += fmaxf(fmaf(eA0, w2a.w, fmaf(eA1, w2b.w, bf2f(gwA.y >> 16) + bm4.w)), 0.f)
        + fmaxf(fmaf(eB0, w2a.w, fmaf(eB1, w2b.w, bf2f(gwB.y >> 16) + bm4.w)), 0.f)
        + fmaxf(fmaf(eC0, w2a.w, fmaf(eC1, w2b.w, bf2f(gwC.y >> 16) + bm4.w)), 0.f)
        + fmaxf(fmaf(eD0, w2a.w, fmaf(eD1, w2b.w, bf2f(gwD.y >> 16) + bm4.w)), 0.f);
  }
  for (; i < end; i += 4) {
    unsigned long long rA = erec[i];
    uint2 gwA = *(const uint2*)(g + (size_t)(unsigned int)rA * H + j0);
    unsigned int eA = (unsigned int)(rA >> 32);
    float eA0 = bf2f(eA & 0xffffu), eA1 = bf2f(eA >> 16);
    a0 += fmaxf(fmaf(eA0, w2a.x, fmaf(eA1, w2b.x, bf2f(gwA.x & 0xffffu) + bm4.x)), 0.f);
    a1 += fmaxf(fmaf(eA0, w2a.y, fmaf(eA1, w2b.y, bf2f(gwA.x >> 16) + bm4.y)), 0.f);
    a2 += fmaxf(fmaf(eA0, w2a.z, fmaf(eA1, w2b.z, bf2f(gwA.y & 0xffffu) + bm4.z)), 0.f);
    a3 += fmaxf(fmaf(eA0, w2a.w, fmaf(eA1, w2b.w, bf2f(gwA.y >> 16) + bm4.w)), 0.f);
  }
  a0 += __shfl_xor(a0, 16); a0 += __shfl_xor(a0, 32);
  a1 += __shfl_xor(a1, 16); a1 += __shfl_xor(a1, 32);
  a2 += __shfl_xor(a2, 16); a2 += __shfl_xor(a2, 32);
  a3 += __shfl_xor(a3, 16); a3 += __shfl_xor(a3, 32);
  if (grp == 0) {
    float inv = 1.f / fmaxf((float)(end - beg), 1.f);
    unsigned int p0 = f2bf(a0 * inv) | ((unsigned int)f2bf(a1 * inv) << 16);
    unsigned int p1 = f2bf(a2 * inv) | ((unsigned int)f2bf(a3 * inv) << 16);
    *(uint2*)(aggb + (size_t)v * H + j0) = make_uint2(p0, p1);
  }
}

// ---- update MLP via MFMA; last layer fuses node head + hsum partials ----
__global__ void k_upd_mfma(const unsigned short* __restrict__ hb,
                           const unsigned short* __restrict__ aggb,
                           const unsigned short* __restrict__ wut,
                           const float* __restrict__ bu,
                           unsigned short* __restrict__ hb_out,
                           float* __restrict__ hout,          // non-null on last layer
                           const float* __restrict__ Wn, const float* __restrict__ bn,
                           float* __restrict__ probs, float* __restrict__ hsumP,
                           int n) {
  __shared__ float shsum[64];
  int lane = threadIdx.x & 63;
  int wv = blockIdx.x * (blockDim.x >> 6) + (threadIdx.x >> 6);
  int v0 = wv * 16;
  bool act = v0 < n;
  int r16 = lane & 15, hi = lane >> 4;
  if (hout && threadIdx.x < 64) shsum[threadIdx.x] = 0.f;
  bf16x8 bfr[4][4];
#pragma unroll
  for (int ks = 0; ks < 4; ++ks)
#pragma unroll
    for (int jt = 0; jt < 4; ++jt)
      bfr[ks][jt] = *(const bf16x8*)(wut + (jt * 16 + r16) * 128 + ks * 32 + hi * 8);
  f32x4 acc[4];
#pragma unroll
  for (int jt = 0; jt < 4; ++jt) {
    float b = bu[jt * 16 + r16];
    acc[jt] = (f32x4){b, b, b, b};
  }
  bf16x8 afr[4];
  int row = v0 + r16;
  if (act && row < n) {
    const unsigned short* hrow = hb   + (size_t)row * H + hi * 8;
    const unsigned short* arow = aggb + (size_t)row * H + hi * 8;
    afr[0] = *(const bf16x8*)(hrow);
    afr[1] = *(const bf16x8*)(hrow + 32);
    afr[2] = *(const bf16x8*)(arow);
    afr[3] = *(const bf16x8*)(arow + 32);
  } else {
    afr[0] = afr[1] = afr[2] = afr[3] = (bf16x8){0,0,0,0,0,0,0,0};
  }
#pragma unroll
  for (int ks = 0; ks < 4; ++ks)
#pragma unroll
    for (int jt = 0; jt < 4; ++jt)
      acc[jt] = __builtin_amdgcn_mfma_f32_16x16x32_bf16(afr[ks], bfr[ks][jt], acc[jt], 0, 0, 0);
  float ov[4][4];
#pragma unroll
  for (int jt = 0; jt < 4; ++jt) {
    int col = jt * 16 + r16;
#pragma unroll
    for (int r = 0; r < 4; ++r) {
      int orow = v0 + hi * 4 + r;
      bool ok = act && orow < n;
      float o = fmaxf(acc[jt][r], 0.f);
      ov[jt][r] = ok ? o : 0.f;
      if (ok) {
        hb_out[(size_t)orow * H + col] = f2bf(o);
        if (hout) hout[(size_t)orow * H + col] = o;
      }
    }
  }
  if (hout) {
    // node logits: dot(h_row, Wn) — reduce cols across the 16-lane group
    float bn0 = bn[0];
    float lg[4] = {0.f, 0.f, 0.f, 0.f};
#pragma unroll
    for (int jt = 0; jt < 4; ++jt) {
      float w = Wn[jt * 16 + r16];
#pragma unroll
      for (int r = 0; r < 4; ++r) lg[r] = fmaf(ov[jt][r], w, lg[r]);
    }
#pragma unroll
    for (int d = 1; d < 16; d <<= 1) {
#pragma unroll
      for (int r = 0; r < 4; ++r) lg[r] += __shfl_xor(lg[r], d);
    }
    if (r16 == 0) {
#pragma unroll
      for (int r = 0; r < 4; ++r) {
        int orow = v0 + hi * 4 + r;
        if (act && orow < n) probs[orow] = 1.f / (1.f + expf(-(lg[r] + bn0)));
      }
    }
    __syncthreads();  // shsum zero-init visible
#pragma unroll
    for (int jt = 0; jt < 4; ++jt) {
      float s = ov[jt][0] + ov[jt][1] + ov[jt][2] + ov[jt][3];
      s += __shfl_xor(s, 16); s += __shfl_xor(s, 32);
      if (hi == 0) atomicAdd(&shsum[jt * 16 + r16], s);
    }
    __syncthreads();
    if (threadIdx.x < 64)
      atomicAdd(&hsumP[((blockIdx.x & 7) << 6) + threadIdx.x], shsum[threadIdx.x]);
  }
}

// ---- global mean + 2-layer head (tiny) ----
__global__ void k_final(const float* __restrict__ hsumP,
                        const float* __restrict__ W1, const float* __restrict__ b1,
                        const float* __restrict__ W2, const float* __restrict__ b2,
                        float* __restrict__ out4, float n_nodes) {
  __shared__ float hmean[64];
  __shared__ float z1[32];
  int tid = threadIdx.x;
  if (tid < 64) {
    float s = 0.f;
#pragma unroll
    for (int b = 0; b < 8; ++b) s += hsumP[b * 64 + tid];
    hmean[tid] = s / n_nodes;
  }
  __syncthreads();
  if (tid < 32) {
    float a = b1[tid];
    for (int k = 0; k < 64; ++k) a = fmaf(hmean[k], W1[k * 32 + tid], a);
    z1[tid] = fmaxf(a, 0.f);
  }
  __syncthreads();
  if (tid < 4) {
    float a = b2[tid];
    for (int k = 0; k < 32; ++k) a = fmaf(z1[k], W2[k * 4 + tid], a);
    out4[tid] = a;
  }
}

extern "C" void kernel_launch(void* const* d_in, const int* in_sizes, int n_in,
                              void* d_out, int out_size, void* d_ws, size_t ws_size,
                              hipStream_t stream) {
  const float* x    = (const float*)d_in[0];
  const int*   ei   = (const int*)d_in[1];
  const float* ea   = (const float*)d_in[2];
  const float* Win  = (const float*)d_in[3];
  const float* bin  = (const float*)d_in[4];
  const float* Wmsg = (const float*)d_in[5];
  const float* bmsg = (const float*)d_in[6];
  const float* Wupd = (const float*)d_in[7];
  const float* bupd = (const float*)d_in[8];
  const float* Wn   = (const float*)d_in[9];
  const float* bn   = (const float*)d_in[10];
  const float* W1   = (const float*)d_in[13];
  const float* b1   = (const float*)d_in[14];
  const float* W2   = (const float*)d_in[15];
  const float* b2   = (const float*)d_in[16];

  const int N = in_sizes[0] / 2;
  const int E = in_sizes[1] / 2;
  const int* src = ei;
  const int* dst = ei + E;

  char* ws = (char*)d_ws;
  size_t off = 0;
  auto alloc = [&](size_t bytes) {
    void* p = ws + off;
    off = (off + bytes + 255) & ~(size_t)255;
    return p;
  };
  int*   hist = (int*)  alloc((size_t)N * 4);
  int*   rptr = (int*)  alloc((size_t)(N + 1) * 4);
  int*   pos  = (int*)  alloc((size_t)N * 4);
  int*   bsum = (int*)  alloc((size_t)1024 * 4);
  unsigned long long* erec = (unsigned long long*)alloc((size_t)E * 8);
  unsigned short* hb   = (unsigned short*)alloc((size_t)N * H * 2);
  unsigned short* g    = (unsigned short*)alloc((size_t)N * H * 2);
  unsigned short* aggb = (unsigned short*)alloc((size_t)N * H * 2);
  unsigned short* WmT  = (unsigned short*)alloc((size_t)3 * 64 * 64 * 2);
  unsigned short* WuT  = (unsigned short*)alloc((size_t)3 * 64 * 128 * 2);
  float* hsumP = (float*)alloc(8 * 64 * 4);
  (void)ws_size;

  float* probs = (float*)d_out;          // [N]
  float* out4  = probs + N;              // [4]
  float* h     = out4 + 4;               // [N, 64] fp32 final embeddings

  hipMemsetAsync(hist, 0, (size_t)N * 4, stream);
  hipMemsetAsync(hsumP, 0, 8 * 64 * 4, stream);
  int eb = (E + 255) / 256;
  int sb = (N + 1023) / 1024;
  k_hist<<<eb, 256, 0, stream>>>(dst, hist, E);
  k_scan1<<<sb, 256, 0, stream>>>(hist, bsum, N);
  k_scan2<<<1, 1024, 0, stream>>>(bsum, sb);
  k_scan3<<<sb, 256, 0, stream>>>(hist, bsum, rptr, pos, N);
  k_scatter<<<eb, 256, 0, stream>>>(src, dst, ea, pos, erec, E);
  k_wprep<<<3, 256, 0, stream>>>(Wmsg, Wupd, WmT, WuT);

  k_inproj<<<(N * 64 + 255) / 256, 256, 0, stream>>>(x, Win, bin, hb, N);

  int tiles = (N + 15) / 16;
  int mb = (tiles + 3) / 4;
  int nb = (N + 3) / 4;
  for (int l = 0; l < 3; ++l) {
    k_gemm_mfma<<<mb, 256, 0, stream>>>(hb, WmT + (size_t)l * 64 * 64, g, N);
    k_agg<<<nb, 256, 0, stream>>>(g, rptr, erec,
                                  Wmsg + (size_t)l * 66 * 64 + 64 * 64,
                                  bmsg + (size_t)l * 64, aggb, N);
    k_upd_mfma<<<mb, 256, 0, stream>>>(hb, aggb, WuT + (size_t)l * 64 * 128,
                                       bupd + (size_t)l * 64, hb,
                                       (l == 2) ? h : nullptr,
                                       Wn, bn, probs, hsumP, N);
  }

  k_final<<<1, 64, 0, stream>>>(hsumP, W1, b1, W2, b2, out4, (float)N);
}

// Round 8
// 263.800 us; speedup vs baseline: 4.1681x; 1.0824x over previous
//
#include <hip/hip_runtime.h>
#include <math.h>

constexpr int H = 64;

typedef __attribute__((ext_vector_type(8))) short bf16x8;
typedef __attribute__((ext_vector_type(4))) float f32x4;

__device__ inline unsigned short f2bf(float f) {
  union { float f; unsigned int u; } c; c.f = f;
  unsigned int u = c.u;
  return (unsigned short)((u + 0x7FFF + ((u >> 16) & 1)) >> 16);  // RNE
}
__device__ inline float bf2f(unsigned int s) {
  union { unsigned int u; float f; } c; c.u = s << 16;
  return c.f;
}

// ---- CSR build ----
__global__ void k_hist(const int* __restrict__ dst, int* __restrict__ hist, int E) {
  int e = blockIdx.x * blockDim.x + threadIdx.x;
  if (e < E) atomicAdd(&hist[dst[e]], 1);
}

__global__ void k_scan1(const int* __restrict__ hist, int* __restrict__ bsum, int n) {
  __shared__ int sred[256];
  int tid = threadIdx.x;
  int base = blockIdx.x * 1024 + tid * 4;
  int s = 0;
#pragma unroll
  for (int k = 0; k < 4; ++k) { int i = base + k; if (i < n) s += hist[i]; }
  sred[tid] = s;
  __syncthreads();
  for (int d = 128; d > 0; d >>= 1) {
    if (tid < d) sred[tid] += sred[tid + d];
    __syncthreads();
  }
  if (tid == 0) bsum[blockIdx.x] = sred[0];
}

__global__ void k_scan2(int* __restrict__ bsum, int nb) {
  __shared__ int sd[1024];
  int tid = threadIdx.x;
  int v = (tid < nb) ? bsum[tid] : 0;
  sd[tid] = v;
  __syncthreads();
  for (int d = 1; d < 1024; d <<= 1) {
    int t = (tid >= d) ? sd[tid - d] : 0;
    __syncthreads();
    sd[tid] += t;
    __syncthreads();
  }
  if (tid < nb) bsum[tid] = sd[tid] - v;
}

__global__ void k_scan3(const int* __restrict__ hist, const int* __restrict__ bsum,
                        int* __restrict__ row_ptr, int* __restrict__ pos, int n) {
  __shared__ int sth[256];
  int tid = threadIdx.x;
  int base = blockIdx.x * 1024 + tid * 4;
  int v[4]; int s = 0;
#pragma unroll
  for (int k = 0; k < 4; ++k) { int i = base + k; v[k] = (i < n) ? hist[i] : 0; s += v[k]; }
  sth[tid] = s;
  __syncthreads();
  for (int d = 1; d < 256; d <<= 1) {
    int t = (tid >= d) ? sth[tid - d] : 0;
    __syncthreads();
    sth[tid] += t;
    __syncthreads();
  }
  int run = bsum[blockIdx.x] + sth[tid] - s;
  if (blockIdx.x == 0 && tid == 0) row_ptr[0] = 0;
#pragma unroll
  for (int k = 0; k < 4; ++k) {
    int i = base + k;
    if (i < n) {
      pos[i] = run;
      run += v[k];
      row_ptr[i + 1] = run;
    }
  }
}

// ---- bucketed two-phase edge placement (buckets = dst >> 10, max 64 buckets) ----
__global__ void k_binit(const int* __restrict__ rptr, int* __restrict__ bcur, int B) {
  int b = threadIdx.x;
  if (b < B) bcur[b] = rptr[b << 10];
}

// Phase A: block-local LDS bucket sort of 2048 edges -> bucket-contiguous staged appends
__global__ void k_part(const int* __restrict__ src, const int* __restrict__ dst,
                       const float2* __restrict__ ea2, int* __restrict__ bcur,
                       uint4* __restrict__ staged, int E, int B) {
  __shared__ uint4 srt[2048];                 // 32 KB
  __shared__ int cnt[64], offs[64], gbase[64];
  int tid = threadIdx.x;
  int base = blockIdx.x * 2048;
  if (tid < 64) cnt[tid] = 0;
  __syncthreads();
  uint4 rec_[8]; int bk_[8], rk_[8];
#pragma unroll
  for (int k = 0; k < 8; ++k) {
    int e = base + k * 256 + tid;
    if (e < E) {
      int d = dst[e];
      int bk = d >> 10;
      float2 eav = ea2[e];
      unsigned int lo = f2bf(eav.x), hi = f2bf(eav.y);
      rec_[k] = make_uint4((unsigned int)src[e], (unsigned int)d, lo | (hi << 16), (unsigned int)bk);
      bk_[k] = bk;
      rk_[k] = atomicAdd(&cnt[bk], 1);
    } else bk_[k] = -1;
  }
  __syncthreads();
  if (tid == 0) {
    int run = 0;
    for (int b = 0; b < B; ++b) { offs[b] = run; run += cnt[b]; }
  }
  __syncthreads();
#pragma unroll
  for (int k = 0; k < 8; ++k)
    if (bk_[k] >= 0) srt[offs[bk_[k]] + rk_[k]] = rec_[k];
  __syncthreads();
  if (tid < B && cnt[tid] > 0) gbase[tid] = atomicAdd(&bcur[tid], cnt[tid]);
  __syncthreads();
  int total = (base + 2048 <= E) ? 2048 : (E > base ? E - base : 0);
  for (int i = tid; i < total; i += 256) {
    uint4 r = srt[i];
    int bk = (int)r.w;
    staged[gbase[bk] + (i - offs[bk])] = r;   // bucket-contiguous, ~full-line appends
  }
}

// Phase B: one workgroup per bucket -> final dst-sorted erec, writes L2-local to one XCD
__global__ void k_place(const uint4* __restrict__ staged, const int* __restrict__ rptr,
                        unsigned long long* __restrict__ erec, int N_) {
  __shared__ int cnt2[1024];
  __shared__ int rptrL[1025];
  int b = blockIdx.x;
  int nd0 = b << 10;
  int nn = min(nd0 + 1024, N_) - nd0;
  int tid = threadIdx.x;  // 1024 threads
  if (tid < nn) { cnt2[tid] = 0; rptrL[tid] = rptr[nd0 + tid]; }
  if (tid == 0) rptrL[nn] = rptr[nd0 + nn];
  __syncthreads();
  int beg = rptrL[0], end = rptrL[nn];
  for (int i = beg + tid; i < end; i += 1024) {
    uint4 r = staged[i];
    int dl = (int)r.y - nd0;
    int p = rptrL[dl] + atomicAdd(&cnt2[dl], 1);
    erec[p] = (unsigned long long)r.x | ((unsigned long long)r.z << 32);
  }
}

// ---- fallback single-pass scatter (only used if N > 65536) ----
__global__ void k_scatter(const int* __restrict__ src, const int* __restrict__ dst,
                          const float* __restrict__ ea, int* __restrict__ pos,
                          unsigned long long* __restrict__ erec, int E) {
  int e = blockIdx.x * blockDim.x + threadIdx.x;
  if (e < E) {
    int d = dst[e];
    int p = atomicAdd(&pos[d], 1);
    unsigned long long lo = f2bf(ea[2 * e]);
    unsigned long long hi = f2bf(ea[2 * e + 1]);
    erec[p] = (unsigned long long)(unsigned int)src[e] | ((lo | (hi << 16)) << 32);
  }
}

// ---- input projection -> bf16 hb ----
__global__ void k_inproj(const float* __restrict__ x, const float* __restrict__ Win,
                         const float* __restrict__ bin, unsigned short* __restrict__ hb, int n) {
  int t = blockIdx.x * blockDim.x + threadIdx.x;
  int v = t >> 6, j = t & 63;
  if (v < n) {
    float x0 = x[2 * v], x1 = x[2 * v + 1];
    hb[(size_t)v * H + j] = f2bf(fmaf(x0, Win[j], fmaf(x1, Win[H + j], bin[j])));
  }
}

// ---- weight prep ----
__global__ void k_wprep(const float* __restrict__ Wmsg, const float* __restrict__ Wupd,
                        unsigned short* __restrict__ WmT, unsigned short* __restrict__ WuT) {
  int l = blockIdx.x;
  const float* Wm = Wmsg + (size_t)l * 66 * 64;
  const float* Wu = Wupd + (size_t)l * 128 * 64;
  unsigned short* wmt = WmT + (size_t)l * 64 * 64;
  unsigned short* wut = WuT + (size_t)l * 64 * 128;
  for (int i = threadIdx.x; i < 64 * 64; i += blockDim.x) {
    int j = i >> 6, k = i & 63;
    wmt[i] = f2bf(Wm[k * 64 + j]);
  }
  for (int i = threadIdx.x; i < 64 * 128; i += blockDim.x) {
    int j = i >> 7, k = i & 127;
    wut[i] = f2bf(Wu[k * 64 + j]);
  }
}

// ---- g = bf16(hb @ Wm1): MFMA, one wave per 16-node tile ----
__global__ void k_gemm_mfma(const unsigned short* __restrict__ hb,
                            const unsigned short* __restrict__ wmt,
                            unsigned short* __restrict__ g, int n) {
  int lane = threadIdx.x & 63;
  int wv = blockIdx.x * (blockDim.x >> 6) + (threadIdx.x >> 6);
  int v0 = wv * 16;
  if (v0 >= n) return;
  int r16 = lane & 15, hi = lane >> 4;
  bf16x8 bfr[2][4];
#pragma unroll
  for (int ks = 0; ks < 2; ++ks)
#pragma unroll
    for (int jt = 0; jt < 4; ++jt)
      bfr[ks][jt] = *(const bf16x8*)(wmt + (jt * 16 + r16) * 64 + ks * 32 + hi * 8);
  bf16x8 afr[2];
  int row = v0 + r16;
  if (row < n) {
    const unsigned short* arow = hb + (size_t)row * H + hi * 8;
    afr[0] = *(const bf16x8*)(arow);
    afr[1] = *(const bf16x8*)(arow + 32);
  } else {
    afr[0] = (bf16x8){0,0,0,0,0,0,0,0};
    afr[1] = (bf16x8){0,0,0,0,0,0,0,0};
  }
  f32x4 acc[4] = {};
#pragma unroll
  for (int ks = 0; ks < 2; ++ks)
#pragma unroll
    for (int jt = 0; jt < 4; ++jt)
      acc[jt] = __builtin_amdgcn_mfma_f32_16x16x32_bf16(afr[ks], bfr[ks][jt], acc[jt], 0, 0, 0);
#pragma unroll
  for (int jt = 0; jt < 4; ++jt) {
    int col = jt * 16 + r16;
#pragma unroll
    for (int r = 0; r < 4; ++r) {
      int orow = v0 + hi * 4 + r;
      if (orow < n) g[(size_t)orow * H + col] = f2bf(acc[jt][r]);
    }
  }
}

// ---- aggregation: persistent grid-stride waves, hoisted weights, 4 gather chains ----
__global__ void k_agg(const unsigned short* __restrict__ g, const int* __restrict__ row_ptr,
                      const unsigned long long* __restrict__ erec,
                      const float* __restrict__ Wm2, const float* __restrict__ bm,
                      unsigned short* __restrict__ aggb, int n) {
  int lane = threadIdx.x & 63;
  int r = lane & 15, grp = lane >> 4;
  int j0 = r * 4;
  float4 w2a = *(const float4*)(Wm2 + j0);
  float4 w2b = *(const float4*)(Wm2 + 64 + j0);
  float4 bm4 = *(const float4*)(bm + j0);
  int gw = blockIdx.x * (blockDim.x >> 6) + (threadIdx.x >> 6);
  int nw = gridDim.x * (blockDim.x >> 6);
  for (int v = gw; v < n; v += nw) {
    int beg = row_ptr[v], end = row_ptr[v + 1];
    float a0 = 0.f, a1 = 0.f, a2 = 0.f, a3 = 0.f;
    int i = beg + grp;
    for (; i + 12 < end; i += 16) {  // 4 independent gather chains
      unsigned long long rA = erec[i], rB = erec[i + 4], rC = erec[i + 8], rD = erec[i + 12];
      uint2 gwA = *(const uint2*)(g + (size_t)(unsigned int)rA * H + j0);
      uint2 gwB = *(const uint2*)(g + (size_t)(unsigned int)rB * H + j0);
      uint2 gwC = *(const uint2*)(g + (size_t)(unsigned int)rC * H + j0);
      uint2 gwD = *(const uint2*)(g + (size_t)(unsigned int)rD * H + j0);
      unsigned int eA = (unsigned int)(rA >> 32), eB = (unsigned int)(rB >> 32);
      unsigned int eC = (unsigned int)(rC >> 32), eD = (unsigned int)(rD >> 32);
      float eA0 = bf2f(eA & 0xffffu), eA1 = bf2f(eA >> 16);
      float eB0 = bf2f(eB & 0xffffu), eB1 = bf2f(eB >> 16);
      float eC0 = bf2f(eC & 0xffffu), eC1 = bf2f(eC >> 16);
      float eD0 = bf2f(eD & 0xffffu), eD1 = bf2f(eD >> 16);
      a0 += fmaxf(fmaf(eA0, w2a.x, fmaf(eA1, w2b.x, bf2f(gwA.x & 0xffffu) + bm4.x)), 0.f)
          + fmaxf(fmaf(eB0, w2a.x, fmaf(eB1, w2b.x, bf2f(gwB.x & 0xffffu) + bm4.x)), 0.f)
          + fmaxf(fmaf(eC0, w2a.x, fmaf(eC1, w2b.x, bf2f(gwC.x & 0xffffu) + bm4.x)), 0.f)
          + fmaxf(fmaf(eD0, w2a.x, fmaf(eD1, w2b.x, bf2f(gwD.x & 0xffffu) + bm4.x)), 0.f);
      a1 += fmaxf(fmaf(eA0, w2a.y, fmaf(eA1, w2b.y, bf2f(gwA.x >> 16) + bm4.y)), 0.f)
          + fmaxf(fmaf(eB0, w2a.y, fmaf(eB1, w2b.y, bf2f(gwB.x >> 16) + bm4.y)), 0.f)
          + fmaxf(fmaf(eC0, w2a.y, fmaf(eC1, w2b.y, bf2f(gwC.x >> 16) + bm4.y)), 0.f)
          + fmaxf(fmaf(eD0, w2a.y, fmaf(eD1, w2b.y, bf2f(gwD.x >> 16) + bm4.y)), 0.f);
      a2 += fmaxf(fmaf(eA0, w2a.z, fmaf(eA1, w2b.z, bf2f(gwA.y & 0xffffu) + bm4.z)), 0.f)
          + fmaxf(fmaf(eB0, w2a.z, fmaf(eB1, w2b.z, bf2f(gwB.y & 0xffffu) + bm4.z)), 0.f)
          + fmaxf(fmaf(eC0, w2a.z, fmaf(eC1, w2b.z, bf2f(gwC.y & 0xffffu) + bm4.z)), 0.f)
          + fmaxf(fmaf(eD0, w2a.z, fmaf(eD1, w2b.z, bf2f(gwD.y & 0xffffu) + bm4.z)), 0.f);
      a3 += fmaxf(fmaf(eA0, w2a.w, fmaf(eA1, w2b.w, bf2f(gwA.y >> 16) + bm4.w)), 0.f)
          + fmaxf(fmaf(eB0, w2a.w, fmaf(eB1, w2b.w, bf2f(gwB.y >> 16) + bm4.w)), 0.f)
          + fmaxf(fmaf(eC0, w2a.w, fmaf(eC1, w2b.w, bf2f(gwC.y >> 16) + bm4.w)), 0.f)
          + fmaxf(fmaf(eD0, w2a.w, fmaf(eD1, w2b.w, bf2f(gwD.y >> 16) + bm4.w)), 0.f);
    }
    for (; i < end; i += 4) {
      unsigned long long rA = erec[i];
      uint2 gwA = *(const uint2*)(g + (size_t)(unsigned int)rA * H + j0);
      unsigned int eA = (unsigned int)(rA >> 32);
      float eA0 = bf2f(eA & 0xffffu), eA1 = bf2f(eA >> 16);
      a0 += fmaxf(fmaf(eA0, w2a.x, fmaf(eA1, w2b.x, bf2f(gwA.x & 0xffffu) + bm4.x)), 0.f);
      a1 += fmaxf(fmaf(eA0, w2a.y, fmaf(eA1, w2b.y, bf2f(gwA.x >> 16) + bm4.y)), 0.f);
      a2 += fmaxf(fmaf(eA0, w2a.z, fmaf(eA1, w2b.z, bf2f(gwA.y & 0xffffu) + bm4.z)), 0.f);
      a3 += fmaxf(fmaf(eA0, w2a.w, fmaf(eA1, w2b.w, bf2f(gwA.y >> 16) + bm4.w)), 0.f);
    }
    a0 += __shfl_xor(a0, 16); a0 += __shfl_xor(a0, 32);
    a1 += __shfl_xor(a1, 16); a1 += __shfl_xor(a1, 32);
    a2 += __shfl_xor(a2, 16); a2 += __shfl_xor(a2, 32);
    a3 += __shfl_xor(a3, 16); a3 += __shfl_xor(a3, 32);
    if (grp == 0) {
      float inv = 1.f / fmaxf((float)(end - beg), 1.f);
      unsigned int p0 = f2bf(a0 * inv) | ((unsigned int)f2bf(a1 * inv) << 16);
      unsigned int p1 = f2bf(a2 * inv) | ((unsigned int)f2bf(a3 * inv) << 16);
      *(uint2*)(aggb + (size_t)v * H + j0) = make_uint2(p0, p1);
    }
  }
}

// ---- update MLP via MFMA; last layer fuses node head + hsum partials ----
__global__ void k_upd_mfma(const unsigned short* __restrict__ hb,
                           const unsigned short* __restrict__ aggb,
                           const unsigned short* __restrict__ wut,
                           const float* __restrict__ bu,
                           unsigned short* __restrict__ hb_out,
                           float* __restrict__ hout,          // non-null on last layer
                           const float* __restrict__ Wn, const float* __restrict__ bn,
                           float* __restrict__ probs, float* __restrict__ hsumP,
                           int n) {
  __shared__ float shsum[64];
  int lane = threadIdx.x & 63;
  int wv = blockIdx.x * (blockDim.x >> 6) + (threadIdx.x >> 6);
  int v0 = wv * 16;
  bool act = v0 < n;
  int r16 = lane & 15, hi = lane >> 4;
  if (hout && threadIdx.x < 64) shsum[threadIdx.x] = 0.f;
  bf16x8 bfr[4][4];
#pragma unroll
  for (int ks = 0; ks < 4; ++ks)
#pragma unroll
    for (int jt = 0; jt < 4; ++jt)
      bfr[ks][jt] = *(const bf16x8*)(wut + (jt * 16 + r16) * 128 + ks * 32 + hi * 8);
  f32x4 acc[4];
#pragma unroll
  for (int jt = 0; jt < 4; ++jt) {
    float b = bu[jt * 16 + r16];
    acc[jt] = (f32x4){b, b, b, b};
  }
  bf16x8 afr[4];
  int row = v0 + r16;
  if (act && row < n) {
    const unsigned short* hrow = hb   + (size_t)row * H + hi * 8;
    const unsigned short* arow = aggb + (size_t)row * H + hi * 8;
    afr[0] = *(const bf16x8*)(hrow);
    afr[1] = *(const bf16x8*)(hrow + 32);
    afr[2] = *(const bf16x8*)(arow);
    afr[3] = *(const bf16x8*)(arow + 32);
  } else {
    afr[0] = afr[1] = afr[2] = afr[3] = (bf16x8){0,0,0,0,0,0,0,0};
  }
#pragma unroll
  for (int ks = 0; ks < 4; ++ks)
#pragma unroll
    for (int jt = 0; jt < 4; ++jt)
      acc[jt] = __builtin_amdgcn_mfma_f32_16x16x32_bf16(afr[ks], bfr[ks][jt], acc[jt], 0, 0, 0);
  float ov[4][4];
#pragma unroll
  for (int jt = 0; jt < 4; ++jt) {
    int col = jt * 16 + r16;
#pragma unroll
    for (int r = 0; r < 4; ++r) {
      int orow = v0 + hi * 4 + r;
      bool ok = act && orow < n;
      float o = fmaxf(acc[jt][r], 0.f);
      ov[jt][r] = ok ? o : 0.f;
      if (ok) {
        hb_out[(size_t)orow * H + col] = f2bf(o);
        if (hout) hout[(size_t)orow * H + col] = o;
      }
    }
  }
  if (hout) {
    float bn0 = bn[0];
    float lg[4] = {0.f, 0.f, 0.f, 0.f};
#pragma unroll
    for (int jt = 0; jt < 4; ++jt) {
      float w = Wn[jt * 16 + r16];
#pragma unroll
      for (int r = 0; r < 4; ++r) lg[r] = fmaf(ov[jt][r], w, lg[r]);
    }
#pragma unroll
    for (int d = 1; d < 16; d <<= 1) {
#pragma unroll
      for (int r = 0; r < 4; ++r) lg[r] += __shfl_xor(lg[r], d);
    }
    if (r16 == 0) {
#pragma unroll
      for (int r = 0; r < 4; ++r) {
        int orow = v0 + hi * 4 + r;
        if (act && orow < n) probs[orow] = 1.f / (1.f + expf(-(lg[r] + bn0)));
      }
    }
    __syncthreads();
#pragma unroll
    for (int jt = 0; jt < 4; ++jt) {
      float s = ov[jt][0] + ov[jt][1] + ov[jt][2] + ov[jt][3];
      s += __shfl_xor(s, 16); s += __shfl_xor(s, 32);
      if (hi == 0) atomicAdd(&shsum[jt * 16 + r16], s);
    }
    __syncthreads();
    if (threadIdx.x < 64)
      atomicAdd(&hsumP[((blockIdx.x & 7) << 6) + threadIdx.x], shsum[threadIdx.x]);
  }
}

// ---- global mean + 2-layer head (tiny) ----
__global__ void k_final(const float* __restrict__ hsumP,
                        const float* __restrict__ W1, const float* __restrict__ b1,
                        const float* __restrict__ W2, const float* __restrict__ b2,
                        float* __restrict__ out4, float n_nodes) {
  __shared__ float hmean[64];
  __shared__ float z1[32];
  int tid = threadIdx.x;
  if (tid < 64) {
    float s = 0.f;
#pragma unroll
    for (int b = 0; b < 8; ++b) s += hsumP[b * 64 + tid];
    hmean[tid] = s / n_nodes;
  }
  __syncthreads();
  if (tid < 32) {
    float a = b1[tid];
    for (int k = 0; k < 64; ++k) a = fmaf(hmean[k], W1[k * 32 + tid], a);
    z1[tid] = fmaxf(a, 0.f);
  }
  __syncthreads();
  if (tid < 4) {
    float a = b2[tid];
    for (int k = 0; k < 32; ++k) a = fmaf(z1[k], W2[k * 4 + tid], a);
    out4[tid] = a;
  }
}

extern "C" void kernel_launch(void* const* d_in, const int* in_sizes, int n_in,
                              void* d_out, int out_size, void* d_ws, size_t ws_size,
                              hipStream_t stream) {
  const float* x    = (const float*)d_in[0];
  const int*   ei   = (const int*)d_in[1];
  const float* ea   = (const float*)d_in[2];
  const float* Win  = (const float*)d_in[3];
  const float* bin  = (const float*)d_in[4];
  const float* Wmsg = (const float*)d_in[5];
  const float* bmsg = (const float*)d_in[6];
  const float* Wupd = (const float*)d_in[7];
  const float* bupd = (const float*)d_in[8];
  const float* Wn   = (const float*)d_in[9];
  const float* bn   = (const float*)d_in[10];
  const float* W1   = (const float*)d_in[13];
  const float* b1   = (const float*)d_in[14];
  const float* W2   = (const float*)d_in[15];
  const float* b2   = (const float*)d_in[16];

  const int N = in_sizes[0] / 2;
  const int E = in_sizes[1] / 2;
  const int* src = ei;
  const int* dst = ei + E;

  char* ws = (char*)d_ws;
  size_t off = 0;
  auto alloc = [&](size_t bytes) {
    void* p = ws + off;
    off = (off + bytes + 255) & ~(size_t)255;
    return p;
  };
  int*   hist = (int*)  alloc((size_t)N * 4);
  int*   rptr = (int*)  alloc((size_t)(N + 1) * 4);
  int*   pos  = (int*)  alloc((size_t)N * 4);
  int*   bsum = (int*)  alloc((size_t)1024 * 4);
  int*   bcur = (int*)  alloc((size_t)64 * 4);
  uint4* staged = (uint4*)alloc((size_t)E * 16);
  unsigned long long* erec = (unsigned long long*)alloc((size_t)E * 8);
  unsigned short* hb   = (unsigned short*)alloc((size_t)N * H * 2);
  unsigned short* g    = (unsigned short*)alloc((size_t)N * H * 2);
  unsigned short* aggb = (unsigned short*)alloc((size_t)N * H * 2);
  unsigned short* WmT  = (unsigned short*)alloc((size_t)3 * 64 * 64 * 2);
  unsigned short* WuT  = (unsigned short*)alloc((size_t)3 * 64 * 128 * 2);
  float* hsumP = (float*)alloc(8 * 64 * 4);
  (void)ws_size;

  float* probs = (float*)d_out;          // [N]
  float* out4  = probs + N;              // [4]
  float* h     = out4 + 4;               // [N, 64] fp32 final embeddings

  hipMemsetAsync(hist, 0, (size_t)N * 4, stream);
  hipMemsetAsync(hsumP, 0, 8 * 64 * 4, stream);
  int eb = (E + 255) / 256;
  int sb = (N + 1023) / 1024;
  k_hist<<<eb, 256, 0, stream>>>(dst, hist, E);
  k_scan1<<<sb, 256, 0, stream>>>(hist, bsum, N);
  k_scan2<<<1, 1024, 0, stream>>>(bsum, sb);
  k_scan3<<<sb, 256, 0, stream>>>(hist, bsum, rptr, pos, N);

  int B = (N + 1023) >> 10;   // dst-buckets of 1024 nodes
  if (B <= 64) {
    k_binit<<<1, 64, 0, stream>>>(rptr, bcur, B);
    k_part<<<(E + 2047) / 2048, 256, 0, stream>>>(src, dst, (const float2*)ea,
                                                  bcur, staged, E, B);
    k_place<<<B, 1024, 0, stream>>>(staged, rptr, erec, N);
  } else {
    k_scatter<<<eb, 256, 0, stream>>>(src, dst, ea, pos, erec, E);  // fallback
  }
  k_wprep<<<3, 256, 0, stream>>>(Wmsg, Wupd, WmT, WuT);

  k_inproj<<<(N * 64 + 255) / 256, 256, 0, stream>>>(x, Win, bin, hb, N);

  int tiles = (N + 15) / 16;
  int mb = (tiles + 3) / 4;
  int ab = 2048;              // persistent k_agg: 8192 waves grid-stride
  for (int l = 0; l < 3; ++l) {
    k_gemm_mfma<<<mb, 256, 0, stream>>>(hb, WmT + (size_t)l * 64 * 64, g, N);
    k_agg<<<ab, 256, 0, stream>>>(g, rptr, erec,
                                  Wmsg + (size_t)l * 66 * 64 + 64 * 64,
                                  bmsg + (size_t)l * 64, aggb, N);
    k_upd_mfma<<<mb, 256, 0, stream>>>(hb, aggb, WuT + (size_t)l * 64 * 128,
                                       bupd + (size_t)l * 64, hb,
                                       (l == 2) ? h : nullptr,
                                       Wn, bn, probs, hsumP, N);
  }

  k_final<<<1, 64, 0, stream>>>(hsumP, W1, b1, W2, b2, out4, (float)N);
}

// Round 9
// 260.145 us; speedup vs baseline: 4.2266x; 1.0140x over previous
//
#include <hip/hip_runtime.h>
#include <math.h>

constexpr int H = 64;

typedef __attribute__((ext_vector_type(8))) short bf16x8;
typedef __attribute__((ext_vector_type(4))) float f32x4;
typedef unsigned long long u64;

__device__ inline unsigned short f2bf(float f) {
  union { float f; unsigned int u; } c; c.f = f;
  unsigned int u = c.u;
  return (unsigned short)((u + 0x7FFF + ((u >> 16) & 1)) >> 16);  // RNE
}
__device__ inline float bf2f(unsigned int s) {
  union { unsigned int u; float f; } c; c.u = s << 16;
  return c.f;
}

// ---- zero-init (replaces hipMemsetAsync fills: rocclr fill kernel showed 45us in-graph) ----
__global__ void k_zero(int* __restrict__ hist, float* __restrict__ hsumP, int n) {
  int i = blockIdx.x * blockDim.x + threadIdx.x;
  if (i < n) hist[i] = 0;
  if (i < 512) hsumP[i] = 0.f;
}

// ---- CSR build ----
__global__ void k_hist(const int* __restrict__ dst, int* __restrict__ hist, int E) {
  int e = blockIdx.x * blockDim.x + threadIdx.x;
  if (e < E) atomicAdd(&hist[dst[e]], 1);
}

__global__ void k_scan1(const int* __restrict__ hist, int* __restrict__ bsum, int n) {
  __shared__ int sred[256];
  int tid = threadIdx.x;
  int base = blockIdx.x * 1024 + tid * 4;
  int s = 0;
#pragma unroll
  for (int k = 0; k < 4; ++k) { int i = base + k; if (i < n) s += hist[i]; }
  sred[tid] = s;
  __syncthreads();
  for (int d = 128; d > 0; d >>= 1) {
    if (tid < d) sred[tid] += sred[tid + d];
    __syncthreads();
  }
  if (tid == 0) bsum[blockIdx.x] = sred[0];
}

__global__ void k_scan2(int* __restrict__ bsum, int nb) {
  __shared__ int sd[1024];
  int tid = threadIdx.x;
  int v = (tid < nb) ? bsum[tid] : 0;
  sd[tid] = v;
  __syncthreads();
  for (int d = 1; d < 1024; d <<= 1) {
    int t = (tid >= d) ? sd[tid - d] : 0;
    __syncthreads();
    sd[tid] += t;
    __syncthreads();
  }
  if (tid < nb) bsum[tid] = sd[tid] - v;
}

__global__ void k_scan3(const int* __restrict__ hist, const int* __restrict__ bsum,
                        int* __restrict__ row_ptr, int* __restrict__ pos, int n) {
  __shared__ int sth[256];
  int tid = threadIdx.x;
  int base = blockIdx.x * 1024 + tid * 4;
  int v[4]; int s = 0;
#pragma unroll
  for (int k = 0; k < 4; ++k) { int i = base + k; v[k] = (i < n) ? hist[i] : 0; s += v[k]; }
  sth[tid] = s;
  __syncthreads();
  for (int d = 1; d < 256; d <<= 1) {
    int t = (tid >= d) ? sth[tid - d] : 0;
    __syncthreads();
    sth[tid] += t;
    __syncthreads();
  }
  int run = bsum[blockIdx.x] + sth[tid] - s;
  if (blockIdx.x == 0 && tid == 0) row_ptr[0] = 0;
#pragma unroll
  for (int k = 0; k < 4; ++k) {
    int i = base + k;
    if (i < n) {
      pos[i] = run;
      run += v[k];
      row_ptr[i + 1] = run;
    }
  }
}

// ---- bucketed two-phase edge placement; 8B packed record:
//      [15:0]=src  [25:16]=dst&1023  [31:26]=bucket  [63:32]=ea as 2xbf16 ----
__global__ void k_binit(const int* __restrict__ rptr, int* __restrict__ bcur, int B) {
  int b = threadIdx.x;
  if (b < B) bcur[b] = rptr[b << 10];
}

__global__ void k_part(const int* __restrict__ src, const int* __restrict__ dst,
                       const float2* __restrict__ ea2, int* __restrict__ bcur,
                       u64* __restrict__ staged, int E, int B) {
  __shared__ u64 srt[2048];                   // 16 KB
  __shared__ int cnt[64], offs[64], gbase[64];
  int tid = threadIdx.x;
  int base = blockIdx.x * 2048;
  if (tid < 64) cnt[tid] = 0;
  __syncthreads();
  u64 rec_[8]; int bk_[8], rk_[8];
#pragma unroll
  for (int k = 0; k < 8; ++k) {
    int e = base + k * 256 + tid;
    if (e < E) {
      int d = dst[e];
      int bk = d >> 10;
      float2 eav = ea2[e];
      unsigned int eap = (unsigned int)f2bf(eav.x) | ((unsigned int)f2bf(eav.y) << 16);
      rec_[k] = (u64)(unsigned int)(src[e] & 0xFFFF)
              | ((u64)(unsigned int)(d & 1023) << 16)
              | ((u64)(unsigned int)bk << 26)
              | ((u64)eap << 32);
      bk_[k] = bk;
      rk_[k] = atomicAdd(&cnt[bk], 1);
    } else bk_[k] = -1;
  }
  __syncthreads();
  if (tid == 0) {
    int run = 0;
    for (int b = 0; b < B; ++b) { offs[b] = run; run += cnt[b]; }
  }
  __syncthreads();
#pragma unroll
  for (int k = 0; k < 8; ++k)
    if (bk_[k] >= 0) srt[offs[bk_[k]] + rk_[k]] = rec_[k];
  __syncthreads();
  if (tid < B && cnt[tid] > 0) gbase[tid] = atomicAdd(&bcur[tid], cnt[tid]);
  __syncthreads();
  int total = (base + 2048 <= E) ? 2048 : (E > base ? E - base : 0);
  for (int i = tid; i < total; i += 256) {
    u64 r = srt[i];
    int bk = (int)((r >> 26) & 63u);
    staged[gbase[bk] + (i - offs[bk])] = r;   // bucket-contiguous full-line appends
  }
}

// Phase B: one workgroup per bucket -> final dst-sorted erec {src, ea}, L2-local writes
__global__ void k_place(const u64* __restrict__ staged, const int* __restrict__ rptr,
                        u64* __restrict__ erec, int N_) {
  __shared__ int cnt2[1024];
  __shared__ int rptrL[1025];
  int b = blockIdx.x;
  int nd0 = b << 10;
  int nn = min(nd0 + 1024, N_) - nd0;
  int tid = threadIdx.x;  // 1024 threads
  if (tid < nn) { cnt2[tid] = 0; rptrL[tid] = rptr[nd0 + tid]; }
  if (tid == 0) rptrL[nn] = rptr[nd0 + nn];
  __syncthreads();
  int beg = rptrL[0], end = rptrL[nn];
  for (int i = beg + tid; i < end; i += 1024) {
    u64 r = staged[i];
    int dl = (int)((r >> 16) & 1023u);
    int p = rptrL[dl] + atomicAdd(&cnt2[dl], 1);
    erec[p] = (r & 0xFFFFull) | ((r >> 32) << 32);
  }
}

// ---- fallback single-pass scatter (only if N > 65536; src wouldn't fit 16 bits) ----
__global__ void k_scatter(const int* __restrict__ src, const int* __restrict__ dst,
                          const float* __restrict__ ea, int* __restrict__ pos,
                          u64* __restrict__ erec, int E) {
  int e = blockIdx.x * blockDim.x + threadIdx.x;
  if (e < E) {
    int d = dst[e];
    int p = atomicAdd(&pos[d], 1);
    u64 lo = f2bf(ea[2 * e]);
    u64 hi = f2bf(ea[2 * e + 1]);
    erec[p] = (u64)(unsigned int)src[e] | ((lo | (hi << 16)) << 32);
  }
}

// ---- input projection -> bf16 hb ----
__global__ void k_inproj(const float* __restrict__ x, const float* __restrict__ Win,
                         const float* __restrict__ bin, unsigned short* __restrict__ hb, int n) {
  int t = blockIdx.x * blockDim.x + threadIdx.x;
  int v = t >> 6, j = t & 63;
  if (v < n) {
    float x0 = x[2 * v], x1 = x[2 * v + 1];
    hb[(size_t)v * H + j] = f2bf(fmaf(x0, Win[j], fmaf(x1, Win[H + j], bin[j])));
  }
}

// ---- weight prep ----
__global__ void k_wprep(const float* __restrict__ Wmsg, const float* __restrict__ Wupd,
                        unsigned short* __restrict__ WmT, unsigned short* __restrict__ WuT) {
  int l = blockIdx.x;
  const float* Wm = Wmsg + (size_t)l * 66 * 64;
  const float* Wu = Wupd + (size_t)l * 128 * 64;
  unsigned short* wmt = WmT + (size_t)l * 64 * 64;
  unsigned short* wut = WuT + (size_t)l * 64 * 128;
  for (int i = threadIdx.x; i < 64 * 64; i += blockDim.x) {
    int j = i >> 6, k = i & 63;
    wmt[i] = f2bf(Wm[k * 64 + j]);
  }
  for (int i = threadIdx.x; i < 64 * 128; i += blockDim.x) {
    int j = i >> 7, k = i & 127;
    wut[i] = f2bf(Wu[k * 64 + j]);
  }
}

// ---- g = bf16(hb @ Wm1): MFMA, one wave per 16-node tile ----
__global__ void k_gemm_mfma(const unsigned short* __restrict__ hb,
                            const unsigned short* __restrict__ wmt,
                            unsigned short* __restrict__ g, int n) {
  int lane = threadIdx.x & 63;
  int wv = blockIdx.x * (blockDim.x >> 6) + (threadIdx.x >> 6);
  int v0 = wv * 16;
  if (v0 >= n) return;
  int r16 = lane & 15, hi = lane >> 4;
  bf16x8 bfr[2][4];
#pragma unroll
  for (int ks = 0; ks < 2; ++ks)
#pragma unroll
    for (int jt = 0; jt < 4; ++jt)
      bfr[ks][jt] = *(const bf16x8*)(wmt + (jt * 16 + r16) * 64 + ks * 32 + hi * 8);
  bf16x8 afr[2];
  int row = v0 + r16;
  if (row < n) {
    const unsigned short* arow = hb + (size_t)row * H + hi * 8;
    afr[0] = *(const bf16x8*)(arow);
    afr[1] = *(const bf16x8*)(arow + 32);
  } else {
    afr[0] = (bf16x8){0,0,0,0,0,0,0,0};
    afr[1] = (bf16x8){0,0,0,0,0,0,0,0};
  }
  f32x4 acc[4] = {};
#pragma unroll
  for (int ks = 0; ks < 2; ++ks)
#pragma unroll
    for (int jt = 0; jt < 4; ++jt)
      acc[jt] = __builtin_amdgcn_mfma_f32_16x16x32_bf16(afr[ks], bfr[ks][jt], acc[jt], 0, 0, 0);
#pragma unroll
  for (int jt = 0; jt < 4; ++jt) {
    int col = jt * 16 + r16;
#pragma unroll
    for (int r = 0; r < 4; ++r) {
      int orow = v0 + hi * 4 + r;
      if (orow < n) g[(size_t)orow * H + col] = f2bf(acc[jt][r]);
    }
  }
}

// ---- aggregation: persistent grid-stride waves, hoisted weights, 4 gather chains ----
__global__ void k_agg(const unsigned short* __restrict__ g, const int* __restrict__ row_ptr,
                      const u64* __restrict__ erec,
                      const float* __restrict__ Wm2, const float* __restrict__ bm,
                      unsigned short* __restrict__ aggb, int n) {
  int lane = threadIdx.x & 63;
  int r = lane & 15, grp = lane >> 4;
  int j0 = r * 4;
  float4 w2a = *(const float4*)(Wm2 + j0);
  float4 w2b = *(const float4*)(Wm2 + 64 + j0);
  float4 bm4 = *(const float4*)(bm + j0);
  int gw = blockIdx.x * (blockDim.x >> 6) + (threadIdx.x >> 6);
  int nw = gridDim.x * (blockDim.x >> 6);
  for (int v = gw; v < n; v += nw) {
    int beg = row_ptr[v], end = row_ptr[v + 1];
    float a0 = 0.f, a1 = 0.f, a2 = 0.f, a3 = 0.f;
    int i = beg + grp;
    for (; i + 12 < end; i += 16) {  // 4 independent gather chains
      u64 rA = erec[i], rB = erec[i + 4], rC = erec[i + 8], rD = erec[i + 12];
      uint2 gwA = *(const uint2*)(g + (size_t)(unsigned int)rA * H + j0);
      uint2 gwB = *(const uint2*)(g + (size_t)(unsigned int)rB * H + j0);
      uint2 gwC = *(const uint2*)(g + (size_t)(unsigned int)rC * H + j0);
      uint2 gwD = *(const uint2*)(g + (size_t)(unsigned int)rD * H + j0);
      unsigned int eA = (unsigned int)(rA >> 32), eB = (unsigned int)(rB >> 32);
      unsigned int eC = (unsigned int)(rC >> 32), eD = (unsigned int)(rD >> 32);
      float eA0 = bf2f(eA & 0xffffu), eA1 = bf2f(eA >> 16);
      float eB0 = bf2f(eB & 0xffffu), eB1 = bf2f(eB >> 16);
      float eC0 = bf2f(eC & 0xffffu), eC1 = bf2f(eC >> 16);
      float eD0 = bf2f(eD & 0xffffu), eD1 = bf2f(eD >> 16);
      a0 += fmaxf(fmaf(eA0, w2a.x, fmaf(eA1, w2b.x, bf2f(gwA.x & 0xffffu) + bm4.x)), 0.f)
          + fmaxf(fmaf(eB0, w2a.x, fmaf(eB1, w2b.x, bf2f(gwB.x & 0xffffu) + bm4.x)), 0.f)
          + fmaxf(fmaf(eC0, w2a.x, fmaf(eC1, w2b.x, bf2f(gwC.x & 0xffffu) + bm4.x)), 0.f)
          + fmaxf(fmaf(eD0, w2a.x, fmaf(eD1, w2b.x, bf2f(gwD.x & 0xffffu) + bm4.x)), 0.f);
      a1 += fmaxf(fmaf(eA0, w2a.y, fmaf(eA1, w2b.y, bf2f(gwA.x >> 16) + bm4.y)), 0.f)
          + fmaxf(fmaf(eB0, w2a.y, fmaf(eB1, w2b.y, bf2f(gwB.x >> 16) + bm4.y)), 0.f)
          + fmaxf(fmaf(eC0, w2a.y, fmaf(eC1, w2b.y, bf2f(gwC.x >> 16) + bm4.y)), 0.f)
          + fmaxf(fmaf(eD0, w2a.y, fmaf(eD1, w2b.y, bf2f(gwD.x >> 16) + bm4.y)), 0.f);
      a2 += fmaxf(fmaf(eA0, w2a.z, fmaf(eA1, w2b.z, bf2f(gwA.y & 0xffffu) + bm4.z)), 0.f)
          + fmaxf(fmaf(eB0, w2a.z, fmaf(eB1, w2b.z, bf2f(gwB.y & 0xffffu) + bm4.z)), 0.f)
          + fmaxf(fmaf(eC0, w2a.z, fmaf(eC1, w2b.z, bf2f(gwC.y & 0xffffu) + bm4.z)), 0.f)
          + fmaxf(fmaf(eD0, w2a.z, fmaf(eD1, w2b.z, bf2f(gwD.y & 0xffffu) + bm4.z)), 0.f);
      a3 += fmaxf(fmaf(eA0, w2a.w, fmaf(eA1, w2b.w, bf2f(gwA.y >> 16) + bm4.w)), 0.f)
          + fmaxf(fmaf(eB0, w2a.w, fmaf(eB1, w2b.w, bf2f(gwB.y >> 16) + bm4.w)), 0.f)
          + fmaxf(fmaf(eC0, w2a.w, fmaf(eC1, w2b.w, bf2f(gwC.y >> 16) + bm4.w)), 0.f)
          + fmaxf(fmaf(eD0, w2a.w, fmaf(eD1, w2b.w, bf2f(gwD.y >> 16) + bm4.w)), 0.f);
    }
    for (; i < end; i += 4) {
      u64 rA = erec[i];
      uint2 gwA = *(const uint2*)(g + (size_t)(unsigned int)rA * H + j0);
      unsigned int eA = (unsigned int)(rA >> 32);
      float eA0 = bf2f(eA & 0xffffu), eA1 = bf2f(eA >> 16);
      a0 += fmaxf(fmaf(eA0, w2a.x, fmaf(eA1, w2b.x, bf2f(gwA.x & 0xffffu) + bm4.x)), 0.f);
      a1 += fmaxf(fmaf(eA0, w2a.y, fmaf(eA1, w2b.y, bf2f(gwA.x >> 16) + bm4.y)), 0.f);
      a2 += fmaxf(fmaf(eA0, w2a.z, fmaf(eA1, w2b.z, bf2f(gwA.y & 0xffffu) + bm4.z)), 0.f);
      a3 += fmaxf(fmaf(eA0, w2a.w, fmaf(eA1, w2b.w, bf2f(gwA.y >> 16) + bm4.w)), 0.f);
    }
    a0 += __shfl_xor(a0, 16); a0 += __shfl_xor(a0, 32);
    a1 += __shfl_xor(a1, 16); a1 += __shfl_xor(a1, 32);
    a2 += __shfl_xor(a2, 16); a2 += __shfl_xor(a2, 32);
    a3 += __shfl_xor(a3, 16); a3 += __shfl_xor(a3, 32);
    if (grp == 0) {
      float inv = 1.f / fmaxf((float)(end - beg), 1.f);
      unsigned int p0 = f2bf(a0 * inv) | ((unsigned int)f2bf(a1 * inv) << 16);
      unsigned int p1 = f2bf(a2 * inv) | ((unsigned int)f2bf(a3 * inv) << 16);
      *(uint2*)(aggb + (size_t)v * H + j0) = make_uint2(p0, p1);
    }
  }
}

// ---- update MLP via MFMA; last layer fuses node head + hsum partials ----
__global__ void k_upd_mfma(const unsigned short* __restrict__ hb,
                           const unsigned short* __restrict__ aggb,
                           const unsigned short* __restrict__ wut,
                           const float* __restrict__ bu,
                           unsigned short* __restrict__ hb_out,
                           float* __restrict__ hout,          // non-null on last layer
                           const float* __restrict__ Wn, const float* __restrict__ bn,
                           float* __restrict__ probs, float* __restrict__ hsumP,
                           int n) {
  __shared__ float shsum[64];
  int lane = threadIdx.x & 63;
  int wv = blockIdx.x * (blockDim.x >> 6) + (threadIdx.x >> 6);
  int v0 = wv * 16;
  bool act = v0 < n;
  int r16 = lane & 15, hi = lane >> 4;
  if (hout && threadIdx.x < 64) shsum[threadIdx.x] = 0.f;
  bf16x8 bfr[4][4];
#pragma unroll
  for (int ks = 0; ks < 4; ++ks)
#pragma unroll
    for (int jt = 0; jt < 4; ++jt)
      bfr[ks][jt] = *(const bf16x8*)(wut + (jt * 16 + r16) * 128 + ks * 32 + hi * 8);
  f32x4 acc[4];
#pragma unroll
  for (int jt = 0; jt < 4; ++jt) {
    float b = bu[jt * 16 + r16];
    acc[jt] = (f32x4){b, b, b, b};
  }
  bf16x8 afr[4];
  int row = v0 + r16;
  if (act && row < n) {
    const unsigned short* hrow = hb   + (size_t)row * H + hi * 8;
    const unsigned short* arow = aggb + (size_t)row * H + hi * 8;
    afr[0] = *(const bf16x8*)(hrow);
    afr[1] = *(const bf16x8*)(hrow + 32);
    afr[2] = *(const bf16x8*)(arow);
    afr[3] = *(const bf16x8*)(arow + 32);
  } else {
    afr[0] = afr[1] = afr[2] = afr[3] = (bf16x8){0,0,0,0,0,0,0,0};
  }
#pragma unroll
  for (int ks = 0; ks < 4; ++ks)
#pragma unroll
    for (int jt = 0; jt < 4; ++jt)
      acc[jt] = __builtin_amdgcn_mfma_f32_16x16x32_bf16(afr[ks], bfr[ks][jt], acc[jt], 0, 0, 0);
  float ov[4][4];
#pragma unroll
  for (int jt = 0; jt < 4; ++jt) {
    int col = jt * 16 + r16;
#pragma unroll
    for (int r = 0; r < 4; ++r) {
      int orow = v0 + hi * 4 + r;
      bool ok = act && orow < n;
      float o = fmaxf(acc[jt][r], 0.f);
      ov[jt][r] = ok ? o : 0.f;
      if (ok) {
        hb_out[(size_t)orow * H + col] = f2bf(o);
        if (hout) hout[(size_t)orow * H + col] = o;
      }
    }
  }
  if (hout) {
    float bn0 = bn[0];
    float lg[4] = {0.f, 0.f, 0.f, 0.f};
#pragma unroll
    for (int jt = 0; jt < 4; ++jt) {
      float w = Wn[jt * 16 + r16];
#pragma unroll
      for (int r = 0; r < 4; ++r) lg[r] = fmaf(ov[jt][r], w, lg[r]);
    }
#pragma unroll
    for (int d = 1; d < 16; d <<= 1) {
#pragma unroll
      for (int r = 0; r < 4; ++r) lg[r] += __shfl_xor(lg[r], d);
    }
    if (r16 == 0) {
#pragma unroll
      for (int r = 0; r < 4; ++r) {
        int orow = v0 + hi * 4 + r;
        if (act && orow < n) probs[orow] = 1.f / (1.f + expf(-(lg[r] + bn0)));
      }
    }
    __syncthreads();
#pragma unroll
    for (int jt = 0; jt < 4; ++jt) {
      float s = ov[jt][0] + ov[jt][1] + ov[jt][2] + ov[jt][3];
      s += __shfl_xor(s, 16); s += __shfl_xor(s, 32);
      if (hi == 0) atomicAdd(&shsum[jt * 16 + r16], s);
    }
    __syncthreads();
    if (threadIdx.x < 64)
      atomicAdd(&hsumP[((blockIdx.x & 7) << 6) + threadIdx.x], shsum[threadIdx.x]);
  }
}

// ---- global mean + 2-layer head (tiny) ----
__global__ void k_final(const float* __restrict__ hsumP,
                        const float* __restrict__ W1, const float* __restrict__ b1,
                        const float* __restrict__ W2, const float* __restrict__ b2,
                        float* __restrict__ out4, float n_nodes) {
  __shared__ float hmean[64];
  __shared__ float z1[32];
  int tid = threadIdx.x;
  if (tid < 64) {
    float s = 0.f;
#pragma unroll
    for (int b = 0; b < 8; ++b) s += hsumP[b * 64 + tid];
    hmean[tid] = s / n_nodes;
  }
  __syncthreads();
  if (tid < 32) {
    float a = b1[tid];
    for (int k = 0; k < 64; ++k) a = fmaf(hmean[k], W1[k * 32 + tid], a);
    z1[tid] = fmaxf(a, 0.f);
  }
  __syncthreads();
  if (tid < 4) {
    float a = b2[tid];
    for (int k = 0; k < 32; ++k) a = fmaf(z1[k], W2[k * 4 + tid], a);
    out4[tid] = a;
  }
}

extern "C" void kernel_launch(void* const* d_in, const int* in_sizes, int n_in,
                              void* d_out, int out_size, void* d_ws, size_t ws_size,
                              hipStream_t stream) {
  const float* x    = (const float*)d_in[0];
  const int*   ei   = (const int*)d_in[1];
  const float* ea   = (const float*)d_in[2];
  const float* Win  = (const float*)d_in[3];
  const float* bin  = (const float*)d_in[4];
  const float* Wmsg = (const float*)d_in[5];
  const float* bmsg = (const float*)d_in[6];
  const float* Wupd = (const float*)d_in[7];
  const float* bupd = (const float*)d_in[8];
  const float* Wn   = (const float*)d_in[9];
  const float* bn   = (const float*)d_in[10];
  const float* W1   = (const float*)d_in[13];
  const float* b1   = (const float*)d_in[14];
  const float* W2   = (const float*)d_in[15];
  const float* b2   = (const float*)d_in[16];

  const int N = in_sizes[0] / 2;
  const int E = in_sizes[1] / 2;
  const int* src = ei;
  const int* dst = ei + E;

  char* ws = (char*)d_ws;
  size_t off = 0;
  auto alloc = [&](size_t bytes) {
    void* p = ws + off;
    off = (off + bytes + 255) & ~(size_t)255;
    return p;
  };
  int*   hist = (int*)  alloc((size_t)N * 4);
  int*   rptr = (int*)  alloc((size_t)(N + 1) * 4);
  int*   pos  = (int*)  alloc((size_t)N * 4);
  int*   bsum = (int*)  alloc((size_t)1024 * 4);
  int*   bcur = (int*)  alloc((size_t)64 * 4);
  u64*   staged = (u64*)alloc((size_t)E * 8);
  u64*   erec = (u64*)  alloc((size_t)E * 8);
  unsigned short* hb   = (unsigned short*)alloc((size_t)N * H * 2);
  unsigned short* g    = (unsigned short*)alloc((size_t)N * H * 2);
  unsigned short* aggb = (unsigned short*)alloc((size_t)N * H * 2);
  unsigned short* WmT  = (unsigned short*)alloc((size_t)3 * 64 * 64 * 2);
  unsigned short* WuT  = (unsigned short*)alloc((size_t)3 * 64 * 128 * 2);
  float* hsumP = (float*)alloc(8 * 64 * 4);
  (void)ws_size;

  float* probs = (float*)d_out;          // [N]
  float* out4  = probs + N;              // [4]
  float* h     = out4 + 4;               // [N, 64] fp32 final embeddings

  int eb = (E + 255) / 256;
  int sb = (N + 1023) / 1024;
  k_zero<<<(N + 255) / 256, 256, 0, stream>>>(hist, hsumP, N);
  k_hist<<<eb, 256, 0, stream>>>(dst, hist, E);
  k_scan1<<<sb, 256, 0, stream>>>(hist, bsum, N);
  k_scan2<<<1, 1024, 0, stream>>>(bsum, sb);
  k_scan3<<<sb, 256, 0, stream>>>(hist, bsum, rptr, pos, N);

  int B = (N + 1023) >> 10;   // dst-buckets of 1024 nodes; B<=64 also implies src fits 16 bits
  if (B <= 64) {
    k_binit<<<1, 64, 0, stream>>>(rptr, bcur, B);
    k_part<<<(E + 2047) / 2048, 256, 0, stream>>>(src, dst, (const float2*)ea,
                                                  bcur, staged, E, B);
    k_place<<<B, 1024, 0, stream>>>(staged, rptr, erec, N);
  } else {
    k_scatter<<<eb, 256, 0, stream>>>(src, dst, ea, pos, erec, E);  // fallback
  }
  k_wprep<<<3, 256, 0, stream>>>(Wmsg, Wupd, WmT, WuT);

  k_inproj<<<(N * 64 + 255) / 256, 256, 0, stream>>>(x, Win, bin, hb, N);

  int tiles = (N + 15) / 16;
  int mb = (tiles + 3) / 4;
  int ab = 2048;              // persistent k_agg: 8192 waves grid-stride
  for (int l = 0; l < 3; ++l) {
    k_gemm_mfma<<<mb, 256, 0, stream>>>(hb, WmT + (size_t)l * 64 * 64, g, N);
    k_agg<<<ab, 256, 0, stream>>>(g, rptr, erec,
                                  Wmsg + (size_t)l * 66 * 64 + 64 * 64,
                                  bmsg + (size_t)l * 64, aggb, N);
    k_upd_mfma<<<mb, 256, 0, stream>>>(hb, aggb, WuT + (size_t)l * 64 * 128,
                                       bupd + (size_t)l * 64, hb,
                                       (l == 2) ? h : nullptr,
                                       Wn, bn, probs, hsumP, N);
  }

  k_final<<<1, 64, 0, stream>>>(hsumP, W1, b1, W2, b2, out4, (float)N);
}

// Round 10
// 223.754 us; speedup vs baseline: 4.9140x; 1.1626x over previous
//
#include <hip/hip_runtime.h>
#include <math.h>

constexpr int H = 64;

typedef __attribute__((ext_vector_type(8))) short bf16x8;
typedef __attribute__((ext_vector_type(4))) float f32x4;
typedef unsigned long long u64;

__device__ inline unsigned short f2bf(float f) {
  union { float f; unsigned int u; } c; c.f = f;
  unsigned int u = c.u;
  return (unsigned short)((u + 0x7FFF + ((u >> 16) & 1)) >> 16);  // RNE
}
__device__ inline float bf2f(unsigned int s) {
  union { unsigned int u; float f; } c; c.u = s << 16;
  return c.f;
}

// ---- prep: zero hist+hsumP, transpose+bf16 weights (one kernel) ----
__global__ void k_prep(int* __restrict__ hist, float* __restrict__ hsumP,
                       const float* __restrict__ Wmsg, const float* __restrict__ Wupd,
                       unsigned short* __restrict__ WmT, unsigned short* __restrict__ WuT,
                       int n) {
  int t = blockIdx.x * blockDim.x + threadIdx.x;
  if (t < n) hist[t] = 0;
  if (t < 512) hsumP[t] = 0.f;
  int u = t - n;
  if (u >= 0 && u < 3 * 12288) {
    int l = u / 12288, rem = u % 12288;
    if (rem < 4096) {
      int j = rem >> 6, k = rem & 63;
      WmT[l * 4096 + rem] = f2bf(Wmsg[(size_t)l * 66 * 64 + k * 64 + j]);
    } else {
      int r2 = rem - 4096;
      int j = r2 >> 7, k = r2 & 127;
      WuT[l * 8192 + r2] = f2bf(Wupd[(size_t)l * 128 * 64 + k * 64 + j]);
    }
  }
}

// ---- CSR build ----
__global__ void k_hist(const int* __restrict__ dst, int* __restrict__ hist, int E) {
  int e = blockIdx.x * blockDim.x + threadIdx.x;
  if (e < E) atomicAdd(&hist[dst[e]], 1);
}

__global__ void k_scan1(const int* __restrict__ hist, int* __restrict__ bsum, int n) {
  __shared__ int sred[256];
  int tid = threadIdx.x;
  int base = blockIdx.x * 1024 + tid * 4;
  int s = 0;
#pragma unroll
  for (int k = 0; k < 4; ++k) { int i = base + k; if (i < n) s += hist[i]; }
  sred[tid] = s;
  __syncthreads();
  for (int d = 128; d > 0; d >>= 1) {
    if (tid < d) sred[tid] += sred[tid + d];
    __syncthreads();
  }
  if (tid == 0) bsum[blockIdx.x] = sred[0];
}

// exclusive scan of block sums; also seeds bcur (bsum[b] == rptr[b<<10])
__global__ void k_scan2(int* __restrict__ bsum, int* __restrict__ bcur, int nb) {
  __shared__ int sd[1024];
  int tid = threadIdx.x;
  int v = (tid < nb) ? bsum[tid] : 0;
  sd[tid] = v;
  __syncthreads();
  for (int d = 1; d < 1024; d <<= 1) {
    int t = (tid >= d) ? sd[tid - d] : 0;
    __syncthreads();
    sd[tid] += t;
    __syncthreads();
  }
  if (tid < nb) {
    int ex = sd[tid] - v;
    bsum[tid] = ex;
    bcur[tid] = ex;
  }
}

__global__ void k_scan3(const int* __restrict__ hist, const int* __restrict__ bsum,
                        int* __restrict__ row_ptr, int* __restrict__ pos, int n) {
  __shared__ int sth[256];
  int tid = threadIdx.x;
  int base = blockIdx.x * 1024 + tid * 4;
  int v[4]; int s = 0;
#pragma unroll
  for (int k = 0; k < 4; ++k) { int i = base + k; v[k] = (i < n) ? hist[i] : 0; s += v[k]; }
  sth[tid] = s;
  __syncthreads();
  for (int d = 1; d < 256; d <<= 1) {
    int t = (tid >= d) ? sth[tid - d] : 0;
    __syncthreads();
    sth[tid] += t;
    __syncthreads();
  }
  int run = bsum[blockIdx.x] + sth[tid] - s;
  if (blockIdx.x == 0 && tid == 0) row_ptr[0] = 0;
#pragma unroll
  for (int k = 0; k < 4; ++k) {
    int i = base + k;
    if (i < n) {
      pos[i] = run;
      run += v[k];
      row_ptr[i + 1] = run;
    }
  }
}

// ---- bucketed two-phase edge placement; 8B packed record:
//      [15:0]=src  [25:16]=dst&1023  [31:26]=bucket  [63:32]=ea as 2xbf16 ----
__global__ void k_part(const int* __restrict__ src, const int* __restrict__ dst,
                       const float2* __restrict__ ea2, int* __restrict__ bcur,
                       u64* __restrict__ staged, int E, int B) {
  __shared__ u64 srt[2048];                   // 16 KB
  __shared__ int cnt[64], offs[64], gbase[64];
  int tid = threadIdx.x;
  int base = blockIdx.x * 2048;
  if (tid < 64) cnt[tid] = 0;
  __syncthreads();
  u64 rec_[8]; int bk_[8], rk_[8];
#pragma unroll
  for (int k = 0; k < 8; ++k) {
    int e = base + k * 256 + tid;
    if (e < E) {
      int d = dst[e];
      int bk = d >> 10;
      float2 eav = ea2[e];
      unsigned int eap = (unsigned int)f2bf(eav.x) | ((unsigned int)f2bf(eav.y) << 16);
      rec_[k] = (u64)(unsigned int)(src[e] & 0xFFFF)
              | ((u64)(unsigned int)(d & 1023) << 16)
              | ((u64)(unsigned int)bk << 26)
              | ((u64)eap << 32);
      bk_[k] = bk;
      rk_[k] = atomicAdd(&cnt[bk], 1);
    } else bk_[k] = -1;
  }
  __syncthreads();
  if (tid == 0) {
    int run = 0;
    for (int b = 0; b < B; ++b) { offs[b] = run; run += cnt[b]; }
  }
  __syncthreads();
#pragma unroll
  for (int k = 0; k < 8; ++k)
    if (bk_[k] >= 0) srt[offs[bk_[k]] + rk_[k]] = rec_[k];
  __syncthreads();
  if (tid < B && cnt[tid] > 0) gbase[tid] = atomicAdd(&bcur[tid], cnt[tid]);
  __syncthreads();
  int total = (base + 2048 <= E) ? 2048 : (E > base ? E - base : 0);
  for (int i = tid; i < total; i += 256) {
    u64 r = srt[i];
    int bk = (int)((r >> 26) & 63u);
    staged[gbase[bk] + (i - offs[bk])] = r;   // bucket-contiguous full-line appends
  }
}

// Phase B: one workgroup per bucket -> final dst-sorted erec {src, ea}, L2-local writes
__global__ void k_place(const u64* __restrict__ staged, const int* __restrict__ rptr,
                        u64* __restrict__ erec, int N_) {
  __shared__ int cnt2[1024];
  __shared__ int rptrL[1025];
  int b = blockIdx.x;
  int nd0 = b << 10;
  int nn = min(nd0 + 1024, N_) - nd0;
  int tid = threadIdx.x;  // 1024 threads
  if (tid < nn) { cnt2[tid] = 0; rptrL[tid] = rptr[nd0 + tid]; }
  if (tid == 0) rptrL[nn] = rptr[nd0 + nn];
  __syncthreads();
  int beg = rptrL[0], end = rptrL[nn];
  for (int i = beg + tid; i < end; i += 1024) {
    u64 r = staged[i];
    int dl = (int)((r >> 16) & 1023u);
    int p = rptrL[dl] + atomicAdd(&cnt2[dl], 1);
    erec[p] = (r & 0xFFFFull) | ((r >> 32) << 32);
  }
}

// ---- fallback single-pass scatter (only if N > 65536) ----
__global__ void k_scatter(const int* __restrict__ src, const int* __restrict__ dst,
                          const float* __restrict__ ea, int* __restrict__ pos,
                          u64* __restrict__ erec, int E) {
  int e = blockIdx.x * blockDim.x + threadIdx.x;
  if (e < E) {
    int d = dst[e];
    int p = atomicAdd(&pos[d], 1);
    u64 lo = f2bf(ea[2 * e]);
    u64 hi = f2bf(ea[2 * e + 1]);
    erec[p] = (u64)(unsigned int)src[e] | ((lo | (hi << 16)) << 32);
  }
}

// ---- fused input projection + gemm0: hb = bf16(x@Win+bin); g = bf16(hb @ Wm1[0]) ----
__global__ void k_inproj_gemm(const float* __restrict__ x, const float* __restrict__ Win,
                              const float* __restrict__ bin,
                              const unsigned short* __restrict__ wmt,
                              unsigned short* __restrict__ hb,
                              unsigned short* __restrict__ g, int n) {
  int lane = threadIdx.x & 63;
  int wv = blockIdx.x * (blockDim.x >> 6) + (threadIdx.x >> 6);
  int v0 = wv * 16;
  if (v0 >= n) return;
  int r16 = lane & 15, hi = lane >> 4;
  int row = v0 + r16;
  float x0 = 0.f, x1 = 0.f;
  if (row < n) { x0 = x[2 * row]; x1 = x[2 * row + 1]; }
  union { bf16x8 v; unsigned short u[8]; } af[2];
#pragma unroll
  for (int s = 0; s < 2; ++s)
#pragma unroll
    for (int t = 0; t < 8; ++t) {
      int j = s * 32 + hi * 8 + t;
      af[s].u[t] = f2bf(fmaf(x0, Win[j], fmaf(x1, Win[64 + j], bin[j])));
    }
  if (row < n) {
    *(bf16x8*)(hb + (size_t)row * H + hi * 8)      = af[0].v;
    *(bf16x8*)(hb + (size_t)row * H + 32 + hi * 8) = af[1].v;
  }
  bf16x8 bfr[2][4];
#pragma unroll
  for (int ks = 0; ks < 2; ++ks)
#pragma unroll
    for (int jt = 0; jt < 4; ++jt)
      bfr[ks][jt] = *(const bf16x8*)(wmt + (jt * 16 + r16) * 64 + ks * 32 + hi * 8);
  f32x4 acc[4] = {};
#pragma unroll
  for (int ks = 0; ks < 2; ++ks)
#pragma unroll
    for (int jt = 0; jt < 4; ++jt)
      acc[jt] = __builtin_amdgcn_mfma_f32_16x16x32_bf16(af[ks].v, bfr[ks][jt], acc[jt], 0, 0, 0);
#pragma unroll
  for (int jt = 0; jt < 4; ++jt) {
    int col = jt * 16 + r16;
#pragma unroll
    for (int r = 0; r < 4; ++r) {
      int orow = v0 + hi * 4 + r;
      if (orow < n) g[(size_t)orow * H + col] = f2bf(acc[jt][r]);
    }
  }
}

// ---- aggregation: one 16-lane group PER NODE, 4-edge unroll (engages at deg>=4) ----
__global__ void k_agg(const unsigned short* __restrict__ g, const int* __restrict__ row_ptr,
                      const u64* __restrict__ erec,
                      const float* __restrict__ Wm2, const float* __restrict__ bm,
                      unsigned short* __restrict__ aggb, int n) {
  int r = threadIdx.x & 15;
  int j0 = r * 4;
  float4 w2a = *(const float4*)(Wm2 + j0);
  float4 w2b = *(const float4*)(Wm2 + 64 + j0);
  float4 bm4 = *(const float4*)(bm + j0);
  int gg = blockIdx.x * (blockDim.x >> 4) + (threadIdx.x >> 4);
  int ng = gridDim.x * (blockDim.x >> 4);
  for (int v = gg; v < n; v += ng) {
    int beg = row_ptr[v], end = row_ptr[v + 1];
    float a0 = 0.f, a1 = 0.f, a2 = 0.f, a3 = 0.f;
    int i = beg;
    for (; i + 3 < end; i += 4) {  // 4 independent gather chains per group
      u64 rA = erec[i], rB = erec[i + 1], rC = erec[i + 2], rD = erec[i + 3];
      uint2 gwA = *(const uint2*)(g + (size_t)(unsigned int)rA * H + j0);
      uint2 gwB = *(const uint2*)(g + (size_t)(unsigned int)rB * H + j0);
      uint2 gwC = *(const uint2*)(g + (size_t)(unsigned int)rC * H + j0);
      uint2 gwD = *(const uint2*)(g + (size_t)(unsigned int)rD * H + j0);
      unsigned int eA = (unsigned int)(rA >> 32), eB = (unsigned int)(rB >> 32);
      unsigned int eC = (unsigned int)(rC >> 32), eD = (unsigned int)(rD >> 32);
      float eA0 = bf2f(eA & 0xffffu), eA1 = bf2f(eA >> 16);
      float eB0 = bf2f(eB & 0xffffu), eB1 = bf2f(eB >> 16);
      float eC0 = bf2f(eC & 0xffffu), eC1 = bf2f(eC >> 16);
      float eD0 = bf2f(eD & 0xffffu), eD1 = bf2f(eD >> 16);
      a0 += fmaxf(fmaf(eA0, w2a.x, fmaf(eA1, w2b.x, bf2f(gwA.x & 0xffffu) + bm4.x)), 0.f)
          + fmaxf(fmaf(eB0, w2a.x, fmaf(eB1, w2b.x, bf2f(gwB.x & 0xffffu) + bm4.x)), 0.f)
          + fmaxf(fmaf(eC0, w2a.x, fmaf(eC1, w2b.x, bf2f(gwC.x & 0xffffu) + bm4.x)), 0.f)
          + fmaxf(fmaf(eD0, w2a.x, fmaf(eD1, w2b.x, bf2f(gwD.x & 0xffffu) + bm4.x)), 0.f);
      a1 += fmaxf(fmaf(eA0, w2a.y, fmaf(eA1, w2b.y, bf2f(gwA.x >> 16) + bm4.y)), 0.f)
          + fmaxf(fmaf(eB0, w2a.y, fmaf(eB1, w2b.y, bf2f(gwB.x >> 16) + bm4.y)), 0.f)
          + fmaxf(fmaf(eC0, w2a.y, fmaf(eC1, w2b.y, bf2f(gwC.x >> 16) + bm4.y)), 0.f)
          + fmaxf(fmaf(eD0, w2a.y, fmaf(eD1, w2b.y, bf2f(gwD.x >> 16) + bm4.y)), 0.f);
      a2 += fmaxf(fmaf(eA0, w2a.z, fmaf(eA1, w2b.z, bf2f(gwA.y & 0xffffu) + bm4.z)), 0.f)
          + fmaxf(fmaf(eB0, w2a.z, fmaf(eB1, w2b.z, bf2f(gwB.y & 0xffffu) + bm4.z)), 0.f)
          + fmaxf(fmaf(eC0, w2a.z, fmaf(eC1, w2b.z, bf2f(gwC.y & 0xffffu) + bm4.z)), 0.f)
          + fmaxf(fmaf(eD0, w2a.z, fmaf(eD1, w2b.z, bf2f(gwD.y & 0xffffu) + bm4.z)), 0.f);
      a3 += fmaxf(fmaf(eA0, w2a.w, fmaf(eA1, w2b.w, bf2f(gwA.y >> 16) + bm4.w)), 0.f)
          + fmaxf(fmaf(eB0, w2a.w, fmaf(eB1, w2b.w, bf2f(gwB.y >> 16) + bm4.w)), 0.f)
          + fmaxf(fmaf(eC0, w2a.w, fmaf(eC1, w2b.w, bf2f(gwC.y >> 16) + bm4.w)), 0.f)
          + fmaxf(fmaf(eD0, w2a.w, fmaf(eD1, w2b.w, bf2f(gwD.y >> 16) + bm4.w)), 0.f);
    }
    for (; i < end; ++i) {
      u64 rA = erec[i];
      uint2 gwA = *(const uint2*)(g + (size_t)(unsigned int)rA * H + j0);
      unsigned int eA = (unsigned int)(rA >> 32);
      float eA0 = bf2f(eA & 0xffffu), eA1 = bf2f(eA >> 16);
      a0 += fmaxf(fmaf(eA0, w2a.x, fmaf(eA1, w2b.x, bf2f(gwA.x & 0xffffu) + bm4.x)), 0.f);
      a1 += fmaxf(fmaf(eA0, w2a.y, fmaf(eA1, w2b.y, bf2f(gwA.x >> 16) + bm4.y)), 0.f);
      a2 += fmaxf(fmaf(eA0, w2a.z, fmaf(eA1, w2b.z, bf2f(gwA.y & 0xffffu) + bm4.z)), 0.f);
      a3 += fmaxf(fmaf(eA0, w2a.w, fmaf(eA1, w2b.w, bf2f(gwA.y >> 16) + bm4.w)), 0.f);
    }
    float inv = 1.f / fmaxf((float)(end - beg), 1.f);
    unsigned int p0 = f2bf(a0 * inv) | ((unsigned int)f2bf(a1 * inv) << 16);
    unsigned int p1 = f2bf(a2 * inv) | ((unsigned int)f2bf(a3 * inv) << 16);
    *(uint2*)(aggb + (size_t)v * H + j0) = make_uint2(p0, p1);
  }
}

// ---- fused update MLP + (next-layer gemm | node head) ----
__global__ void k_updgemm(const unsigned short* __restrict__ hb,
                          const unsigned short* __restrict__ aggb,
                          const unsigned short* __restrict__ wut,
                          const float* __restrict__ bu,
                          const unsigned short* __restrict__ wmt_next, // null on last layer
                          unsigned short* __restrict__ hb_out,
                          unsigned short* __restrict__ g_out,
                          float* __restrict__ hout,                    // non-null on last layer
                          const float* __restrict__ Wn, const float* __restrict__ bn,
                          float* __restrict__ probs, float* __restrict__ hsumP,
                          int n) {
  __shared__ __align__(16) unsigned short hstage[4][16][72];  // +8 pad: kills stride-128B bank conflict
  __shared__ float shsum[64];
  int lane = threadIdx.x & 63;
  int w = threadIdx.x >> 6;
  int wv = blockIdx.x * (blockDim.x >> 6) + w;
  int v0 = wv * 16;
  bool act = v0 < n;
  int r16 = lane & 15, hi = lane >> 4;
  if (hout && threadIdx.x < 64) shsum[threadIdx.x] = 0.f;
  bf16x8 bfr[4][4];
#pragma unroll
  for (int ks = 0; ks < 4; ++ks)
#pragma unroll
    for (int jt = 0; jt < 4; ++jt)
      bfr[ks][jt] = *(const bf16x8*)(wut + (jt * 16 + r16) * 128 + ks * 32 + hi * 8);
  f32x4 acc[4];
#pragma unroll
  for (int jt = 0; jt < 4; ++jt) {
    float b = bu[jt * 16 + r16];
    acc[jt] = (f32x4){b, b, b, b};
  }
  bf16x8 afr[4];
  int row = v0 + r16;
  if (act && row < n) {
    const unsigned short* hrow = hb   + (size_t)row * H + hi * 8;
    const unsigned short* arow = aggb + (size_t)row * H + hi * 8;
    afr[0] = *(const bf16x8*)(hrow);
    afr[1] = *(const bf16x8*)(hrow + 32);
    afr[2] = *(const bf16x8*)(arow);
    afr[3] = *(const bf16x8*)(arow + 32);
  } else {
    afr[0] = afr[1] = afr[2] = afr[3] = (bf16x8){0,0,0,0,0,0,0,0};
  }
#pragma unroll
  for (int ks = 0; ks < 4; ++ks)
#pragma unroll
    for (int jt = 0; jt < 4; ++jt)
      acc[jt] = __builtin_amdgcn_mfma_f32_16x16x32_bf16(afr[ks], bfr[ks][jt], acc[jt], 0, 0, 0);
  float ov[4][4];
  unsigned short ob[4][4];
#pragma unroll
  for (int jt = 0; jt < 4; ++jt) {
    int col = jt * 16 + r16;
#pragma unroll
    for (int r = 0; r < 4; ++r) {
      int orow = v0 + hi * 4 + r;
      bool ok = act && orow < n;
      float o = fmaxf(acc[jt][r], 0.f);
      ov[jt][r] = ok ? o : 0.f;
      ob[jt][r] = f2bf(ov[jt][r]);
      if (ok) {
        hb_out[(size_t)orow * H + col] = ob[jt][r];
        if (hout) hout[(size_t)orow * H + col] = o;
      }
    }
  }
  if (wmt_next) {
    // stage h_out through LDS to re-shape C-layout -> A-fragment layout
#pragma unroll
    for (int jt = 0; jt < 4; ++jt)
#pragma unroll
      for (int r = 0; r < 4; ++r)
        hstage[w][hi * 4 + r][jt * 16 + r16] = ob[jt][r];
    __syncthreads();
    bf16x8 af2[2];
    af2[0] = *(const bf16x8*)(&hstage[w][r16][hi * 8]);
    af2[1] = *(const bf16x8*)(&hstage[w][r16][32 + hi * 8]);
    bf16x8 bf2r[2][4];
#pragma unroll
    for (int ks = 0; ks < 2; ++ks)
#pragma unroll
      for (int jt = 0; jt < 4; ++jt)
        bf2r[ks][jt] = *(const bf16x8*)(wmt_next + (jt * 16 + r16) * 64 + ks * 32 + hi * 8);
    f32x4 acc2[4] = {};
#pragma unroll
    for (int ks = 0; ks < 2; ++ks)
#pragma unroll
      for (int jt = 0; jt < 4; ++jt)
        acc2[jt] = __builtin_amdgcn_mfma_f32_16x16x32_bf16(af2[ks], bf2r[ks][jt], acc2[jt], 0, 0, 0);
#pragma unroll
    for (int jt = 0; jt < 4; ++jt) {
      int col = jt * 16 + r16;
#pragma unroll
      for (int r = 0; r < 4; ++r) {
        int orow = v0 + hi * 4 + r;
        if (act && orow < n) g_out[(size_t)orow * H + col] = f2bf(acc2[jt][r]);
      }
    }
  } else {
    float bn0 = bn[0];
    float lg[4] = {0.f, 0.f, 0.f, 0.f};
#pragma unroll
    for (int jt = 0; jt < 4; ++jt) {
      float wn = Wn[jt * 16 + r16];
#pragma unroll
      for (int r = 0; r < 4; ++r) lg[r] = fmaf(ov[jt][r], wn, lg[r]);
    }
#pragma unroll
    for (int d = 1; d < 16; d <<= 1) {
#pragma unroll
      for (int r = 0; r < 4; ++r) lg[r] += __shfl_xor(lg[r], d);
    }
    if (r16 == 0) {
#pragma unroll
      for (int r = 0; r < 4; ++r) {
        int orow = v0 + hi * 4 + r;
        if (act && orow < n) probs[orow] = 1.f / (1.f + expf(-(lg[r] + bn0)));
      }
    }
    __syncthreads();
#pragma unroll
    for (int jt = 0; jt < 4; ++jt) {
      float s = ov[jt][0] + ov[jt][1] + ov[jt][2] + ov[jt][3];
      s += __shfl_xor(s, 16); s += __shfl_xor(s, 32);
      if (hi == 0) atomicAdd(&shsum[jt * 16 + r16], s);
    }
    __syncthreads();
    if (threadIdx.x < 64)
      atomicAdd(&hsumP[((blockIdx.x & 7) << 6) + threadIdx.x], shsum[threadIdx.x]);
  }
}

// ---- global mean + 2-layer head (tiny) ----
__global__ void k_final(const float* __restrict__ hsumP,
                        const float* __restrict__ W1, const float* __restrict__ b1,
                        const float* __restrict__ W2, const float* __restrict__ b2,
                        float* __restrict__ out4, float n_nodes) {
  __shared__ float hmean[64];
  __shared__ float z1[32];
  int tid = threadIdx.x;
  if (tid < 64) {
    float s = 0.f;
#pragma unroll
    for (int b = 0; b < 8; ++b) s += hsumP[b * 64 + tid];
    hmean[tid] = s / n_nodes;
  }
  __syncthreads();
  if (tid < 32) {
    float a = b1[tid];
    for (int k = 0; k < 64; ++k) a = fmaf(hmean[k], W1[k * 32 + tid], a);
    z1[tid] = fmaxf(a, 0.f);
  }
  __syncthreads();
  if (tid < 4) {
    float a = b2[tid];
    for (int k = 0; k < 32; ++k) a = fmaf(z1[k], W2[k * 4 + tid], a);
    out4[tid] = a;
  }
}

extern "C" void kernel_launch(void* const* d_in, const int* in_sizes, int n_in,
                              void* d_out, int out_size, void* d_ws, size_t ws_size,
                              hipStream_t stream) {
  const float* x    = (const float*)d_in[0];
  const int*   ei   = (const int*)d_in[1];
  const float* ea   = (const float*)d_in[2];
  const float* Win  = (const float*)d_in[3];
  const float* bin  = (const float*)d_in[4];
  const float* Wmsg = (const float*)d_in[5];
  const float* bmsg = (const float*)d_in[6];
  const float* Wupd = (const float*)d_in[7];
  const float* bupd = (const float*)d_in[8];
  const float* Wn   = (const float*)d_in[9];
  const float* bn   = (const float*)d_in[10];
  const float* W1   = (const float*)d_in[13];
  const float* b1   = (const float*)d_in[14];
  const float* W2   = (const float*)d_in[15];
  const float* b2   = (const float*)d_in[16];

  const int N = in_sizes[0] / 2;
  const int E = in_sizes[1] / 2;
  const int* src = ei;
  const int* dst = ei + E;

  char* ws = (char*)d_ws;
  size_t off = 0;
  auto alloc = [&](size_t bytes) {
    void* p = ws + off;
    off = (off + bytes + 255) & ~(size_t)255;
    return p;
  };
  int*   hist = (int*)  alloc((size_t)N * 4);
  int*   rptr = (int*)  alloc((size_t)(N + 1) * 4);
  int*   pos  = (int*)  alloc((size_t)N * 4);
  int*   bsum = (int*)  alloc((size_t)1024 * 4);
  int*   bcur = (int*)  alloc((size_t)1024 * 4);
  u64*   staged = (u64*)alloc((size_t)E * 8);
  u64*   erec = (u64*)  alloc((size_t)E * 8);
  unsigned short* hb   = (unsigned short*)alloc((size_t)N * H * 2);
  unsigned short* g    = (unsigned short*)alloc((size_t)N * H * 2);
  unsigned short* aggb = (unsigned short*)alloc((size_t)N * H * 2);
  unsigned short* WmT  = (unsigned short*)alloc((size_t)3 * 64 * 64 * 2);
  unsigned short* WuT  = (unsigned short*)alloc((size_t)3 * 64 * 128 * 2);
  float* hsumP = (float*)alloc(8 * 64 * 4);
  (void)ws_size;

  float* probs = (float*)d_out;          // [N]
  float* out4  = probs + N;              // [4]
  float* h     = out4 + 4;               // [N, 64] fp32 final embeddings

  int eb = (E + 255) / 256;
  int sb = (N + 1023) / 1024;
  k_prep<<<(N + 3 * 12288 + 255) / 256, 256, 0, stream>>>(hist, hsumP, Wmsg, Wupd, WmT, WuT, N);
  k_hist<<<eb, 256, 0, stream>>>(dst, hist, E);
  k_scan1<<<sb, 256, 0, stream>>>(hist, bsum, N);
  k_scan2<<<1, 1024, 0, stream>>>(bsum, bcur, sb);
  k_scan3<<<sb, 256, 0, stream>>>(hist, bsum, rptr, pos, N);

  int B = (N + 1023) >> 10;   // dst-buckets of 1024 nodes; B<=64 implies src fits 16 bits
  if (B <= 64) {
    k_part<<<(E + 2047) / 2048, 256, 0, stream>>>(src, dst, (const float2*)ea,
                                                  bcur, staged, E, B);
    k_place<<<B, 1024, 0, stream>>>(staged, rptr, erec, N);
  } else {
    k_scatter<<<eb, 256, 0, stream>>>(src, dst, ea, pos, erec, E);  // fallback
  }

  int tiles = (N + 15) / 16;
  int mb = (tiles + 3) / 4;
  k_inproj_gemm<<<mb, 256, 0, stream>>>(x, Win, bin, WmT, hb, g, N);

  int ab = 2048;              // k_agg: 2048 blocks x 16 groups = 32768 node-groups
  for (int l = 0; l < 3; ++l) {
    k_agg<<<ab, 256, 0, stream>>>(g, rptr, erec,
                                  Wmsg + (size_t)l * 66 * 64 + 64 * 64,
                                  bmsg + (size_t)l * 64, aggb, N);
    k_updgemm<<<mb, 256, 0, stream>>>(hb, aggb, WuT + (size_t)l * 64 * 128,
                                      bupd + (size_t)l * 64,
                                      (l < 2) ? (WmT + (size_t)(l + 1) * 64 * 64) : nullptr,
                                      hb, g,
                                      (l == 2) ? h : nullptr,
                                      Wn, bn, probs, hsumP, N);
  }

  k_final<<<1, 64, 0, stream>>>(hsumP, W1, b1, W2, b2, out4, (float)N);
}

// Round 11
// 222.673 us; speedup vs baseline: 4.9379x; 1.0049x over previous
//
#include <hip/hip_runtime.h>
#include <math.h>

constexpr int H = 64;

typedef __attribute__((ext_vector_type(8))) short bf16x8;
typedef __attribute__((ext_vector_type(4))) float f32x4;
typedef unsigned long long u64;

__device__ inline unsigned short f2bf(float f) {
  union { float f; unsigned int u; } c; c.f = f;
  unsigned int u = c.u;
  return (unsigned short)((u + 0x7FFF + ((u >> 16) & 1)) >> 16);  // RNE
}
__device__ inline float bf2f(unsigned int s) {
  union { unsigned int u; float f; } c; c.u = s << 16;
  return c.f;
}

// ---- prep: zero hist+hsumP, transpose+bf16 weights (one kernel) ----
__global__ void k_prep(int* __restrict__ hist, float* __restrict__ hsumP,
                       const float* __restrict__ Wmsg, const float* __restrict__ Wupd,
                       unsigned short* __restrict__ WmT, unsigned short* __restrict__ WuT,
                       int n) {
  int t = blockIdx.x * blockDim.x + threadIdx.x;
  if (t < n) hist[t] = 0;
  if (t < 512) hsumP[t] = 0.f;
  int u = t - n;
  if (u >= 0 && u < 3 * 12288) {
    int l = u / 12288, rem = u % 12288;
    if (rem < 4096) {
      int j = rem >> 6, k = rem & 63;
      WmT[l * 4096 + rem] = f2bf(Wmsg[(size_t)l * 66 * 64 + k * 64 + j]);
    } else {
      int r2 = rem - 4096;
      int j = r2 >> 7, k = r2 & 127;
      WuT[l * 8192 + r2] = f2bf(Wupd[(size_t)l * 128 * 64 + k * 64 + j]);
    }
  }
}

// ---- CSR build ----
__global__ void k_hist(const int* __restrict__ dst, int* __restrict__ hist, int E) {
  int e = blockIdx.x * blockDim.x + threadIdx.x;
  if (e < E) atomicAdd(&hist[dst[e]], 1);
}

__global__ void k_scan1(const int* __restrict__ hist, int* __restrict__ bsum, int n) {
  __shared__ int sred[256];
  int tid = threadIdx.x;
  int base = blockIdx.x * 1024 + tid * 4;
  int s = 0;
#pragma unroll
  for (int k = 0; k < 4; ++k) { int i = base + k; if (i < n) s += hist[i]; }
  sred[tid] = s;
  __syncthreads();
  for (int d = 128; d > 0; d >>= 1) {
    if (tid < d) sred[tid] += sred[tid + d];
    __syncthreads();
  }
  if (tid == 0) bsum[blockIdx.x] = sred[0];
}

// exclusive scan of block sums; also seeds bcur (bsum[b] == rptr[b<<10])
__global__ void k_scan2(int* __restrict__ bsum, int* __restrict__ bcur, int nb) {
  __shared__ int sd[1024];
  int tid = threadIdx.x;
  int v = (tid < nb) ? bsum[tid] : 0;
  sd[tid] = v;
  __syncthreads();
  for (int d = 1; d < 1024; d <<= 1) {
    int t = (tid >= d) ? sd[tid - d] : 0;
    __syncthreads();
    sd[tid] += t;
    __syncthreads();
  }
  if (tid < nb) {
    int ex = sd[tid] - v;
    bsum[tid] = ex;
    bcur[tid] = ex;
  }
}

__global__ void k_scan3(const int* __restrict__ hist, const int* __restrict__ bsum,
                        int* __restrict__ row_ptr, int* __restrict__ pos, int n) {
  __shared__ int sth[256];
  int tid = threadIdx.x;
  int base = blockIdx.x * 1024 + tid * 4;
  int v[4]; int s = 0;
#pragma unroll
  for (int k = 0; k < 4; ++k) { int i = base + k; v[k] = (i < n) ? hist[i] : 0; s += v[k]; }
  sth[tid] = s;
  __syncthreads();
  for (int d = 1; d < 256; d <<= 1) {
    int t = (tid >= d) ? sth[tid - d] : 0;
    __syncthreads();
    sth[tid] += t;
    __syncthreads();
  }
  int run = bsum[blockIdx.x] + sth[tid] - s;
  if (blockIdx.x == 0 && tid == 0) row_ptr[0] = 0;
#pragma unroll
  for (int k = 0; k < 4; ++k) {
    int i = base + k;
    if (i < n) {
      pos[i] = run;
      run += v[k];
      row_ptr[i + 1] = run;
    }
  }
}

// ---- bucketed two-phase edge placement; 8B packed record:
//      [15:0]=src  [25:16]=dst&1023  [31:26]=bucket  [63:32]=ea as 2xbf16 ----
__global__ void k_part(const int* __restrict__ src, const int* __restrict__ dst,
                       const float2* __restrict__ ea2, int* __restrict__ bcur,
                       u64* __restrict__ staged, int E, int B) {
  __shared__ u64 srt[2048];                   // 16 KB
  __shared__ int cnt[64], offs[64], gbase[64];
  int tid = threadIdx.x;
  int base = blockIdx.x * 2048;
  if (tid < 64) cnt[tid] = 0;
  __syncthreads();
  u64 rec_[8]; int bk_[8], rk_[8];
#pragma unroll
  for (int k = 0; k < 8; ++k) {
    int e = base + k * 256 + tid;
    if (e < E) {
      int d = dst[e];
      int bk = d >> 10;
      float2 eav = ea2[e];
      unsigned int eap = (unsigned int)f2bf(eav.x) | ((unsigned int)f2bf(eav.y) << 16);
      rec_[k] = (u64)(unsigned int)(src[e] & 0xFFFF)
              | ((u64)(unsigned int)(d & 1023) << 16)
              | ((u64)(unsigned int)bk << 26)
              | ((u64)eap << 32);
      bk_[k] = bk;
      rk_[k] = atomicAdd(&cnt[bk], 1);
    } else bk_[k] = -1;
  }
  __syncthreads();
  if (tid == 0) {
    int run = 0;
    for (int b = 0; b < B; ++b) { offs[b] = run; run += cnt[b]; }
  }
  __syncthreads();
#pragma unroll
  for (int k = 0; k < 8; ++k)
    if (bk_[k] >= 0) srt[offs[bk_[k]] + rk_[k]] = rec_[k];
  __syncthreads();
  if (tid < B && cnt[tid] > 0) gbase[tid] = atomicAdd(&bcur[tid], cnt[tid]);
  __syncthreads();
  int total = (base + 2048 <= E) ? 2048 : (E > base ? E - base : 0);
  for (int i = tid; i < total; i += 256) {
    u64 r = srt[i];
    int bk = (int)((r >> 26) & 63u);
    staged[gbase[bk] + (i - offs[bk])] = r;   // bucket-contiguous full-line appends
  }
}

// Phase B: one workgroup per bucket -> final dst-sorted erec {src, ea}, L2-local writes
__global__ void k_place(const u64* __restrict__ staged, const int* __restrict__ rptr,
                        u64* __restrict__ erec, int N_) {
  __shared__ int cnt2[1024];
  __shared__ int rptrL[1025];
  int b = blockIdx.x;
  int nd0 = b << 10;
  int nn = min(nd0 + 1024, N_) - nd0;
  int tid = threadIdx.x;  // 1024 threads
  if (tid < nn) { cnt2[tid] = 0; rptrL[tid] = rptr[nd0 + tid]; }
  if (tid == 0) rptrL[nn] = rptr[nd0 + nn];
  __syncthreads();
  int beg = rptrL[0], end = rptrL[nn];
  for (int i = beg + tid; i < end; i += 1024) {
    u64 r = staged[i];
    int dl = (int)((r >> 16) & 1023u);
    int p = rptrL[dl] + atomicAdd(&cnt2[dl], 1);
    erec[p] = (r & 0xFFFFull) | ((r >> 32) << 32);
  }
}

// ---- fallback single-pass scatter (only if N > 65536) ----
__global__ void k_scatter(const int* __restrict__ src, const int* __restrict__ dst,
                          const float* __restrict__ ea, int* __restrict__ pos,
                          u64* __restrict__ erec, int E) {
  int e = blockIdx.x * blockDim.x + threadIdx.x;
  if (e < E) {
    int d = dst[e];
    int p = atomicAdd(&pos[d], 1);
    u64 lo = f2bf(ea[2 * e]);
    u64 hi = f2bf(ea[2 * e + 1]);
    erec[p] = (u64)(unsigned int)src[e] | ((lo | (hi << 16)) << 32);
  }
}

// ---- fused input projection + gemm0: hb = bf16(x@Win+bin); g = bf16(hb @ Wm1[0]) ----
__global__ void k_inproj_gemm(const float* __restrict__ x, const float* __restrict__ Win,
                              const float* __restrict__ bin,
                              const unsigned short* __restrict__ wmt,
                              unsigned short* __restrict__ hb,
                              unsigned short* __restrict__ g, int n) {
  int lane = threadIdx.x & 63;
  int wv = blockIdx.x * (blockDim.x >> 6) + (threadIdx.x >> 6);
  int v0 = wv * 16;
  if (v0 >= n) return;
  int r16 = lane & 15, hi = lane >> 4;
  int row = v0 + r16;
  float x0 = 0.f, x1 = 0.f;
  if (row < n) { x0 = x[2 * row]; x1 = x[2 * row + 1]; }
  union { bf16x8 v; unsigned short u[8]; } af[2];
#pragma unroll
  for (int s = 0; s < 2; ++s)
#pragma unroll
    for (int t = 0; t < 8; ++t) {
      int j = s * 32 + hi * 8 + t;
      af[s].u[t] = f2bf(fmaf(x0, Win[j], fmaf(x1, Win[64 + j], bin[j])));
    }
  if (row < n) {
    *(bf16x8*)(hb + (size_t)row * H + hi * 8)      = af[0].v;
    *(bf16x8*)(hb + (size_t)row * H + 32 + hi * 8) = af[1].v;
  }
  bf16x8 bfr[2][4];
#pragma unroll
  for (int ks = 0; ks < 2; ++ks)
#pragma unroll
    for (int jt = 0; jt < 4; ++jt)
      bfr[ks][jt] = *(const bf16x8*)(wmt + (jt * 16 + r16) * 64 + ks * 32 + hi * 8);
  f32x4 acc[4] = {};
#pragma unroll
  for (int ks = 0; ks < 2; ++ks)
#pragma unroll
    for (int jt = 0; jt < 4; ++jt)
      acc[jt] = __builtin_amdgcn_mfma_f32_16x16x32_bf16(af[ks].v, bfr[ks][jt], acc[jt], 0, 0, 0);
#pragma unroll
  for (int jt = 0; jt < 4; ++jt) {
    int col = jt * 16 + r16;
#pragma unroll
    for (int r = 0; r < 4; ++r) {
      int orow = v0 + hi * 4 + r;
      if (orow < n) g[(size_t)orow * H + col] = f2bf(acc[jt][r]);
    }
  }
}

// ---- per-chain accumulate: 8 feats from a uint4 (8 bf16) ----
__device__ inline void acc8(float* a, uint4 gw, float e0, float e1,
                            const float4 waL, const float4 waH,
                            const float4 wbL, const float4 wbH,
                            const float4 bL, const float4 bH) {
  a[0] += fmaxf(fmaf(e0, waL.x, fmaf(e1, wbL.x, bf2f(gw.x & 0xffffu) + bL.x)), 0.f);
  a[1] += fmaxf(fmaf(e0, waL.y, fmaf(e1, wbL.y, bf2f(gw.x >> 16)     + bL.y)), 0.f);
  a[2] += fmaxf(fmaf(e0, waL.z, fmaf(e1, wbL.z, bf2f(gw.y & 0xffffu) + bL.z)), 0.f);
  a[3] += fmaxf(fmaf(e0, waL.w, fmaf(e1, wbL.w, bf2f(gw.y >> 16)     + bL.w)), 0.f);
  a[4] += fmaxf(fmaf(e0, waH.x, fmaf(e1, wbH.x, bf2f(gw.z & 0xffffu) + bH.x)), 0.f);
  a[5] += fmaxf(fmaf(e0, waH.y, fmaf(e1, wbH.y, bf2f(gw.z >> 16)     + bH.y)), 0.f);
  a[6] += fmaxf(fmaf(e0, waH.z, fmaf(e1, wbH.z, bf2f(gw.w & 0xffffu) + bH.z)), 0.f);
  a[7] += fmaxf(fmaf(e0, waH.w, fmaf(e1, wbH.w, bf2f(gw.w >> 16)     + bH.w)), 0.f);
}

// ---- aggregation: one 8-lane group PER NODE, 16B row-slices, 4 gather chains ----
__global__ void k_agg(const unsigned short* __restrict__ g, const int* __restrict__ row_ptr,
                      const u64* __restrict__ erec,
                      const float* __restrict__ Wm2, const float* __restrict__ bm,
                      unsigned short* __restrict__ aggb, int n) {
  int r = threadIdx.x & 7;
  int j0 = r * 8;                 // 8 features (16 B) per lane
  float4 waL = *(const float4*)(Wm2 + j0);
  float4 waH = *(const float4*)(Wm2 + j0 + 4);
  float4 wbL = *(const float4*)(Wm2 + 64 + j0);
  float4 wbH = *(const float4*)(Wm2 + 64 + j0 + 4);
  float4 bL  = *(const float4*)(bm + j0);
  float4 bH  = *(const float4*)(bm + j0 + 4);
  int v = blockIdx.x * (blockDim.x >> 3) + (threadIdx.x >> 3);
  if (v >= n) return;
  int beg = row_ptr[v], end = row_ptr[v + 1];
  float a[8] = {0.f, 0.f, 0.f, 0.f, 0.f, 0.f, 0.f, 0.f};
  int i = beg;
  for (; i + 3 < end; i += 4) {   // 4 independent 16B gather chains per group
    u64 rA = erec[i], rB = erec[i + 1], rC = erec[i + 2], rD = erec[i + 3];
    uint4 gwA = *(const uint4*)(g + (size_t)(unsigned int)rA * H + j0);
    uint4 gwB = *(const uint4*)(g + (size_t)(unsigned int)rB * H + j0);
    uint4 gwC = *(const uint4*)(g + (size_t)(unsigned int)rC * H + j0);
    uint4 gwD = *(const uint4*)(g + (size_t)(unsigned int)rD * H + j0);
    unsigned int eA = (unsigned int)(rA >> 32), eB = (unsigned int)(rB >> 32);
    unsigned int eC = (unsigned int)(rC >> 32), eD = (unsigned int)(rD >> 32);
    acc8(a, gwA, bf2f(eA & 0xffffu), bf2f(eA >> 16), waL, waH, wbL, wbH, bL, bH);
    acc8(a, gwB, bf2f(eB & 0xffffu), bf2f(eB >> 16), waL, waH, wbL, wbH, bL, bH);
    acc8(a, gwC, bf2f(eC & 0xffffu), bf2f(eC >> 16), waL, waH, wbL, wbH, bL, bH);
    acc8(a, gwD, bf2f(eD & 0xffffu), bf2f(eD >> 16), waL, waH, wbL, wbH, bL, bH);
  }
  for (; i < end; ++i) {
    u64 rA = erec[i];
    uint4 gwA = *(const uint4*)(g + (size_t)(unsigned int)rA * H + j0);
    unsigned int eA = (unsigned int)(rA >> 32);
    acc8(a, gwA, bf2f(eA & 0xffffu), bf2f(eA >> 16), waL, waH, wbL, wbH, bL, bH);
  }
  float inv = 1.f / fmaxf((float)(end - beg), 1.f);
  uint4 o;
  o.x = (unsigned int)f2bf(a[0] * inv) | ((unsigned int)f2bf(a[1] * inv) << 16);
  o.y = (unsigned int)f2bf(a[2] * inv) | ((unsigned int)f2bf(a[3] * inv) << 16);
  o.z = (unsigned int)f2bf(a[4] * inv) | ((unsigned int)f2bf(a[5] * inv) << 16);
  o.w = (unsigned int)f2bf(a[6] * inv) | ((unsigned int)f2bf(a[7] * inv) << 16);
  *(uint4*)(aggb + (size_t)v * H + j0) = o;
}

// ---- fused update MLP + (next-layer gemm | node head) ----
__global__ void k_updgemm(const unsigned short* __restrict__ hb,
                          const unsigned short* __restrict__ aggb,
                          const unsigned short* __restrict__ wut,
                          const float* __restrict__ bu,
                          const unsigned short* __restrict__ wmt_next, // null on last layer
                          unsigned short* __restrict__ hb_out,
                          unsigned short* __restrict__ g_out,
                          float* __restrict__ hout,                    // non-null on last layer
                          const float* __restrict__ Wn, const float* __restrict__ bn,
                          float* __restrict__ probs, float* __restrict__ hsumP,
                          int n) {
  __shared__ __align__(16) unsigned short hstage[4][16][72];  // +8 pad: kills stride-128B bank conflict
  __shared__ float shsum[64];
  int lane = threadIdx.x & 63;
  int w = threadIdx.x >> 6;
  int wv = blockIdx.x * (blockDim.x >> 6) + w;
  int v0 = wv * 16;
  bool act = v0 < n;
  int r16 = lane & 15, hi = lane >> 4;
  if (hout && threadIdx.x < 64) shsum[threadIdx.x] = 0.f;
  bf16x8 bfr[4][4];
#pragma unroll
  for (int ks = 0; ks < 4; ++ks)
#pragma unroll
    for (int jt = 0; jt < 4; ++jt)
      bfr[ks][jt] = *(const bf16x8*)(wut + (jt * 16 + r16) * 128 + ks * 32 + hi * 8);
  f32x4 acc[4];
#pragma unroll
  for (int jt = 0; jt < 4; ++jt) {
    float b = bu[jt * 16 + r16];
    acc[jt] = (f32x4){b, b, b, b};
  }
  bf16x8 afr[4];
  int row = v0 + r16;
  if (act && row < n) {
    const unsigned short* hrow = hb   + (size_t)row * H + hi * 8;
    const unsigned short* arow = aggb + (size_t)row * H + hi * 8;
    afr[0] = *(const bf16x8*)(hrow);
    afr[1] = *(const bf16x8*)(hrow + 32);
    afr[2] = *(const bf16x8*)(arow);
    afr[3] = *(const bf16x8*)(arow + 32);
  } else {
    afr[0] = afr[1] = afr[2] = afr[3] = (bf16x8){0,0,0,0,0,0,0,0};
  }
#pragma unroll
  for (int ks = 0; ks < 4; ++ks)
#pragma unroll
    for (int jt = 0; jt < 4; ++jt)
      acc[jt] = __builtin_amdgcn_mfma_f32_16x16x32_bf16(afr[ks], bfr[ks][jt], acc[jt], 0, 0, 0);
  float ov[4][4];
  unsigned short ob[4][4];
#pragma unroll
  for (int jt = 0; jt < 4; ++jt) {
    int col = jt * 16 + r16;
#pragma unroll
    for (int r = 0; r < 4; ++r) {
      int orow = v0 + hi * 4 + r;
      bool ok = act && orow < n;
      float o = fmaxf(acc[jt][r], 0.f);
      ov[jt][r] = ok ? o : 0.f;
      ob[jt][r] = f2bf(ov[jt][r]);
      if (ok) {
        hb_out[(size_t)orow * H + col] = ob[jt][r];
        if (hout) hout[(size_t)orow * H + col] = o;
      }
    }
  }
  if (wmt_next) {
    // stage h_out through LDS to re-shape C-layout -> A-fragment layout
#pragma unroll
    for (int jt = 0; jt < 4; ++jt)
#pragma unroll
      for (int r = 0; r < 4; ++r)
        hstage[w][hi * 4 + r][jt * 16 + r16] = ob[jt][r];
    __syncthreads();
    bf16x8 af2[2];
    af2[0] = *(const bf16x8*)(&hstage[w][r16][hi * 8]);
    af2[1] = *(const bf16x8*)(&hstage[w][r16][32 + hi * 8]);
    bf16x8 bf2r[2][4];
#pragma unroll
    for (int ks = 0; ks < 2; ++ks)
#pragma unroll
      for (int jt = 0; jt < 4; ++jt)
        bf2r[ks][jt] = *(const bf16x8*)(wmt_next + (jt * 16 + r16) * 64 + ks * 32 + hi * 8);
    f32x4 acc2[4] = {};
#pragma unroll
    for (int ks = 0; ks < 2; ++ks)
#pragma unroll
      for (int jt = 0; jt < 4; ++jt)
        acc2[jt] = __builtin_amdgcn_mfma_f32_16x16x32_bf16(af2[ks], bf2r[ks][jt], acc2[jt], 0, 0, 0);
#pragma unroll
    for (int jt = 0; jt < 4; ++jt) {
      int col = jt * 16 + r16;
#pragma unroll
      for (int r = 0; r < 4; ++r) {
        int orow = v0 + hi * 4 + r;
        if (act && orow < n) g_out[(size_t)orow * H + col] = f2bf(acc2[jt][r]);
      }
    }
  } else {
    float bn0 = bn[0];
    float lg[4] = {0.f, 0.f, 0.f, 0.f};
#pragma unroll
    for (int jt = 0; jt < 4; ++jt) {
      float wn = Wn[jt * 16 + r16];
#pragma unroll
      for (int r = 0; r < 4; ++r) lg[r] = fmaf(ov[jt][r], wn, lg[r]);
    }
#pragma unroll
    for (int d = 1; d < 16; d <<= 1) {
#pragma unroll
      for (int r = 0; r < 4; ++r) lg[r] += __shfl_xor(lg[r], d);
    }
    if (r16 == 0) {
#pragma unroll
      for (int r = 0; r < 4; ++r) {
        int orow = v0 + hi * 4 + r;
        if (act && orow < n) probs[orow] = 1.f / (1.f + expf(-(lg[r] + bn0)));
      }
    }
    __syncthreads();
#pragma unroll
    for (int jt = 0; jt < 4; ++jt) {
      float s = ov[jt][0] + ov[jt][1] + ov[jt][2] + ov[jt][3];
      s += __shfl_xor(s, 16); s += __shfl_xor(s, 32);
      if (hi == 0) atomicAdd(&shsum[jt * 16 + r16], s);
    }
    __syncthreads();
    if (threadIdx.x < 64)
      atomicAdd(&hsumP[((blockIdx.x & 7) << 6) + threadIdx.x], shsum[threadIdx.x]);
  }
}

// ---- global mean + 2-layer head (tiny) ----
__global__ void k_final(const float* __restrict__ hsumP,
                        const float* __restrict__ W1, const float* __restrict__ b1,
                        const float* __restrict__ W2, const float* __restrict__ b2,
                        float* __restrict__ out4, float n_nodes) {
  __shared__ float hmean[64];
  __shared__ float z1[32];
  int tid = threadIdx.x;
  if (tid < 64) {
    float s = 0.f;
#pragma unroll
    for (int b = 0; b < 8; ++b) s += hsumP[b * 64 + tid];
    hmean[tid] = s / n_nodes;
  }
  __syncthreads();
  if (tid < 32) {
    float a = b1[tid];
    for (int k = 0; k < 64; ++k) a = fmaf(hmean[k], W1[k * 32 + tid], a);
    z1[tid] = fmaxf(a, 0.f);
  }
  __syncthreads();
  if (tid < 4) {
    float a = b2[tid];
    for (int k = 0; k < 32; ++k) a = fmaf(z1[k], W2[k * 4 + tid], a);
    out4[tid] = a;
  }
}

extern "C" void kernel_launch(void* const* d_in, const int* in_sizes, int n_in,
                              void* d_out, int out_size, void* d_ws, size_t ws_size,
                              hipStream_t stream) {
  const float* x    = (const float*)d_in[0];
  const int*   ei   = (const int*)d_in[1];
  const float* ea   = (const float*)d_in[2];
  const float* Win  = (const float*)d_in[3];
  const float* bin  = (const float*)d_in[4];
  const float* Wmsg = (const float*)d_in[5];
  const float* bmsg = (const float*)d_in[6];
  const float* Wupd = (const float*)d_in[7];
  const float* bupd = (const float*)d_in[8];
  const float* Wn   = (const float*)d_in[9];
  const float* bn   = (const float*)d_in[10];
  const float* W1   = (const float*)d_in[13];
  const float* b1   = (const float*)d_in[14];
  const float* W2   = (const float*)d_in[15];
  const float* b2   = (const float*)d_in[16];

  const int N = in_sizes[0] / 2;
  const int E = in_sizes[1] / 2;
  const int* src = ei;
  const int* dst = ei + E;

  char* ws = (char*)d_ws;
  size_t off = 0;
  auto alloc = [&](size_t bytes) {
    void* p = ws + off;
    off = (off + bytes + 255) & ~(size_t)255;
    return p;
  };
  int*   hist = (int*)  alloc((size_t)N * 4);
  int*   rptr = (int*)  alloc((size_t)(N + 1) * 4);
  int*   pos  = (int*)  alloc((size_t)N * 4);
  int*   bsum = (int*)  alloc((size_t)1024 * 4);
  int*   bcur = (int*)  alloc((size_t)1024 * 4);
  u64*   staged = (u64*)alloc((size_t)E * 8);
  u64*   erec = (u64*)  alloc((size_t)E * 8);
  unsigned short* hb   = (unsigned short*)alloc((size_t)N * H * 2);
  unsigned short* g    = (unsigned short*)alloc((size_t)N * H * 2);
  unsigned short* aggb = (unsigned short*)alloc((size_t)N * H * 2);
  unsigned short* WmT  = (unsigned short*)alloc((size_t)3 * 64 * 64 * 2);
  unsigned short* WuT  = (unsigned short*)alloc((size_t)3 * 64 * 128 * 2);
  float* hsumP = (float*)alloc(8 * 64 * 4);
  (void)ws_size;

  float* probs = (float*)d_out;          // [N]
  float* out4  = probs + N;              // [4]
  float* h     = out4 + 4;               // [N, 64] fp32 final embeddings

  int eb = (E + 255) / 256;
  int sb = (N + 1023) / 1024;
  k_prep<<<(N + 3 * 12288 + 255) / 256, 256, 0, stream>>>(hist, hsumP, Wmsg, Wupd, WmT, WuT, N);
  k_hist<<<eb, 256, 0, stream>>>(dst, hist, E);
  k_scan1<<<sb, 256, 0, stream>>>(hist, bsum, N);
  k_scan2<<<1, 1024, 0, stream>>>(bsum, bcur, sb);
  k_scan3<<<sb, 256, 0, stream>>>(hist, bsum, rptr, pos, N);

  int B = (N + 1023) >> 10;   // dst-buckets of 1024 nodes; B<=64 implies src fits 16 bits
  if (B <= 64) {
    k_part<<<(E + 2047) / 2048, 256, 0, stream>>>(src, dst, (const float2*)ea,
                                                  bcur, staged, E, B);
    k_place<<<B, 1024, 0, stream>>>(staged, rptr, erec, N);
  } else {
    k_scatter<<<eb, 256, 0, stream>>>(src, dst, ea, pos, erec, E);  // fallback
  }

  int tiles = (N + 15) / 16;
  int mb = (tiles + 3) / 4;
  k_inproj_gemm<<<mb, 256, 0, stream>>>(x, Win, bin, WmT, hb, g, N);

  int ab = (N + 31) / 32;     // k_agg: 32 8-lane groups per 256-thread block, 1 node/group
  for (int l = 0; l < 3; ++l) {
    k_agg<<<ab, 256, 0, stream>>>(g, rptr, erec,
                                  Wmsg + (size_t)l * 66 * 64 + 64 * 64,
                                  bmsg + (size_t)l * 64, aggb, N);
    k_updgemm<<<mb, 256, 0, stream>>>(hb, aggb, WuT + (size_t)l * 64 * 128,
                                      bupd + (size_t)l * 64,
                                      (l < 2) ? (WmT + (size_t)(l + 1) * 64 * 64) : nullptr,
                                      hb, g,
                                      (l == 2) ? h : nullptr,
                                      Wn, bn, probs, hsumP, N);
  }

  k_final<<<1, 64, 0, stream>>>(hsumP, W1, b1, W2, b2, out4, (float)N);
}

// Round 12
// 219.017 us; speedup vs baseline: 5.0203x; 1.0167x over previous
//
#include <hip/hip_runtime.h>
#include <math.h>

constexpr int H = 64;

typedef __attribute__((ext_vector_type(8))) short bf16x8;
typedef __attribute__((ext_vector_type(4))) float f32x4;
typedef unsigned long long u64;

__device__ inline unsigned short f2bf(float f) {
  union { float f; unsigned int u; } c; c.f = f;
  unsigned int u = c.u;
  return (unsigned short)((u + 0x7FFF + ((u >> 16) & 1)) >> 16);  // RNE
}
__device__ inline float bf2f(unsigned int s) {
  union { unsigned int u; float f; } c; c.u = s << 16;
  return c.f;
}
// fp8 e4m3 via HW cvt (encode+decode on same chip -> self-consistent format)
__device__ inline unsigned char f2fp8(float f) {
  return (unsigned char)(__builtin_amdgcn_cvt_pk_fp8_f32(f, f, 0, false) & 0xFF);
}

// ---- prep: zero hist+hsumP, transpose+bf16 weights (one kernel) ----
__global__ void k_prep(int* __restrict__ hist, float* __restrict__ hsumP,
                       const float* __restrict__ Wmsg, const float* __restrict__ Wupd,
                       unsigned short* __restrict__ WmT, unsigned short* __restrict__ WuT,
                       int n) {
  int t = blockIdx.x * blockDim.x + threadIdx.x;
  if (t < n) hist[t] = 0;
  if (t < 512) hsumP[t] = 0.f;
  int u = t - n;
  if (u >= 0 && u < 3 * 12288) {
    int l = u / 12288, rem = u % 12288;
    if (rem < 4096) {
      int j = rem >> 6, k = rem & 63;
      WmT[l * 4096 + rem] = f2bf(Wmsg[(size_t)l * 66 * 64 + k * 64 + j]);
    } else {
      int r2 = rem - 4096;
      int j = r2 >> 7, k = r2 & 127;
      WuT[l * 8192 + r2] = f2bf(Wupd[(size_t)l * 128 * 64 + k * 64 + j]);
    }
  }
}

// ---- CSR build ----
__global__ void k_hist(const int* __restrict__ dst, int* __restrict__ hist, int E) {
  int e = blockIdx.x * blockDim.x + threadIdx.x;
  if (e < E) atomicAdd(&hist[dst[e]], 1);
}

__global__ void k_scan1(const int* __restrict__ hist, int* __restrict__ bsum, int n) {
  __shared__ int sred[256];
  int tid = threadIdx.x;
  int base = blockIdx.x * 1024 + tid * 4;
  int s = 0;
#pragma unroll
  for (int k = 0; k < 4; ++k) { int i = base + k; if (i < n) s += hist[i]; }
  sred[tid] = s;
  __syncthreads();
  for (int d = 128; d > 0; d >>= 1) {
    if (tid < d) sred[tid] += sred[tid + d];
    __syncthreads();
  }
  if (tid == 0) bsum[blockIdx.x] = sred[0];
}

// exclusive scan of block sums; also seeds bcur (bsum[b] == rptr[b<<10])
__global__ void k_scan2(int* __restrict__ bsum, int* __restrict__ bcur, int nb) {
  __shared__ int sd[1024];
  int tid = threadIdx.x;
  int v = (tid < nb) ? bsum[tid] : 0;
  sd[tid] = v;
  __syncthreads();
  for (int d = 1; d < 1024; d <<= 1) {
    int t = (tid >= d) ? sd[tid - d] : 0;
    __syncthreads();
    sd[tid] += t;
    __syncthreads();
  }
  if (tid < nb) {
    int ex = sd[tid] - v;
    bsum[tid] = ex;
    bcur[tid] = ex;
  }
}

__global__ void k_scan3(const int* __restrict__ hist, const int* __restrict__ bsum,
                        int* __restrict__ row_ptr, int* __restrict__ pos, int n) {
  __shared__ int sth[256];
  int tid = threadIdx.x;
  int base = blockIdx.x * 1024 + tid * 4;
  int v[4]; int s = 0;
#pragma unroll
  for (int k = 0; k < 4; ++k) { int i = base + k; v[k] = (i < n) ? hist[i] : 0; s += v[k]; }
  sth[tid] = s;
  __syncthreads();
  for (int d = 1; d < 256; d <<= 1) {
    int t = (tid >= d) ? sth[tid - d] : 0;
    __syncthreads();
    sth[tid] += t;
    __syncthreads();
  }
  int run = bsum[blockIdx.x] + sth[tid] - s;
  if (blockIdx.x == 0 && tid == 0) row_ptr[0] = 0;
#pragma unroll
  for (int k = 0; k < 4; ++k) {
    int i = base + k;
    if (i < n) {
      pos[i] = run;
      run += v[k];
      row_ptr[i + 1] = run;
    }
  }
}

// ---- bucketed two-phase edge placement; 8B packed record:
//      [15:0]=src  [25:16]=dst&1023  [31:26]=bucket  [63:32]=ea as 2xbf16 ----
__global__ void k_part(const int* __restrict__ src, const int* __restrict__ dst,
                       const float2* __restrict__ ea2, int* __restrict__ bcur,
                       u64* __restrict__ staged, int E, int B) {
  __shared__ u64 srt[2048];                   // 16 KB
  __shared__ int cnt[64], offs[64], gbase[64];
  int tid = threadIdx.x;
  int base = blockIdx.x * 2048;
  if (tid < 64) cnt[tid] = 0;
  __syncthreads();
  u64 rec_[8]; int bk_[8], rk_[8];
#pragma unroll
  for (int k = 0; k < 8; ++k) {
    int e = base + k * 256 + tid;
    if (e < E) {
      int d = dst[e];
      int bk = d >> 10;
      float2 eav = ea2[e];
      unsigned int eap = (unsigned int)f2bf(eav.x) | ((unsigned int)f2bf(eav.y) << 16);
      rec_[k] = (u64)(unsigned int)(src[e] & 0xFFFF)
              | ((u64)(unsigned int)(d & 1023) << 16)
              | ((u64)(unsigned int)bk << 26)
              | ((u64)eap << 32);
      bk_[k] = bk;
      rk_[k] = atomicAdd(&cnt[bk], 1);
    } else bk_[k] = -1;
  }
  __syncthreads();
  if (tid == 0) {
    int run = 0;
    for (int b = 0; b < B; ++b) { offs[b] = run; run += cnt[b]; }
  }
  __syncthreads();
#pragma unroll
  for (int k = 0; k < 8; ++k)
    if (bk_[k] >= 0) srt[offs[bk_[k]] + rk_[k]] = rec_[k];
  __syncthreads();
  if (tid < B && cnt[tid] > 0) gbase[tid] = atomicAdd(&bcur[tid], cnt[tid]);
  __syncthreads();
  int total = (base + 2048 <= E) ? 2048 : (E > base ? E - base : 0);
  for (int i = tid; i < total; i += 256) {
    u64 r = srt[i];
    int bk = (int)((r >> 26) & 63u);
    staged[gbase[bk] + (i - offs[bk])] = r;   // bucket-contiguous full-line appends
  }
}

// Phase B: one workgroup per bucket -> final dst-sorted erec {src, ea}, L2-local writes
__global__ void k_place(const u64* __restrict__ staged, const int* __restrict__ rptr,
                        u64* __restrict__ erec, int N_) {
  __shared__ int cnt2[1024];
  __shared__ int rptrL[1025];
  int b = blockIdx.x;
  int nd0 = b << 10;
  int nn = min(nd0 + 1024, N_) - nd0;
  int tid = threadIdx.x;  // 1024 threads
  if (tid < nn) { cnt2[tid] = 0; rptrL[tid] = rptr[nd0 + tid]; }
  if (tid == 0) rptrL[nn] = rptr[nd0 + nn];
  __syncthreads();
  int beg = rptrL[0], end = rptrL[nn];
  for (int i = beg + tid; i < end; i += 1024) {
    u64 r = staged[i];
    int dl = (int)((r >> 16) & 1023u);
    int p = rptrL[dl] + atomicAdd(&cnt2[dl], 1);
    erec[p] = (r & 0xFFFFull) | ((r >> 32) << 32);
  }
}

// ---- fallback single-pass scatter (only if N > 65536) ----
__global__ void k_scatter(const int* __restrict__ src, const int* __restrict__ dst,
                          const float* __restrict__ ea, int* __restrict__ pos,
                          u64* __restrict__ erec, int E) {
  int e = blockIdx.x * blockDim.x + threadIdx.x;
  if (e < E) {
    int d = dst[e];
    int p = atomicAdd(&pos[d], 1);
    u64 lo = f2bf(ea[2 * e]);
    u64 hi = f2bf(ea[2 * e + 1]);
    erec[p] = (u64)(unsigned int)src[e] | ((lo | (hi << 16)) << 32);
  }
}

// ---- fused input projection + gemm0: hb = bf16(x@Win+bin); g = fp8(hb @ Wm1[0]) ----
__global__ void k_inproj_gemm(const float* __restrict__ x, const float* __restrict__ Win,
                              const float* __restrict__ bin,
                              const unsigned short* __restrict__ wmt,
                              unsigned short* __restrict__ hb,
                              unsigned char* __restrict__ g, int n) {
  int lane = threadIdx.x & 63;
  int wv = blockIdx.x * (blockDim.x >> 6) + (threadIdx.x >> 6);
  int v0 = wv * 16;
  if (v0 >= n) return;
  int r16 = lane & 15, hi = lane >> 4;
  int row = v0 + r16;
  float x0 = 0.f, x1 = 0.f;
  if (row < n) { x0 = x[2 * row]; x1 = x[2 * row + 1]; }
  union { bf16x8 v; unsigned short u[8]; } af[2];
#pragma unroll
  for (int s = 0; s < 2; ++s)
#pragma unroll
    for (int t = 0; t < 8; ++t) {
      int j = s * 32 + hi * 8 + t;
      af[s].u[t] = f2bf(fmaf(x0, Win[j], fmaf(x1, Win[64 + j], bin[j])));
    }
  if (row < n) {
    *(bf16x8*)(hb + (size_t)row * H + hi * 8)      = af[0].v;
    *(bf16x8*)(hb + (size_t)row * H + 32 + hi * 8) = af[1].v;
  }
  bf16x8 bfr[2][4];
#pragma unroll
  for (int ks = 0; ks < 2; ++ks)
#pragma unroll
    for (int jt = 0; jt < 4; ++jt)
      bfr[ks][jt] = *(const bf16x8*)(wmt + (jt * 16 + r16) * 64 + ks * 32 + hi * 8);
  f32x4 acc[4] = {};
#pragma unroll
  for (int ks = 0; ks < 2; ++ks)
#pragma unroll
    for (int jt = 0; jt < 4; ++jt)
      acc[jt] = __builtin_amdgcn_mfma_f32_16x16x32_bf16(af[ks].v, bfr[ks][jt], acc[jt], 0, 0, 0);
#pragma unroll
  for (int jt = 0; jt < 4; ++jt) {
    int col = jt * 16 + r16;
#pragma unroll
    for (int r = 0; r < 4; ++r) {
      int orow = v0 + hi * 4 + r;
      if (orow < n) g[(size_t)orow * H + col] = f2fp8(acc[jt][r]);
    }
  }
}

// ---- per-chain accumulate: 8 fp8 feats from a uint2 ----
__device__ inline void acc8(float* a, uint2 gw, float e0, float e1,
                            const float4 waL, const float4 waH,
                            const float4 wbL, const float4 wbH,
                            const float4 bL, const float4 bH) {
  a[0] += fmaxf(fmaf(e0, waL.x, fmaf(e1, wbL.x, __builtin_amdgcn_cvt_f32_fp8(gw.x, 0) + bL.x)), 0.f);
  a[1] += fmaxf(fmaf(e0, waL.y, fmaf(e1, wbL.y, __builtin_amdgcn_cvt_f32_fp8(gw.x, 1) + bL.y)), 0.f);
  a[2] += fmaxf(fmaf(e0, waL.z, fmaf(e1, wbL.z, __builtin_amdgcn_cvt_f32_fp8(gw.x, 2) + bL.z)), 0.f);
  a[3] += fmaxf(fmaf(e0, waL.w, fmaf(e1, wbL.w, __builtin_amdgcn_cvt_f32_fp8(gw.x, 3) + bL.w)), 0.f);
  a[4] += fmaxf(fmaf(e0, waH.x, fmaf(e1, wbH.x, __builtin_amdgcn_cvt_f32_fp8(gw.y, 0) + bH.x)), 0.f);
  a[5] += fmaxf(fmaf(e0, waH.y, fmaf(e1, wbH.y, __builtin_amdgcn_cvt_f32_fp8(gw.y, 1) + bH.y)), 0.f);
  a[6] += fmaxf(fmaf(e0, waH.z, fmaf(e1, wbH.z, __builtin_amdgcn_cvt_f32_fp8(gw.y, 2) + bH.z)), 0.f);
  a[7] += fmaxf(fmaf(e0, waH.w, fmaf(e1, wbH.w, __builtin_amdgcn_cvt_f32_fp8(gw.y, 3) + bH.w)), 0.f);
}

// ---- aggregation: one 8-lane group PER NODE, 8B fp8 row-slices, 4 gather chains ----
__global__ void k_agg(const unsigned char* __restrict__ g, const int* __restrict__ row_ptr,
                      const u64* __restrict__ erec,
                      const float* __restrict__ Wm2, const float* __restrict__ bm,
                      unsigned short* __restrict__ aggb, int n) {
  int r = threadIdx.x & 7;
  int j0 = r * 8;                 // 8 features (8 B fp8) per lane
  float4 waL = *(const float4*)(Wm2 + j0);
  float4 waH = *(const float4*)(Wm2 + j0 + 4);
  float4 wbL = *(const float4*)(Wm2 + 64 + j0);
  float4 wbH = *(const float4*)(Wm2 + 64 + j0 + 4);
  float4 bL  = *(const float4*)(bm + j0);
  float4 bH  = *(const float4*)(bm + j0 + 4);
  int v = blockIdx.x * (blockDim.x >> 3) + (threadIdx.x >> 3);
  if (v >= n) return;
  int beg = row_ptr[v], end = row_ptr[v + 1];
  float a[8] = {0.f, 0.f, 0.f, 0.f, 0.f, 0.f, 0.f, 0.f};
  int i = beg;
  for (; i + 3 < end; i += 4) {   // 4 independent gather chains per group
    u64 rA = erec[i], rB = erec[i + 1], rC = erec[i + 2], rD = erec[i + 3];
    uint2 gwA = *(const uint2*)(g + (size_t)(unsigned int)rA * H + j0);
    uint2 gwB = *(const uint2*)(g + (size_t)(unsigned int)rB * H + j0);
    uint2 gwC = *(const uint2*)(g + (size_t)(unsigned int)rC * H + j0);
    uint2 gwD = *(const uint2*)(g + (size_t)(unsigned int)rD * H + j0);
    unsigned int eA = (unsigned int)(rA >> 32), eB = (unsigned int)(rB >> 32);
    unsigned int eC = (unsigned int)(rC >> 32), eD = (unsigned int)(rD >> 32);
    acc8(a, gwA, bf2f(eA & 0xffffu), bf2f(eA >> 16), waL, waH, wbL, wbH, bL, bH);
    acc8(a, gwB, bf2f(eB & 0xffffu), bf2f(eB >> 16), waL, waH, wbL, wbH, bL, bH);
    acc8(a, gwC, bf2f(eC & 0xffffu), bf2f(eC >> 16), waL, waH, wbL, wbH, bL, bH);
    acc8(a, gwD, bf2f(eD & 0xffffu), bf2f(eD >> 16), waL, waH, wbL, wbH, bL, bH);
  }
  for (; i < end; ++i) {
    u64 rA = erec[i];
    uint2 gwA = *(const uint2*)(g + (size_t)(unsigned int)rA * H + j0);
    unsigned int eA = (unsigned int)(rA >> 32);
    acc8(a, gwA, bf2f(eA & 0xffffu), bf2f(eA >> 16), waL, waH, wbL, wbH, bL, bH);
  }
  float inv = 1.f / fmaxf((float)(end - beg), 1.f);
  uint4 o;
  o.x = (unsigned int)f2bf(a[0] * inv) | ((unsigned int)f2bf(a[1] * inv) << 16);
  o.y = (unsigned int)f2bf(a[2] * inv) | ((unsigned int)f2bf(a[3] * inv) << 16);
  o.z = (unsigned int)f2bf(a[4] * inv) | ((unsigned int)f2bf(a[5] * inv) << 16);
  o.w = (unsigned int)f2bf(a[6] * inv) | ((unsigned int)f2bf(a[7] * inv) << 16);
  *(uint4*)(aggb + (size_t)v * H + j0) = o;
}

// ---- fused update MLP + (next-layer gemm | node head) ----
__global__ void k_updgemm(const unsigned short* __restrict__ hb,
                          const unsigned short* __restrict__ aggb,
                          const unsigned short* __restrict__ wut,
                          const float* __restrict__ bu,
                          const unsigned short* __restrict__ wmt_next, // null on last layer
                          unsigned short* __restrict__ hb_out,
                          unsigned char* __restrict__ g_out,
                          float* __restrict__ hout,                    // non-null on last layer
                          const float* __restrict__ Wn, const float* __restrict__ bn,
                          float* __restrict__ probs, float* __restrict__ hsumP,
                          int n) {
  __shared__ __align__(16) unsigned short hstage[4][16][72];  // +8 pad: kills stride-128B bank conflict
  __shared__ float shsum[64];
  int lane = threadIdx.x & 63;
  int w = threadIdx.x >> 6;
  int wv = blockIdx.x * (blockDim.x >> 6) + w;
  int v0 = wv * 16;
  bool act = v0 < n;
  int r16 = lane & 15, hi = lane >> 4;
  if (hout && threadIdx.x < 64) shsum[threadIdx.x] = 0.f;
  bf16x8 bfr[4][4];
#pragma unroll
  for (int ks = 0; ks < 4; ++ks)
#pragma unroll
    for (int jt = 0; jt < 4; ++jt)
      bfr[ks][jt] = *(const bf16x8*)(wut + (jt * 16 + r16) * 128 + ks * 32 + hi * 8);
  f32x4 acc[4];
#pragma unroll
  for (int jt = 0; jt < 4; ++jt) {
    float b = bu[jt * 16 + r16];
    acc[jt] = (f32x4){b, b, b, b};
  }
  bf16x8 afr[4];
  int row = v0 + r16;
  if (act && row < n) {
    const unsigned short* hrow = hb   + (size_t)row * H + hi * 8;
    const unsigned short* arow = aggb + (size_t)row * H + hi * 8;
    afr[0] = *(const bf16x8*)(hrow);
    afr[1] = *(const bf16x8*)(hrow + 32);
    afr[2] = *(const bf16x8*)(arow);
    afr[3] = *(const bf16x8*)(arow + 32);
  } else {
    afr[0] = afr[1] = afr[2] = afr[3] = (bf16x8){0,0,0,0,0,0,0,0};
  }
#pragma unroll
  for (int ks = 0; ks < 4; ++ks)
#pragma unroll
    for (int jt = 0; jt < 4; ++jt)
      acc[jt] = __builtin_amdgcn_mfma_f32_16x16x32_bf16(afr[ks], bfr[ks][jt], acc[jt], 0, 0, 0);
  float ov[4][4];
  unsigned short ob[4][4];
#pragma unroll
  for (int jt = 0; jt < 4; ++jt) {
    int col = jt * 16 + r16;
#pragma unroll
    for (int r = 0; r < 4; ++r) {
      int orow = v0 + hi * 4 + r;
      bool ok = act && orow < n;
      float o = fmaxf(acc[jt][r], 0.f);
      ov[jt][r] = ok ? o : 0.f;
      ob[jt][r] = f2bf(ov[jt][r]);
      if (ok) {
        hb_out[(size_t)orow * H + col] = ob[jt][r];
        if (hout) hout[(size_t)orow * H + col] = o;
      }
    }
  }
  if (wmt_next) {
    // stage h_out through LDS to re-shape C-layout -> A-fragment layout
#pragma unroll
    for (int jt = 0; jt < 4; ++jt)
#pragma unroll
      for (int r = 0; r < 4; ++r)
        hstage[w][hi * 4 + r][jt * 16 + r16] = ob[jt][r];
    __syncthreads();
    bf16x8 af2[2];
    af2[0] = *(const bf16x8*)(&hstage[w][r16][hi * 8]);
    af2[1] = *(const bf16x8*)(&hstage[w][r16][32 + hi * 8]);
    bf16x8 bf2r[2][4];
#pragma unroll
    for (int ks = 0; ks < 2; ++ks)
#pragma unroll
      for (int jt = 0; jt < 4; ++jt)
        bf2r[ks][jt] = *(const bf16x8*)(wmt_next + (jt * 16 + r16) * 64 + ks * 32 + hi * 8);
    f32x4 acc2[4] = {};
#pragma unroll
    for (int ks = 0; ks < 2; ++ks)
#pragma unroll
      for (int jt = 0; jt < 4; ++jt)
        acc2[jt] = __builtin_amdgcn_mfma_f32_16x16x32_bf16(af2[ks], bf2r[ks][jt], acc2[jt], 0, 0, 0);
#pragma unroll
    for (int jt = 0; jt < 4; ++jt) {
      int col = jt * 16 + r16;
#pragma unroll
      for (int r = 0; r < 4; ++r) {
        int orow = v0 + hi * 4 + r;
        if (act && orow < n) g_out[(size_t)orow * H + col] = f2fp8(acc2[jt][r]);
      }
    }
  } else {
    float bn0 = bn[0];
    float lg[4] = {0.f, 0.f, 0.f, 0.f};
#pragma unroll
    for (int jt = 0; jt < 4; ++jt) {
      float wn = Wn[jt * 16 + r16];
#pragma unroll
      for (int r = 0; r < 4; ++r) lg[r] = fmaf(ov[jt][r], wn, lg[r]);
    }
#pragma unroll
    for (int d = 1; d < 16; d <<= 1) {
#pragma unroll
      for (int r = 0; r < 4; ++r) lg[r] += __shfl_xor(lg[r], d);
    }
    if (r16 == 0) {
#pragma unroll
      for (int r = 0; r < 4; ++r) {
        int orow = v0 + hi * 4 + r;
        if (act && orow < n) probs[orow] = 1.f / (1.f + expf(-(lg[r] + bn0)));
      }
    }
    __syncthreads();
#pragma unroll
    for (int jt = 0; jt < 4; ++jt) {
      float s = ov[jt][0] + ov[jt][1] + ov[jt][2] + ov[jt][3];
      s += __shfl_xor(s, 16); s += __shfl_xor(s, 32);
      if (hi == 0) atomicAdd(&shsum[jt * 16 + r16], s);
    }
    __syncthreads();
    if (threadIdx.x < 64)
      atomicAdd(&hsumP[((blockIdx.x & 7) << 6) + threadIdx.x], shsum[threadIdx.x]);
  }
}

// ---- global mean + 2-layer head (tiny) ----
__global__ void k_final(const float* __restrict__ hsumP,
                        const float* __restrict__ W1, const float* __restrict__ b1,
                        const float* __restrict__ W2, const float* __restrict__ b2,
                        float* __restrict__ out4, float n_nodes) {
  __shared__ float hmean[64];
  __shared__ float z1[32];
  int tid = threadIdx.x;
  if (tid < 64) {
    float s = 0.f;
#pragma unroll
    for (int b = 0; b < 8; ++b) s += hsumP[b * 64 + tid];
    hmean[tid] = s / n_nodes;
  }
  __syncthreads();
  if (tid < 32) {
    float a = b1[tid];
    for (int k = 0; k < 64; ++k) a = fmaf(hmean[k], W1[k * 32 + tid], a);
    z1[tid] = fmaxf(a, 0.f);
  }
  __syncthreads();
  if (tid < 4) {
    float a = b2[tid];
    for (int k = 0; k < 32; ++k) a = fmaf(z1[k], W2[k * 4 + tid], a);
    out4[tid] = a;
  }
}

extern "C" void kernel_launch(void* const* d_in, const int* in_sizes, int n_in,
                              void* d_out, int out_size, void* d_ws, size_t ws_size,
                              hipStream_t stream) {
  const float* x    = (const float*)d_in[0];
  const int*   ei   = (const int*)d_in[1];
  const float* ea   = (const float*)d_in[2];
  const float* Win  = (const float*)d_in[3];
  const float* bin  = (const float*)d_in[4];
  const float* Wmsg = (const float*)d_in[5];
  const float* bmsg = (const float*)d_in[6];
  const float* Wupd = (const float*)d_in[7];
  const float* bupd = (const float*)d_in[8];
  const float* Wn   = (const float*)d_in[9];
  const float* bn   = (const float*)d_in[10];
  const float* W1   = (const float*)d_in[13];
  const float* b1   = (const float*)d_in[14];
  const float* W2   = (const float*)d_in[15];
  const float* b2   = (const float*)d_in[16];

  const int N = in_sizes[0] / 2;
  const int E = in_sizes[1] / 2;
  const int* src = ei;
  const int* dst = ei + E;

  char* ws = (char*)d_ws;
  size_t off = 0;
  auto alloc = [&](size_t bytes) {
    void* p = ws + off;
    off = (off + bytes + 255) & ~(size_t)255;
    return p;
  };
  int*   hist = (int*)  alloc((size_t)N * 4);
  int*   rptr = (int*)  alloc((size_t)(N + 1) * 4);
  int*   pos  = (int*)  alloc((size_t)N * 4);
  int*   bsum = (int*)  alloc((size_t)1024 * 4);
  int*   bcur = (int*)  alloc((size_t)1024 * 4);
  u64*   staged = (u64*)alloc((size_t)E * 8);
  u64*   erec = (u64*)  alloc((size_t)E * 8);
  unsigned short* hb   = (unsigned short*)alloc((size_t)N * H * 2);
  unsigned char*  g    = (unsigned char*) alloc((size_t)N * H);      // fp8: 3.2MB < 4MB L2/XCD
  unsigned short* aggb = (unsigned short*)alloc((size_t)N * H * 2);
  unsigned short* WmT  = (unsigned short*)alloc((size_t)3 * 64 * 64 * 2);
  unsigned short* WuT  = (unsigned short*)alloc((size_t)3 * 64 * 128 * 2);
  float* hsumP = (float*)alloc(8 * 64 * 4);
  (void)ws_size;

  float* probs = (float*)d_out;          // [N]
  float* out4  = probs + N;              // [4]
  float* h     = out4 + 4;               // [N, 64] fp32 final embeddings

  int eb = (E + 255) / 256;
  int sb = (N + 1023) / 1024;
  k_prep<<<(N + 3 * 12288 + 255) / 256, 256, 0, stream>>>(hist, hsumP, Wmsg, Wupd, WmT, WuT, N);
  k_hist<<<eb, 256, 0, stream>>>(dst, hist, E);
  k_scan1<<<sb, 256, 0, stream>>>(hist, bsum, N);
  k_scan2<<<1, 1024, 0, stream>>>(bsum, bcur, sb);
  k_scan3<<<sb, 256, 0, stream>>>(hist, bsum, rptr, pos, N);

  int B = (N + 1023) >> 10;   // dst-buckets of 1024 nodes; B<=64 implies src fits 16 bits
  if (B <= 64) {
    k_part<<<(E + 2047) / 2048, 256, 0, stream>>>(src, dst, (const float2*)ea,
                                                  bcur, staged, E, B);
    k_place<<<B, 1024, 0, stream>>>(staged, rptr, erec, N);
  } else {
    k_scatter<<<eb, 256, 0, stream>>>(src, dst, ea, pos, erec, E);  // fallback
  }

  int tiles = (N + 15) / 16;
  int mb = (tiles + 3) / 4;
  k_inproj_gemm<<<mb, 256, 0, stream>>>(x, Win, bin, WmT, hb, g, N);

  int ab = (N + 31) / 32;     // k_agg: 32 8-lane groups per 256-thread block, 1 node/group
  for (int l = 0; l < 3; ++l) {
    k_agg<<<ab, 256, 0, stream>>>(g, rptr, erec,
                                  Wmsg + (size_t)l * 66 * 64 + 64 * 64,
                                  bmsg + (size_t)l * 64, aggb, N);
    k_updgemm<<<mb, 256, 0, stream>>>(hb, aggb, WuT + (size_t)l * 64 * 128,
                                      bupd + (size_t)l * 64,
                                      (l < 2) ? (WmT + (size_t)(l + 1) * 64 * 64) : nullptr,
                                      hb, g,
                                      (l == 2) ? h : nullptr,
                                      Wn, bn, probs, hsumP, N);
  }

  k_final<<<1, 64, 0, stream>>>(hsumP, W1, b1, W2, b2, out4, (float)N);
}

// Round 13
// 215.863 us; speedup vs baseline: 5.0936x; 1.0146x over previous
//
#include <hip/hip_runtime.h>
#include <math.h>

constexpr int H = 64;

typedef __attribute__((ext_vector_type(8))) short bf16x8;
typedef __attribute__((ext_vector_type(4))) float f32x4;
typedef unsigned long long u64;

__device__ inline unsigned short f2bf(float f) {
  union { float f; unsigned int u; } c; c.f = f;
  unsigned int u = c.u;
  return (unsigned short)((u + 0x7FFF + ((u >> 16) & 1)) >> 16);  // RNE
}
__device__ inline float bf2f(unsigned int s) {
  union { unsigned int u; float f; } c; c.u = s << 16;
  return c.f;
}
// fp8 e4m3 via HW cvt (encode+decode on same chip -> self-consistent format)
__device__ inline unsigned char f2fp8(float f) {
  return (unsigned char)(__builtin_amdgcn_cvt_pk_fp8_f32(f, f, 0, false) & 0xFF);
}

// ---- prep: zero hist+hsumP, transpose+bf16 weights (one kernel) ----
__global__ void k_prep(int* __restrict__ hist, float* __restrict__ hsumP,
                       const float* __restrict__ Wmsg, const float* __restrict__ Wupd,
                       unsigned short* __restrict__ WmT, unsigned short* __restrict__ WuT,
                       int n) {
  int t = blockIdx.x * blockDim.x + threadIdx.x;
  if (t < n) hist[t] = 0;
  if (t < 512) hsumP[t] = 0.f;
  int u = t - n;
  if (u >= 0 && u < 3 * 12288) {
    int l = u / 12288, rem = u % 12288;
    if (rem < 4096) {
      int j = rem >> 6, k = rem & 63;
      WmT[l * 4096 + rem] = f2bf(Wmsg[(size_t)l * 66 * 64 + k * 64 + j]);
    } else {
      int r2 = rem - 4096;
      int j = r2 >> 7, k = r2 & 127;
      WuT[l * 8192 + r2] = f2bf(Wupd[(size_t)l * 128 * 64 + k * 64 + j]);
    }
  }
}

// ---- CSR build ----
__global__ void k_hist(const int* __restrict__ dst, int* __restrict__ hist, int E) {
  int e = blockIdx.x * blockDim.x + threadIdx.x;
  if (e < E) atomicAdd(&hist[dst[e]], 1);
}

__global__ void k_scan1(const int* __restrict__ hist, int* __restrict__ bsum, int n) {
  __shared__ int sred[256];
  int tid = threadIdx.x;
  int base = blockIdx.x * 1024 + tid * 4;
  int s = 0;
#pragma unroll
  for (int k = 0; k < 4; ++k) { int i = base + k; if (i < n) s += hist[i]; }
  sred[tid] = s;
  __syncthreads();
  for (int d = 128; d > 0; d >>= 1) {
    if (tid < d) sred[tid] += sred[tid + d];
    __syncthreads();
  }
  if (tid == 0) bsum[blockIdx.x] = sred[0];
}

// exclusive scan of block sums; also seeds bcur (bsum[b] == rptr[b<<10])
__global__ void k_scan2(int* __restrict__ bsum, int* __restrict__ bcur, int nb) {
  __shared__ int sd[1024];
  int tid = threadIdx.x;
  int v = (tid < nb) ? bsum[tid] : 0;
  sd[tid] = v;
  __syncthreads();
  for (int d = 1; d < 1024; d <<= 1) {
    int t = (tid >= d) ? sd[tid - d] : 0;
    __syncthreads();
    sd[tid] += t;
    __syncthreads();
  }
  if (tid < nb) {
    int ex = sd[tid] - v;
    bsum[tid] = ex;
    bcur[tid] = ex;
  }
}

__global__ void k_scan3(const int* __restrict__ hist, const int* __restrict__ bsum,
                        int* __restrict__ row_ptr, int* __restrict__ pos, int n) {
  __shared__ int sth[256];
  int tid = threadIdx.x;
  int base = blockIdx.x * 1024 + tid * 4;
  int v[4]; int s = 0;
#pragma unroll
  for (int k = 0; k < 4; ++k) { int i = base + k; v[k] = (i < n) ? hist[i] : 0; s += v[k]; }
  sth[tid] = s;
  __syncthreads();
  for (int d = 1; d < 256; d <<= 1) {
    int t = (tid >= d) ? sth[tid - d] : 0;
    __syncthreads();
    sth[tid] += t;
    __syncthreads();
  }
  int run = bsum[blockIdx.x] + sth[tid] - s;
  if (blockIdx.x == 0 && tid == 0) row_ptr[0] = 0;
#pragma unroll
  for (int k = 0; k < 4; ++k) {
    int i = base + k;
    if (i < n) {
      pos[i] = run;
      run += v[k];
      row_ptr[i + 1] = run;
    }
  }
}

// ---- bucketed two-phase edge placement; 8B packed record ----
__global__ void k_part(const int* __restrict__ src, const int* __restrict__ dst,
                       const float2* __restrict__ ea2, int* __restrict__ bcur,
                       u64* __restrict__ staged, int E, int B) {
  __shared__ u64 srt[2048];                   // 16 KB
  __shared__ int cnt[64], offs[64], gbase[64];
  int tid = threadIdx.x;
  int base = blockIdx.x * 2048;
  if (tid < 64) cnt[tid] = 0;
  __syncthreads();
  u64 rec_[8]; int bk_[8], rk_[8];
#pragma unroll
  for (int k = 0; k < 8; ++k) {
    int e = base + k * 256 + tid;
    if (e < E) {
      int d = dst[e];
      int bk = d >> 10;
      float2 eav = ea2[e];
      unsigned int eap = (unsigned int)f2bf(eav.x) | ((unsigned int)f2bf(eav.y) << 16);
      rec_[k] = (u64)(unsigned int)(src[e] & 0xFFFF)
              | ((u64)(unsigned int)(d & 1023) << 16)
              | ((u64)(unsigned int)bk << 26)
              | ((u64)eap << 32);
      bk_[k] = bk;
      rk_[k] = atomicAdd(&cnt[bk], 1);
    } else bk_[k] = -1;
  }
  __syncthreads();
  if (tid == 0) {
    int run = 0;
    for (int b = 0; b < B; ++b) { offs[b] = run; run += cnt[b]; }
  }
  __syncthreads();
#pragma unroll
  for (int k = 0; k < 8; ++k)
    if (bk_[k] >= 0) srt[offs[bk_[k]] + rk_[k]] = rec_[k];
  __syncthreads();
  if (tid < B && cnt[tid] > 0) gbase[tid] = atomicAdd(&bcur[tid], cnt[tid]);
  __syncthreads();
  int total = (base + 2048 <= E) ? 2048 : (E > base ? E - base : 0);
  for (int i = tid; i < total; i += 256) {
    u64 r = srt[i];
    int bk = (int)((r >> 26) & 63u);
    staged[gbase[bk] + (i - offs[bk])] = r;   // bucket-contiguous full-line appends
  }
}

// Phase B: one workgroup per bucket -> final dst-sorted erec {src, ea}, L2-local writes
__global__ void k_place(const u64* __restrict__ staged, const int* __restrict__ rptr,
                        u64* __restrict__ erec, int N_) {
  __shared__ int cnt2[1024];
  __shared__ int rptrL[1025];
  int b = blockIdx.x;
  int nd0 = b << 10;
  int nn = min(nd0 + 1024, N_) - nd0;
  int tid = threadIdx.x;  // 1024 threads
  if (tid < nn) { cnt2[tid] = 0; rptrL[tid] = rptr[nd0 + tid]; }
  if (tid == 0) rptrL[nn] = rptr[nd0 + nn];
  __syncthreads();
  int beg = rptrL[0], end = rptrL[nn];
  for (int i = beg + tid; i < end; i += 1024) {
    u64 r = staged[i];
    int dl = (int)((r >> 16) & 1023u);
    int p = rptrL[dl] + atomicAdd(&cnt2[dl], 1);
    erec[p] = (r & 0xFFFFull) | ((r >> 32) << 32);
  }
}

// ---- fallback single-pass scatter (only if N > 65536) ----
__global__ void k_scatter(const int* __restrict__ src, const int* __restrict__ dst,
                          const float* __restrict__ ea, int* __restrict__ pos,
                          u64* __restrict__ erec, int E) {
  int e = blockIdx.x * blockDim.x + threadIdx.x;
  if (e < E) {
    int d = dst[e];
    int p = atomicAdd(&pos[d], 1);
    u64 lo = f2bf(ea[2 * e]);
    u64 hi = f2bf(ea[2 * e + 1]);
    erec[p] = (u64)(unsigned int)src[e] | ((lo | (hi << 16)) << 32);
  }
}

// ---- fused input projection + gemm0: hb = bf16(x@Win+bin); g = fp8(hb @ Wm1[0]) ----
__global__ void k_inproj_gemm(const float* __restrict__ x, const float* __restrict__ Win,
                              const float* __restrict__ bin,
                              const unsigned short* __restrict__ wmt,
                              unsigned short* __restrict__ hb,
                              unsigned char* __restrict__ g, int n) {
  int lane = threadIdx.x & 63;
  int wv = blockIdx.x * (blockDim.x >> 6) + (threadIdx.x >> 6);
  int v0 = wv * 16;
  if (v0 >= n) return;
  int r16 = lane & 15, hi = lane >> 4;
  int row = v0 + r16;
  float x0 = 0.f, x1 = 0.f;
  if (row < n) { x0 = x[2 * row]; x1 = x[2 * row + 1]; }
  union { bf16x8 v; unsigned short u[8]; } af[2];
#pragma unroll
  for (int s = 0; s < 2; ++s)
#pragma unroll
    for (int t = 0; t < 8; ++t) {
      int j = s * 32 + hi * 8 + t;
      af[s].u[t] = f2bf(fmaf(x0, Win[j], fmaf(x1, Win[64 + j], bin[j])));
    }
  if (row < n) {
    *(bf16x8*)(hb + (size_t)row * H + hi * 8)      = af[0].v;
    *(bf16x8*)(hb + (size_t)row * H + 32 + hi * 8) = af[1].v;
  }
  bf16x8 bfr[2][4];
#pragma unroll
  for (int ks = 0; ks < 2; ++ks)
#pragma unroll
    for (int jt = 0; jt < 4; ++jt)
      bfr[ks][jt] = *(const bf16x8*)(wmt + (jt * 16 + r16) * 64 + ks * 32 + hi * 8);
  f32x4 acc[4] = {};
#pragma unroll
  for (int ks = 0; ks < 2; ++ks)
#pragma unroll
    for (int jt = 0; jt < 4; ++jt)
      acc[jt] = __builtin_amdgcn_mfma_f32_16x16x32_bf16(af[ks].v, bfr[ks][jt], acc[jt], 0, 0, 0);
#pragma unroll
  for (int jt = 0; jt < 4; ++jt) {
    int col = jt * 16 + r16;
#pragma unroll
    for (int r = 0; r < 4; ++r) {
      int orow = v0 + hi * 4 + r;
      if (orow < n) g[(size_t)orow * H + col] = f2fp8(acc[jt][r]);
    }
  }
}

// ---- per-chain accumulate: 8 fp8 feats from a uint2 ----
__device__ inline void acc8(float* a, uint2 gw, float e0, float e1,
                            const float4 waL, const float4 waH,
                            const float4 wbL, const float4 wbH,
                            const float4 bL, const float4 bH) {
  a[0] += fmaxf(fmaf(e0, waL.x, fmaf(e1, wbL.x, __builtin_amdgcn_cvt_f32_fp8(gw.x, 0) + bL.x)), 0.f);
  a[1] += fmaxf(fmaf(e0, waL.y, fmaf(e1, wbL.y, __builtin_amdgcn_cvt_f32_fp8(gw.x, 1) + bL.y)), 0.f);
  a[2] += fmaxf(fmaf(e0, waL.z, fmaf(e1, wbL.z, __builtin_amdgcn_cvt_f32_fp8(gw.x, 2) + bL.z)), 0.f);
  a[3] += fmaxf(fmaf(e0, waL.w, fmaf(e1, wbL.w, __builtin_amdgcn_cvt_f32_fp8(gw.x, 3) + bL.w)), 0.f);
  a[4] += fmaxf(fmaf(e0, waH.x, fmaf(e1, wbH.x, __builtin_amdgcn_cvt_f32_fp8(gw.y, 0) + bH.x)), 0.f);
  a[5] += fmaxf(fmaf(e0, waH.y, fmaf(e1, wbH.y, __builtin_amdgcn_cvt_f32_fp8(gw.y, 1) + bH.y)), 0.f);
  a[6] += fmaxf(fmaf(e0, waH.z, fmaf(e1, wbH.z, __builtin_amdgcn_cvt_f32_fp8(gw.y, 2) + bH.z)), 0.f);
  a[7] += fmaxf(fmaf(e0, waH.w, fmaf(e1, wbH.w, __builtin_amdgcn_cvt_f32_fp8(gw.y, 3) + bH.w)), 0.f);
}

// ---- fused layer: agg (into LDS) + update MFMA + (next gemm | node head) ----
// block = 256 threads, owns 64 nodes. g double-buffered across layers (phase-2
// writes g_out while other blocks' phase-1 still reads g_in).
__global__ void k_layer(const unsigned char* __restrict__ g_in,
                        const int* __restrict__ row_ptr, const u64* __restrict__ erec,
                        const float* __restrict__ Wm2, const float* __restrict__ bm,
                        unsigned short* __restrict__ hb,     // in/out (row-owner rw)
                        const unsigned short* __restrict__ wut,
                        const float* __restrict__ bu,
                        const unsigned short* __restrict__ wmt_next, // null on last layer
                        unsigned char* __restrict__ g_out,
                        float* __restrict__ hout,                    // non-null on last layer
                        const float* __restrict__ Wn, const float* __restrict__ bn,
                        float* __restrict__ probs, float* __restrict__ hsumP,
                        int n) {
  __shared__ __align__(16) unsigned short aggL[64][72];   // +8 pad: 2-way banks only
  __shared__ __align__(16) unsigned short hstage[4][16][72];
  __shared__ float shsum[64];
  int v0 = blockIdx.x * 64;

  // ---- phase 1: aggregate this block's 64 nodes into aggL ----
  {
    int gid = threadIdx.x >> 3, r = threadIdx.x & 7;
    int j0 = r * 8;
    float4 waL = *(const float4*)(Wm2 + j0);
    float4 waH = *(const float4*)(Wm2 + j0 + 4);
    float4 wbL = *(const float4*)(Wm2 + 64 + j0);
    float4 wbH = *(const float4*)(Wm2 + 64 + j0 + 4);
    float4 bL  = *(const float4*)(bm + j0);
    float4 bH  = *(const float4*)(bm + j0 + 4);
#pragma unroll
    for (int it = 0; it < 2; ++it) {
      int lv = it * 32 + gid;
      int v = v0 + lv;
      uint4 o = make_uint4(0, 0, 0, 0);
      if (v < n) {
        int beg = row_ptr[v], end = row_ptr[v + 1];
        float a[8] = {0.f, 0.f, 0.f, 0.f, 0.f, 0.f, 0.f, 0.f};
        int i = beg;
        for (; i + 3 < end; i += 4) {  // 4 independent gather chains
          u64 rA = erec[i], rB = erec[i + 1], rC = erec[i + 2], rD = erec[i + 3];
          uint2 gwA = *(const uint2*)(g_in + (size_t)(unsigned int)rA * H + j0);
          uint2 gwB = *(const uint2*)(g_in + (size_t)(unsigned int)rB * H + j0);
          uint2 gwC = *(const uint2*)(g_in + (size_t)(unsigned int)rC * H + j0);
          uint2 gwD = *(const uint2*)(g_in + (size_t)(unsigned int)rD * H + j0);
          unsigned int eA = (unsigned int)(rA >> 32), eB = (unsigned int)(rB >> 32);
          unsigned int eC = (unsigned int)(rC >> 32), eD = (unsigned int)(rD >> 32);
          acc8(a, gwA, bf2f(eA & 0xffffu), bf2f(eA >> 16), waL, waH, wbL, wbH, bL, bH);
          acc8(a, gwB, bf2f(eB & 0xffffu), bf2f(eB >> 16), waL, waH, wbL, wbH, bL, bH);
          acc8(a, gwC, bf2f(eC & 0xffffu), bf2f(eC >> 16), waL, waH, wbL, wbH, bL, bH);
          acc8(a, gwD, bf2f(eD & 0xffffu), bf2f(eD >> 16), waL, waH, wbL, wbH, bL, bH);
        }
        for (; i < end; ++i) {
          u64 rA = erec[i];
          uint2 gwA = *(const uint2*)(g_in + (size_t)(unsigned int)rA * H + j0);
          unsigned int eA = (unsigned int)(rA >> 32);
          acc8(a, gwA, bf2f(eA & 0xffffu), bf2f(eA >> 16), waL, waH, wbL, wbH, bL, bH);
        }
        float inv = 1.f / fmaxf((float)(end - beg), 1.f);
        o.x = (unsigned int)f2bf(a[0] * inv) | ((unsigned int)f2bf(a[1] * inv) << 16);
        o.y = (unsigned int)f2bf(a[2] * inv) | ((unsigned int)f2bf(a[3] * inv) << 16);
        o.z = (unsigned int)f2bf(a[4] * inv) | ((unsigned int)f2bf(a[5] * inv) << 16);
        o.w = (unsigned int)f2bf(a[6] * inv) | ((unsigned int)f2bf(a[7] * inv) << 16);
      }
      *(uint4*)(&aggL[lv][j0]) = o;
    }
  }
  __syncthreads();

  // ---- phase 2: update MFMA; agg A-frags straight from LDS ----
  int lane = threadIdx.x & 63;
  int w = threadIdx.x >> 6;
  int wv0 = v0 + w * 16;              // this wave's 16 rows
  bool act = wv0 < n;
  int r16 = lane & 15, hi = lane >> 4;
  int lw = w * 16 + r16;              // local row in aggL
  if (hout && threadIdx.x < 64) shsum[threadIdx.x] = 0.f;
  bf16x8 bfr[4][4];
#pragma unroll
  for (int ks = 0; ks < 4; ++ks)
#pragma unroll
    for (int jt = 0; jt < 4; ++jt)
      bfr[ks][jt] = *(const bf16x8*)(wut + (jt * 16 + r16) * 128 + ks * 32 + hi * 8);
  f32x4 acc[4];
#pragma unroll
  for (int jt = 0; jt < 4; ++jt) {
    float b = bu[jt * 16 + r16];
    acc[jt] = (f32x4){b, b, b, b};
  }
  bf16x8 afr[4];
  int row = wv0 + r16;
  if (act && row < n) {
    const unsigned short* hrow = hb + (size_t)row * H + hi * 8;
    afr[0] = *(const bf16x8*)(hrow);
    afr[1] = *(const bf16x8*)(hrow + 32);
  } else {
    afr[0] = afr[1] = (bf16x8){0,0,0,0,0,0,0,0};
  }
  afr[2] = *(const bf16x8*)(&aggL[lw][hi * 8]);        // garbage rows only affect
  afr[3] = *(const bf16x8*)(&aggL[lw][32 + hi * 8]);   // unstored C rows
#pragma unroll
  for (int ks = 0; ks < 4; ++ks)
#pragma unroll
    for (int jt = 0; jt < 4; ++jt)
      acc[jt] = __builtin_amdgcn_mfma_f32_16x16x32_bf16(afr[ks], bfr[ks][jt], acc[jt], 0, 0, 0);
  float ov[4][4];
  unsigned short ob[4][4];
#pragma unroll
  for (int jt = 0; jt < 4; ++jt) {
    int col = jt * 16 + r16;
#pragma unroll
    for (int r = 0; r < 4; ++r) {
      int orow = wv0 + hi * 4 + r;
      bool ok = act && orow < n;
      float o = fmaxf(acc[jt][r], 0.f);
      ov[jt][r] = ok ? o : 0.f;
      ob[jt][r] = f2bf(ov[jt][r]);
      if (ok) {
        hb[(size_t)orow * H + col] = ob[jt][r];
        if (hout) hout[(size_t)orow * H + col] = o;
      }
    }
  }
  if (wmt_next) {
    // stage h_out through LDS to re-shape C-layout -> A-fragment layout
#pragma unroll
    for (int jt = 0; jt < 4; ++jt)
#pragma unroll
      for (int r = 0; r < 4; ++r)
        hstage[w][hi * 4 + r][jt * 16 + r16] = ob[jt][r];
    __syncthreads();
    bf16x8 af2[2];
    af2[0] = *(const bf16x8*)(&hstage[w][r16][hi * 8]);
    af2[1] = *(const bf16x8*)(&hstage[w][r16][32 + hi * 8]);
    bf16x8 bf2r[2][4];
#pragma unroll
    for (int ks = 0; ks < 2; ++ks)
#pragma unroll
      for (int jt = 0; jt < 4; ++jt)
        bf2r[ks][jt] = *(const bf16x8*)(wmt_next + (jt * 16 + r16) * 64 + ks * 32 + hi * 8);
    f32x4 acc2[4] = {};
#pragma unroll
    for (int ks = 0; ks < 2; ++ks)
#pragma unroll
      for (int jt = 0; jt < 4; ++jt)
        acc2[jt] = __builtin_amdgcn_mfma_f32_16x16x32_bf16(af2[ks], bf2r[ks][jt], acc2[jt], 0, 0, 0);
#pragma unroll
    for (int jt = 0; jt < 4; ++jt) {
      int col = jt * 16 + r16;
#pragma unroll
      for (int r = 0; r < 4; ++r) {
        int orow = wv0 + hi * 4 + r;
        if (act && orow < n) g_out[(size_t)orow * H + col] = f2fp8(acc2[jt][r]);
      }
    }
  } else {
    float bn0 = bn[0];
    float lg[4] = {0.f, 0.f, 0.f, 0.f};
#pragma unroll
    for (int jt = 0; jt < 4; ++jt) {
      float wn = Wn[jt * 16 + r16];
#pragma unroll
      for (int r = 0; r < 4; ++r) lg[r] = fmaf(ov[jt][r], wn, lg[r]);
    }
#pragma unroll
    for (int d = 1; d < 16; d <<= 1) {
#pragma unroll
      for (int r = 0; r < 4; ++r) lg[r] += __shfl_xor(lg[r], d);
    }
    if (r16 == 0) {
#pragma unroll
      for (int r = 0; r < 4; ++r) {
        int orow = wv0 + hi * 4 + r;
        if (act && orow < n) probs[orow] = 1.f / (1.f + expf(-(lg[r] + bn0)));
      }
    }
    __syncthreads();
#pragma unroll
    for (int jt = 0; jt < 4; ++jt) {
      float s = ov[jt][0] + ov[jt][1] + ov[jt][2] + ov[jt][3];
      s += __shfl_xor(s, 16); s += __shfl_xor(s, 32);
      if (hi == 0) atomicAdd(&shsum[jt * 16 + r16], s);
    }
    __syncthreads();
    if (threadIdx.x < 64)
      atomicAdd(&hsumP[((blockIdx.x & 7) << 6) + threadIdx.x], shsum[threadIdx.x]);
  }
}

// ---- global mean + 2-layer head (tiny) ----
__global__ void k_final(const float* __restrict__ hsumP,
                        const float* __restrict__ W1, const float* __restrict__ b1,
                        const float* __restrict__ W2, const float* __restrict__ b2,
                        float* __restrict__ out4, float n_nodes) {
  __shared__ float hmean[64];
  __shared__ float z1[32];
  int tid = threadIdx.x;
  if (tid < 64) {
    float s = 0.f;
#pragma unroll
    for (int b = 0; b < 8; ++b) s += hsumP[b * 64 + tid];
    hmean[tid] = s / n_nodes;
  }
  __syncthreads();
  if (tid < 32) {
    float a = b1[tid];
    for (int k = 0; k < 64; ++k) a = fmaf(hmean[k], W1[k * 32 + tid], a);
    z1[tid] = fmaxf(a, 0.f);
  }
  __syncthreads();
  if (tid < 4) {
    float a = b2[tid];
    for (int k = 0; k < 32; ++k) a = fmaf(z1[k], W2[k * 4 + tid], a);
    out4[tid] = a;
  }
}

extern "C" void kernel_launch(void* const* d_in, const int* in_sizes, int n_in,
                              void* d_out, int out_size, void* d_ws, size_t ws_size,
                              hipStream_t stream) {
  const float* x    = (const float*)d_in[0];
  const int*   ei   = (const int*)d_in[1];
  const float* ea   = (const float*)d_in[2];
  const float* Win  = (const float*)d_in[3];
  const float* bin  = (const float*)d_in[4];
  const float* Wmsg = (const float*)d_in[5];
  const float* bmsg = (const float*)d_in[6];
  const float* Wupd = (const float*)d_in[7];
  const float* bupd = (const float*)d_in[8];
  const float* Wn   = (const float*)d_in[9];
  const float* bn   = (const float*)d_in[10];
  const float* W1   = (const float*)d_in[13];
  const float* b1   = (const float*)d_in[14];
  const float* W2   = (const float*)d_in[15];
  const float* b2   = (const float*)d_in[16];

  const int N = in_sizes[0] / 2;
  const int E = in_sizes[1] / 2;
  const int* src = ei;
  const int* dst = ei + E;

  char* ws = (char*)d_ws;
  size_t off = 0;
  auto alloc = [&](size_t bytes) {
    void* p = ws + off;
    off = (off + bytes + 255) & ~(size_t)255;
    return p;
  };
  int*   hist = (int*)  alloc((size_t)N * 4);
  int*   rptr = (int*)  alloc((size_t)(N + 1) * 4);
  int*   pos  = (int*)  alloc((size_t)N * 4);
  int*   bsum = (int*)  alloc((size_t)1024 * 4);
  int*   bcur = (int*)  alloc((size_t)1024 * 4);
  u64*   staged = (u64*)alloc((size_t)E * 8);
  u64*   erec = (u64*)  alloc((size_t)E * 8);
  unsigned short* hb   = (unsigned short*)alloc((size_t)N * H * 2);
  unsigned char*  gA   = (unsigned char*) alloc((size_t)N * H);   // fp8 ping
  unsigned char*  gB   = (unsigned char*) alloc((size_t)N * H);   // fp8 pong
  unsigned short* WmT  = (unsigned short*)alloc((size_t)3 * 64 * 64 * 2);
  unsigned short* WuT  = (unsigned short*)alloc((size_t)3 * 64 * 128 * 2);
  float* hsumP = (float*)alloc(8 * 64 * 4);
  (void)ws_size;

  float* probs = (float*)d_out;          // [N]
  float* out4  = probs + N;              // [4]
  float* h     = out4 + 4;               // [N, 64] fp32 final embeddings

  int eb = (E + 255) / 256;
  int sb = (N + 1023) / 1024;
  k_prep<<<(N + 3 * 12288 + 255) / 256, 256, 0, stream>>>(hist, hsumP, Wmsg, Wupd, WmT, WuT, N);
  k_hist<<<eb, 256, 0, stream>>>(dst, hist, E);
  k_scan1<<<sb, 256, 0, stream>>>(hist, bsum, N);
  k_scan2<<<1, 1024, 0, stream>>>(bsum, bcur, sb);
  k_scan3<<<sb, 256, 0, stream>>>(hist, bsum, rptr, pos, N);

  int B = (N + 1023) >> 10;   // dst-buckets of 1024 nodes; B<=64 implies src fits 16 bits
  if (B <= 64) {
    k_part<<<(E + 2047) / 2048, 256, 0, stream>>>(src, dst, (const float2*)ea,
                                                  bcur, staged, E, B);
    k_place<<<B, 1024, 0, stream>>>(staged, rptr, erec, N);
  } else {
    k_scatter<<<eb, 256, 0, stream>>>(src, dst, ea, pos, erec, E);  // fallback
  }

  int tiles = (N + 15) / 16;
  int mb = (tiles + 3) / 4;
  k_inproj_gemm<<<mb, 256, 0, stream>>>(x, Win, bin, WmT, hb, gA, N);

  int lb = (N + 63) / 64;     // fused layer: one block per 64 nodes
  for (int l = 0; l < 3; ++l) {
    const unsigned char* gin = (l & 1) ? gB : gA;
    unsigned char* gout      = (l & 1) ? gA : gB;
    k_layer<<<lb, 256, 0, stream>>>(gin, rptr, erec,
                                    Wmsg + (size_t)l * 66 * 64 + 64 * 64,
                                    bmsg + (size_t)l * 64,
                                    hb, WuT + (size_t)l * 64 * 128,
                                    bupd + (size_t)l * 64,
                                    (l < 2) ? (WmT + (size_t)(l + 1) * 64 * 64) : nullptr,
                                    gout,
                                    (l == 2) ? h : nullptr,
                                    Wn, bn, probs, hsumP, N);
  }

  k_final<<<1, 64, 0, stream>>>(hsumP, W1, b1, W2, b2, out4, (float)N);
}

// Round 14
// 215.372 us; speedup vs baseline: 5.1052x; 1.0023x over previous
//
#include <hip/hip_runtime.h>
#include <math.h>

constexpr int H = 64;

typedef __attribute__((ext_vector_type(8))) short bf16x8;
typedef __attribute__((ext_vector_type(4))) float f32x4;
typedef unsigned long long u64;

__device__ inline unsigned short f2bf(float f) {
  union { float f; unsigned int u; } c; c.f = f;
  unsigned int u = c.u;
  return (unsigned short)((u + 0x7FFF + ((u >> 16) & 1)) >> 16);  // RNE
}
__device__ inline float bf2f(unsigned int s) {
  union { unsigned int u; float f; } c; c.u = s << 16;
  return c.f;
}
// fp8 e4m3 via HW cvt (encode+decode on same chip -> self-consistent format)
__device__ inline unsigned char f2fp8(float f) {
  return (unsigned char)(__builtin_amdgcn_cvt_pk_fp8_f32(f, f, 0, false) & 0xFF);
}

// ---- prep: zero hist+hsumP+bcur2, transpose+bf16 weights (one kernel) ----
__global__ void k_prep(int* __restrict__ hist, float* __restrict__ hsumP,
                       int* __restrict__ bcur2,
                       const float* __restrict__ Wmsg, const float* __restrict__ Wupd,
                       unsigned short* __restrict__ WmT, unsigned short* __restrict__ WuT,
                       int n) {
  int t = blockIdx.x * blockDim.x + threadIdx.x;
  if (t < n) hist[t] = 0;
  if (t < 512) hsumP[t] = 0.f;
  if (t < 64) bcur2[t] = 0;
  int u = t - n;
  if (u >= 0 && u < 3 * 12288) {
    int l = u / 12288, rem = u % 12288;
    if (rem < 4096) {
      int j = rem >> 6, k = rem & 63;
      WmT[l * 4096 + rem] = f2bf(Wmsg[(size_t)l * 66 * 64 + k * 64 + j]);
    } else {
      int r2 = rem - 4096;
      int j = r2 >> 7, k = r2 & 127;
      WuT[l * 8192 + r2] = f2bf(Wupd[(size_t)l * 128 * 64 + k * 64 + j]);
    }
  }
}

// ---- hist (fallback path only) ----
__global__ void k_hist(const int* __restrict__ dst, int* __restrict__ hist, int E) {
  int e = blockIdx.x * blockDim.x + threadIdx.x;
  if (e < E) atomicAdd(&hist[dst[e]], 1);
}

__global__ void k_scan1(const int* __restrict__ hist, int* __restrict__ bsum, int n) {
  __shared__ int sred[256];
  int tid = threadIdx.x;
  int base = blockIdx.x * 1024 + tid * 4;
  int s = 0;
#pragma unroll
  for (int k = 0; k < 4; ++k) { int i = base + k; if (i < n) s += hist[i]; }
  sred[tid] = s;
  __syncthreads();
  for (int d = 128; d > 0; d >>= 1) {
    if (tid < d) sred[tid] += sred[tid + d];
    __syncthreads();
  }
  if (tid == 0) bsum[blockIdx.x] = sred[0];
}

__global__ void k_scan2(int* __restrict__ bsum, int nb) {
  __shared__ int sd[1024];
  int tid = threadIdx.x;
  int v = (tid < nb) ? bsum[tid] : 0;
  sd[tid] = v;
  __syncthreads();
  for (int d = 1; d < 1024; d <<= 1) {
    int t = (tid >= d) ? sd[tid - d] : 0;
    __syncthreads();
    sd[tid] += t;
    __syncthreads();
  }
  if (tid < nb) bsum[tid] = sd[tid] - v;
}

__global__ void k_scan3(const int* __restrict__ hist, const int* __restrict__ bsum,
                        int* __restrict__ row_ptr, int* __restrict__ pos, int n) {
  __shared__ int sth[256];
  int tid = threadIdx.x;
  int base = blockIdx.x * 1024 + tid * 4;
  int v[4]; int s = 0;
#pragma unroll
  for (int k = 0; k < 4; ++k) { int i = base + k; v[k] = (i < n) ? hist[i] : 0; s += v[k]; }
  sth[tid] = s;
  __syncthreads();
  for (int d = 1; d < 256; d <<= 1) {
    int t = (tid >= d) ? sth[tid - d] : 0;
    __syncthreads();
    sth[tid] += t;
    __syncthreads();
  }
  int run = bsum[blockIdx.x] + sth[tid] - s;
  if (blockIdx.x == 0 && tid == 0) row_ptr[0] = 0;
#pragma unroll
  for (int k = 0; k < 4; ++k) {
    int i = base + k;
    if (i < n) {
      pos[i] = run;
      run += v[k];
      row_ptr[i + 1] = run;
    }
  }
}

// ---- k_part: fused hist + block-local bucket sort -> independent staging regions
//      8B record: [15:0]=src [25:16]=dst&1023 [31:26]=bucket [63:32]=ea 2xbf16 ----
__global__ void k_part(const int* __restrict__ src, const int* __restrict__ dst,
                       const float2* __restrict__ ea2,
                       int* __restrict__ hist, int* __restrict__ bcur2,
                       u64* __restrict__ staged, int E, int B, int C) {
  __shared__ u64 srt[2048];                   // 16 KB
  __shared__ int cnt[64], offs[64], gbase[64];
  int tid = threadIdx.x;
  int base = blockIdx.x * 2048;
  if (tid < 64) cnt[tid] = 0;
  __syncthreads();
  u64 rec_[8]; int bk_[8], rk_[8];
#pragma unroll
  for (int k = 0; k < 8; ++k) {
    int e = base + k * 256 + tid;
    if (e < E) {
      int d = dst[e];
      atomicAdd(&hist[d], 1);                 // fused histogram
      int bk = d >> 10;
      float2 eav = ea2[e];
      unsigned int eap = (unsigned int)f2bf(eav.x) | ((unsigned int)f2bf(eav.y) << 16);
      rec_[k] = (u64)(unsigned int)(src[e] & 0xFFFF)
              | ((u64)(unsigned int)(d & 1023) << 16)
              | ((u64)(unsigned int)bk << 26)
              | ((u64)eap << 32);
      bk_[k] = bk;
      rk_[k] = atomicAdd(&cnt[bk], 1);
    } else bk_[k] = -1;
  }
  __syncthreads();
  if (tid == 0) {
    int run = 0;
    for (int b = 0; b < B; ++b) { offs[b] = run; run += cnt[b]; }
  }
  __syncthreads();
#pragma unroll
  for (int k = 0; k < 8; ++k)
    if (bk_[k] >= 0) srt[offs[bk_[k]] + rk_[k]] = rec_[k];
  __syncthreads();
  if (tid < B && cnt[tid] > 0) gbase[tid] = atomicAdd(&bcur2[tid], cnt[tid]);
  __syncthreads();
  int total = (base + 2048 <= E) ? 2048 : (E > base ? E - base : 0);
  for (int i = tid; i < total; i += 256) {
    u64 r = srt[i];
    int bk = (int)((r >> 26) & 63u);
    staged[(size_t)bk * C + gbase[bk] + (i - offs[bk])] = r;  // full-line appends
  }
}

// Phase B: one workgroup per bucket -> final dst-sorted erec, L2-local writes
__global__ void k_place(const u64* __restrict__ staged, const int* __restrict__ bcur2,
                        const int* __restrict__ rptr,
                        u64* __restrict__ erec, int N_, int C) {
  __shared__ int cnt2[1024];
  __shared__ int rptrL[1025];
  int b = blockIdx.x;
  int nd0 = b << 10;
  int nn = min(nd0 + 1024, N_) - nd0;
  int tid = threadIdx.x;  // 1024 threads
  if (tid < nn) { cnt2[tid] = 0; rptrL[tid] = rptr[nd0 + tid]; }
  if (tid == 0) rptrL[nn] = rptr[nd0 + nn];
  __syncthreads();
  int count = bcur2[b];
  const u64* sb = staged + (size_t)b * C;
  for (int i = tid; i < count; i += 1024) {
    u64 r = sb[i];
    int dl = (int)((r >> 16) & 1023u);
    int p = rptrL[dl] + atomicAdd(&cnt2[dl], 1);
    erec[p] = (r & 0xFFFFull) | ((r >> 32) << 32);
  }
}

// ---- fallback single-pass scatter (only if N > 65536) ----
__global__ void k_scatter(const int* __restrict__ src, const int* __restrict__ dst,
                          const float* __restrict__ ea, int* __restrict__ pos,
                          u64* __restrict__ erec, int E) {
  int e = blockIdx.x * blockDim.x + threadIdx.x;
  if (e < E) {
    int d = dst[e];
    int p = atomicAdd(&pos[d], 1);
    u64 lo = f2bf(ea[2 * e]);
    u64 hi = f2bf(ea[2 * e + 1]);
    erec[p] = (u64)(unsigned int)src[e] | ((lo | (hi << 16)) << 32);
  }
}

// ---- fused input projection + gemm0 ----
__global__ void k_inproj_gemm(const float* __restrict__ x, const float* __restrict__ Win,
                              const float* __restrict__ bin,
                              const unsigned short* __restrict__ wmt,
                              unsigned short* __restrict__ hb,
                              unsigned char* __restrict__ g, int n) {
  int lane = threadIdx.x & 63;
  int wv = blockIdx.x * (blockDim.x >> 6) + (threadIdx.x >> 6);
  int v0 = wv * 16;
  if (v0 >= n) return;
  int r16 = lane & 15, hi = lane >> 4;
  int row = v0 + r16;
  float x0 = 0.f, x1 = 0.f;
  if (row < n) { x0 = x[2 * row]; x1 = x[2 * row + 1]; }
  union { bf16x8 v; unsigned short u[8]; } af[2];
#pragma unroll
  for (int s = 0; s < 2; ++s)
#pragma unroll
    for (int t = 0; t < 8; ++t) {
      int j = s * 32 + hi * 8 + t;
      af[s].u[t] = f2bf(fmaf(x0, Win[j], fmaf(x1, Win[64 + j], bin[j])));
    }
  if (row < n) {
    *(bf16x8*)(hb + (size_t)row * H + hi * 8)      = af[0].v;
    *(bf16x8*)(hb + (size_t)row * H + 32 + hi * 8) = af[1].v;
  }
  bf16x8 bfr[2][4];
#pragma unroll
  for (int ks = 0; ks < 2; ++ks)
#pragma unroll
    for (int jt = 0; jt < 4; ++jt)
      bfr[ks][jt] = *(const bf16x8*)(wmt + (jt * 16 + r16) * 64 + ks * 32 + hi * 8);
  f32x4 acc[4] = {};
#pragma unroll
  for (int ks = 0; ks < 2; ++ks)
#pragma unroll
    for (int jt = 0; jt < 4; ++jt)
      acc[jt] = __builtin_amdgcn_mfma_f32_16x16x32_bf16(af[ks].v, bfr[ks][jt], acc[jt], 0, 0, 0);
#pragma unroll
  for (int jt = 0; jt < 4; ++jt) {
    int col = jt * 16 + r16;
#pragma unroll
    for (int r = 0; r < 4; ++r) {
      int orow = v0 + hi * 4 + r;
      if (orow < n) g[(size_t)orow * H + col] = f2fp8(acc[jt][r]);
    }
  }
}

// ---- per-chain accumulate: 8 fp8 feats from a uint2 ----
__device__ inline void acc8(float* a, uint2 gw, float e0, float e1,
                            const float4 waL, const float4 waH,
                            const float4 wbL, const float4 wbH,
                            const float4 bL, const float4 bH) {
  a[0] += fmaxf(fmaf(e0, waL.x, fmaf(e1, wbL.x, __builtin_amdgcn_cvt_f32_fp8(gw.x, 0) + bL.x)), 0.f);
  a[1] += fmaxf(fmaf(e0, waL.y, fmaf(e1, wbL.y, __builtin_amdgcn_cvt_f32_fp8(gw.x, 1) + bL.y)), 0.f);
  a[2] += fmaxf(fmaf(e0, waL.z, fmaf(e1, wbL.z, __builtin_amdgcn_cvt_f32_fp8(gw.x, 2) + bL.z)), 0.f);
  a[3] += fmaxf(fmaf(e0, waL.w, fmaf(e1, wbL.w, __builtin_amdgcn_cvt_f32_fp8(gw.x, 3) + bL.w)), 0.f);
  a[4] += fmaxf(fmaf(e0, waH.x, fmaf(e1, wbH.x, __builtin_amdgcn_cvt_f32_fp8(gw.y, 0) + bH.x)), 0.f);
  a[5] += fmaxf(fmaf(e0, waH.y, fmaf(e1, wbH.y, __builtin_amdgcn_cvt_f32_fp8(gw.y, 1) + bH.y)), 0.f);
  a[6] += fmaxf(fmaf(e0, waH.z, fmaf(e1, wbH.z, __builtin_amdgcn_cvt_f32_fp8(gw.y, 2) + bH.z)), 0.f);
  a[7] += fmaxf(fmaf(e0, waH.w, fmaf(e1, wbH.w, __builtin_amdgcn_cvt_f32_fp8(gw.y, 3) + bH.w)), 0.f);
}

// ---- fused layer: 32 nodes/block (1 node per 8-lane group -> max phase-1 TLP) ----
__global__ void k_layer(const unsigned char* __restrict__ g_in,
                        const int* __restrict__ row_ptr, const u64* __restrict__ erec,
                        const float* __restrict__ Wm2, const float* __restrict__ bm,
                        unsigned short* __restrict__ hb,
                        const unsigned short* __restrict__ wut,
                        const float* __restrict__ bu,
                        const unsigned short* __restrict__ wmt_next, // null on last layer
                        unsigned char* __restrict__ g_out,
                        float* __restrict__ hout,                    // non-null on last layer
                        const float* __restrict__ Wn, const float* __restrict__ bn,
                        float* __restrict__ probs, float* __restrict__ hsumP,
                        int n) {
  __shared__ __align__(16) unsigned short aggL[32][72];   // +8 pad: bank-conflict-free
  __shared__ __align__(16) unsigned short hstage[2][16][72];
  __shared__ float shsum[64];
  int v0 = blockIdx.x * 32;

  // ---- phase 1: 32 groups aggregate 32 nodes into aggL ----
  {
    int gid = threadIdx.x >> 3, r = threadIdx.x & 7;
    int j0 = r * 8;
    float4 waL = *(const float4*)(Wm2 + j0);
    float4 waH = *(const float4*)(Wm2 + j0 + 4);
    float4 wbL = *(const float4*)(Wm2 + 64 + j0);
    float4 wbH = *(const float4*)(Wm2 + 64 + j0 + 4);
    float4 bL  = *(const float4*)(bm + j0);
    float4 bH  = *(const float4*)(bm + j0 + 4);
    int v = v0 + gid;
    uint4 o = make_uint4(0, 0, 0, 0);
    if (v < n) {
      int beg = row_ptr[v], end = row_ptr[v + 1];
      float a[8] = {0.f, 0.f, 0.f, 0.f, 0.f, 0.f, 0.f, 0.f};
      int i = beg;
      for (; i + 3 < end; i += 4) {  // 4 independent gather chains
        u64 rA = erec[i], rB = erec[i + 1], rC = erec[i + 2], rD = erec[i + 3];
        uint2 gwA = *(const uint2*)(g_in + (size_t)(unsigned int)rA * H + j0);
        uint2 gwB = *(const uint2*)(g_in + (size_t)(unsigned int)rB * H + j0);
        uint2 gwC = *(const uint2*)(g_in + (size_t)(unsigned int)rC * H + j0);
        uint2 gwD = *(const uint2*)(g_in + (size_t)(unsigned int)rD * H + j0);
        unsigned int eA = (unsigned int)(rA >> 32), eB = (unsigned int)(rB >> 32);
        unsigned int eC = (unsigned int)(rC >> 32), eD = (unsigned int)(rD >> 32);
        acc8(a, gwA, bf2f(eA & 0xffffu), bf2f(eA >> 16), waL, waH, wbL, wbH, bL, bH);
        acc8(a, gwB, bf2f(eB & 0xffffu), bf2f(eB >> 16), waL, waH, wbL, wbH, bL, bH);
        acc8(a, gwC, bf2f(eC & 0xffffu), bf2f(eC >> 16), waL, waH, wbL, wbH, bL, bH);
        acc8(a, gwD, bf2f(eD & 0xffffu), bf2f(eD >> 16), waL, waH, wbL, wbH, bL, bH);
      }
      for (; i < end; ++i) {
        u64 rA = erec[i];
        uint2 gwA = *(const uint2*)(g_in + (size_t)(unsigned int)rA * H + j0);
        unsigned int eA = (unsigned int)(rA >> 32);
        acc8(a, gwA, bf2f(eA & 0xffffu), bf2f(eA >> 16), waL, waH, wbL, wbH, bL, bH);
      }
      float inv = 1.f / fmaxf((float)(end - beg), 1.f);
      o.x = (unsigned int)f2bf(a[0] * inv) | ((unsigned int)f2bf(a[1] * inv) << 16);
      o.y = (unsigned int)f2bf(a[2] * inv) | ((unsigned int)f2bf(a[3] * inv) << 16);
      o.z = (unsigned int)f2bf(a[4] * inv) | ((unsigned int)f2bf(a[5] * inv) << 16);
      o.w = (unsigned int)f2bf(a[6] * inv) | ((unsigned int)f2bf(a[7] * inv) << 16);
    }
    *(uint4*)(&aggL[gid][j0]) = o;
  }
  __syncthreads();

  // ---- phase 2: waves 0,1 do the update MFMA for rows v0..v0+31 ----
  int lane = threadIdx.x & 63;
  int w = threadIdx.x >> 6;
  bool mw = (w < 2);
  int wv0 = v0 + w * 16;
  bool act = mw && (wv0 < n);
  int r16 = lane & 15, hi = lane >> 4;
  if (hout && threadIdx.x < 64) shsum[threadIdx.x] = 0.f;
  bf16x8 bfr[4][4];
#pragma unroll
  for (int ks = 0; ks < 4; ++ks)
#pragma unroll
    for (int jt = 0; jt < 4; ++jt)
      bfr[ks][jt] = *(const bf16x8*)(wut + (jt * 16 + r16) * 128 + ks * 32 + hi * 8);
  f32x4 acc[4];
#pragma unroll
  for (int jt = 0; jt < 4; ++jt) {
    float b = bu[jt * 16 + r16];
    acc[jt] = (f32x4){b, b, b, b};
  }
  bf16x8 afr[4];
  int row = wv0 + r16;
  if (act && row < n) {
    const unsigned short* hrow = hb + (size_t)row * H + hi * 8;
    afr[0] = *(const bf16x8*)(hrow);
    afr[1] = *(const bf16x8*)(hrow + 32);
  } else {
    afr[0] = afr[1] = (bf16x8){0,0,0,0,0,0,0,0};
  }
  if (mw) {
    int lw = w * 16 + r16;
    afr[2] = *(const bf16x8*)(&aggL[lw][hi * 8]);
    afr[3] = *(const bf16x8*)(&aggL[lw][32 + hi * 8]);
  } else {
    afr[2] = afr[3] = (bf16x8){0,0,0,0,0,0,0,0};
  }
#pragma unroll
  for (int ks = 0; ks < 4; ++ks)
#pragma unroll
    for (int jt = 0; jt < 4; ++jt)
      acc[jt] = __builtin_amdgcn_mfma_f32_16x16x32_bf16(afr[ks], bfr[ks][jt], acc[jt], 0, 0, 0);
  float ov[4][4];
  unsigned short ob[4][4];
#pragma unroll
  for (int jt = 0; jt < 4; ++jt) {
    int col = jt * 16 + r16;
#pragma unroll
    for (int r = 0; r < 4; ++r) {
      int orow = wv0 + hi * 4 + r;
      bool ok = act && orow < n;
      float o = fmaxf(acc[jt][r], 0.f);
      ov[jt][r] = ok ? o : 0.f;
      ob[jt][r] = f2bf(ov[jt][r]);
      if (ok) {
        hb[(size_t)orow * H + col] = ob[jt][r];
        if (hout) hout[(size_t)orow * H + col] = o;
      }
    }
  }
  if (wmt_next) {
    if (mw) {
#pragma unroll
      for (int jt = 0; jt < 4; ++jt)
#pragma unroll
        for (int r = 0; r < 4; ++r)
          hstage[w][hi * 4 + r][jt * 16 + r16] = ob[jt][r];
    }
    __syncthreads();
    if (mw) {
      bf16x8 af2[2];
      af2[0] = *(const bf16x8*)(&hstage[w][r16][hi * 8]);
      af2[1] = *(const bf16x8*)(&hstage[w][r16][32 + hi * 8]);
      bf16x8 bf2r[2][4];
#pragma unroll
      for (int ks = 0; ks < 2; ++ks)
#pragma unroll
        for (int jt = 0; jt < 4; ++jt)
          bf2r[ks][jt] = *(const bf16x8*)(wmt_next + (jt * 16 + r16) * 64 + ks * 32 + hi * 8);
      f32x4 acc2[4] = {};
#pragma unroll
      for (int ks = 0; ks < 2; ++ks)
#pragma unroll
        for (int jt = 0; jt < 4; ++jt)
          acc2[jt] = __builtin_amdgcn_mfma_f32_16x16x32_bf16(af2[ks], bf2r[ks][jt], acc2[jt], 0, 0, 0);
#pragma unroll
      for (int jt = 0; jt < 4; ++jt) {
        int col = jt * 16 + r16;
#pragma unroll
        for (int r = 0; r < 4; ++r) {
          int orow = wv0 + hi * 4 + r;
          if (act && orow < n) g_out[(size_t)orow * H + col] = f2fp8(acc2[jt][r]);
        }
      }
    }
  } else {
    float bn0 = bn[0];
    float lg[4] = {0.f, 0.f, 0.f, 0.f};
#pragma unroll
    for (int jt = 0; jt < 4; ++jt) {
      float wn = Wn[jt * 16 + r16];
#pragma unroll
      for (int r = 0; r < 4; ++r) lg[r] = fmaf(ov[jt][r], wn, lg[r]);
    }
#pragma unroll
    for (int d = 1; d < 16; d <<= 1) {
#pragma unroll
      for (int r = 0; r < 4; ++r) lg[r] += __shfl_xor(lg[r], d);
    }
    if (r16 == 0 && act) {
#pragma unroll
      for (int r = 0; r < 4; ++r) {
        int orow = wv0 + hi * 4 + r;
        if (orow < n) probs[orow] = 1.f / (1.f + expf(-(lg[r] + bn0)));
      }
    }
    __syncthreads();
#pragma unroll
    for (int jt = 0; jt < 4; ++jt) {
      float s = ov[jt][0] + ov[jt][1] + ov[jt][2] + ov[jt][3];
      s += __shfl_xor(s, 16); s += __shfl_xor(s, 32);
      if (hi == 0) atomicAdd(&shsum[jt * 16 + r16], s);
    }
    __syncthreads();
    if (threadIdx.x < 64)
      atomicAdd(&hsumP[((blockIdx.x & 7) << 6) + threadIdx.x], shsum[threadIdx.x]);
  }
}

// ---- global mean + 2-layer head (tiny) ----
__global__ void k_final(const float* __restrict__ hsumP,
                        const float* __restrict__ W1, const float* __restrict__ b1,
                        const float* __restrict__ W2, const float* __restrict__ b2,
                        float* __restrict__ out4, float n_nodes) {
  __shared__ float hmean[64];
  __shared__ float z1[32];
  int tid = threadIdx.x;
  if (tid < 64) {
    float s = 0.f;
#pragma unroll
    for (int b = 0; b < 8; ++b) s += hsumP[b * 64 + tid];
    hmean[tid] = s / n_nodes;
  }
  __syncthreads();
  if (tid < 32) {
    float a = b1[tid];
    for (int k = 0; k < 64; ++k) a = fmaf(hmean[k], W1[k * 32 + tid], a);
    z1[tid] = fmaxf(a, 0.f);
  }
  __syncthreads();
  if (tid < 4) {
    float a = b2[tid];
    for (int k = 0; k < 32; ++k) a = fmaf(z1[k], W2[k * 4 + tid], a);
    out4[tid] = a;
  }
}

extern "C" void kernel_launch(void* const* d_in, const int* in_sizes, int n_in,
                              void* d_out, int out_size, void* d_ws, size_t ws_size,
                              hipStream_t stream) {
  const float* x    = (const float*)d_in[0];
  const int*   ei   = (const int*)d_in[1];
  const float* ea   = (const float*)d_in[2];
  const float* Win  = (const float*)d_in[3];
  const float* bin  = (const float*)d_in[4];
  const float* Wmsg = (const float*)d_in[5];
  const float* bmsg = (const float*)d_in[6];
  const float* Wupd = (const float*)d_in[7];
  const float* bupd = (const float*)d_in[8];
  const float* Wn   = (const float*)d_in[9];
  const float* bn   = (const float*)d_in[10];
  const float* W1   = (const float*)d_in[13];
  const float* b1   = (const float*)d_in[14];
  const float* W2   = (const float*)d_in[15];
  const float* b2   = (const float*)d_in[16];

  const int N = in_sizes[0] / 2;
  const int E = in_sizes[1] / 2;
  const int* src = ei;
  const int* dst = ei + E;

  const int B = (N + 1023) >> 10;            // dst-buckets of 1024 nodes
  const int C = (2 * (E / (B > 0 ? B : 1)) + 2048 + 255) & ~255;  // per-bucket staging cap

  char* ws = (char*)d_ws;
  size_t off = 0;
  auto alloc = [&](size_t bytes) {
    void* p = ws + off;
    off = (off + bytes + 255) & ~(size_t)255;
    return p;
  };
  int*   hist  = (int*)  alloc((size_t)N * 4);
  int*   rptr  = (int*)  alloc((size_t)(N + 1) * 4);
  int*   pos   = (int*)  alloc((size_t)N * 4);
  int*   bsum  = (int*)  alloc((size_t)1024 * 4);
  int*   bcur2 = (int*)  alloc((size_t)64 * 4);
  u64*   staged = (u64*) alloc((size_t)(B <= 64 ? 64 : 0) * C * 8 + 8);
  u64*   erec  = (u64*)  alloc((size_t)E * 8);
  unsigned short* hb   = (unsigned short*)alloc((size_t)N * H * 2);
  unsigned char*  gA   = (unsigned char*) alloc((size_t)N * H);   // fp8 ping
  unsigned char*  gB   = (unsigned char*) alloc((size_t)N * H);   // fp8 pong
  unsigned short* WmT  = (unsigned short*)alloc((size_t)3 * 64 * 64 * 2);
  unsigned short* WuT  = (unsigned short*)alloc((size_t)3 * 64 * 128 * 2);
  float* hsumP = (float*)alloc(8 * 64 * 4);
  (void)ws_size;

  float* probs = (float*)d_out;          // [N]
  float* out4  = probs + N;              // [4]
  float* h     = out4 + 4;               // [N, 64] fp32 final embeddings

  int eb = (E + 255) / 256;
  int sb = (N + 1023) / 1024;
  k_prep<<<(N + 3 * 12288 + 255) / 256, 256, 0, stream>>>(hist, hsumP, bcur2,
                                                          Wmsg, Wupd, WmT, WuT, N);
  if (B <= 64) {
    k_part<<<(E + 2047) / 2048, 256, 0, stream>>>(src, dst, (const float2*)ea,
                                                  hist, bcur2, staged, E, B, C);
    k_scan1<<<sb, 256, 0, stream>>>(hist, bsum, N);
    k_scan2<<<1, 1024, 0, stream>>>(bsum, sb);
    k_scan3<<<sb, 256, 0, stream>>>(hist, bsum, rptr, pos, N);
    k_place<<<B, 1024, 0, stream>>>(staged, bcur2, rptr, erec, N, C);
  } else {
    k_hist<<<eb, 256, 0, stream>>>(dst, hist, E);
    k_scan1<<<sb, 256, 0, stream>>>(hist, bsum, N);
    k_scan2<<<1, 1024, 0, stream>>>(bsum, sb);
    k_scan3<<<sb, 256, 0, stream>>>(hist, bsum, rptr, pos, N);
    k_scatter<<<eb, 256, 0, stream>>>(src, dst, ea, pos, erec, E);
  }

  int tiles = (N + 15) / 16;
  int mb = (tiles + 3) / 4;
  k_inproj_gemm<<<mb, 256, 0, stream>>>(x, Win, bin, WmT, hb, gA, N);

  int lb = (N + 31) / 32;     // fused layer: 32 nodes/block, 1 node per 8-lane group
  for (int l = 0; l < 3; ++l) {
    const unsigned char* gin = (l & 1) ? gB : gA;
    unsigned char* gout      = (l & 1) ? gA : gB;
    k_layer<<<lb, 256, 0, stream>>>(gin, rptr, erec,
                                    Wmsg + (size_t)l * 66 * 64 + 64 * 64,
                                    bmsg + (size_t)l * 64,
                                    hb, WuT + (size_t)l * 64 * 128,
                                    bupd + (size_t)l * 64,
                                    (l < 2) ? (WmT + (size_t)(l + 1) * 64 * 64) : nullptr,
                                    gout,
                                    (l == 2) ? h : nullptr,
                                    Wn, bn, probs, hsumP, N);
  }

  k_final<<<1, 64, 0, stream>>>(hsumP, W1, b1, W2, b2, out4, (float)N);
}